// Round 1
// baseline (7781.023 us; speedup 1.0000x reference)
//
#include <hip/hip_runtime.h>
#include <math.h>

#define EPSBN 1e-5f

// ---------------- conv 3x3 SAME + bias + relu + BN(eval) ----------------
template<int CIN, int COUT, int COB, int PX>
__global__ __launch_bounds__(256) void conv_bn_relu(
    const float* __restrict__ in, const float* __restrict__ w,
    const float* __restrict__ bias, const float* __restrict__ sc,
    const float* __restrict__ of, const float* __restrict__ mn,
    const float* __restrict__ vr, float* __restrict__ out, int H, int W) {
  int tid = threadIdx.x;
  int col = tid % COB;
  int px  = tid / COB;
  int co  = blockIdx.y * COB + col;
  long p  = (long)blockIdx.x * PX + px;       // pixel id over B*H*W
  long hw = (long)H * W;
  int b = (int)(p / hw);
  long rem = p - (long)b * hw;
  int y = (int)(rem / W);
  int x = (int)(rem % W);
  float scale = sc[co] * rsqrtf(vr[co] + EPSBN);
  float shift = of[co] - mn[co] * scale;
  float acc = bias[co];
  #pragma unroll
  for (int dy = 0; dy < 3; ++dy) {
    int iy = y + dy - 1;
    if ((unsigned)iy >= (unsigned)H) continue;
    #pragma unroll
    for (int dx = 0; dx < 3; ++dx) {
      int ix = x + dx - 1;
      if ((unsigned)ix >= (unsigned)W) continue;
      const float* ip = in + ((long)(b * H + iy) * W + ix) * CIN;
      const float* wp = w + (long)((dy * 3 + dx) * CIN) * COUT + co;
      #pragma unroll 4
      for (int ci = 0; ci < CIN; ++ci)
        acc = fmaf(ip[ci], wp[(long)ci * COUT], acc);
    }
  }
  acc = fmaxf(acc, 0.f);
  out[p * COUT + co] = acc * scale + shift;
}

// ---------------- 2x2 maxpool stride 2 (H,W even) ----------------
__global__ __launch_bounds__(256) void maxpool2(
    const float* __restrict__ in, float* __restrict__ out,
    int H, int W, int C, long total) {
  long i = (long)blockIdx.x * 256 + threadIdx.x;
  if (i >= total) return;
  int W2 = W >> 1, H2 = H >> 1;
  int c = (int)(i % C);
  long r = i / C;
  int x = (int)(r % W2); r /= W2;
  int y = (int)(r % H2);
  int b = (int)(r / H2);
  const float* p0 = in + ((long)(b * H + 2 * y) * W + 2 * x) * C + c;
  long rs = (long)W * C;
  float mx = fmaxf(fmaxf(p0[0], p0[C]), fmaxf(p0[rs], p0[rs + C]));
  out[i] = mx;
}

// ---------------- xw = gather(x_seq) @ Wi + b   (M=2048,K=2048,N=2048) ----------------
// row r = t*64 + b ; A[r][k] = src[b*65536 + tt*2048 + k], tt = rev ? 31-t : t
__global__ __launch_bounds__(256) void gemm_xw(
    const float* __restrict__ src, const float* __restrict__ Wi,
    const float* __restrict__ bvec, float* __restrict__ xw, int rev) {
  __shared__ float As[16][64];
  __shared__ float Bs[16][64];
  int tid = threadIdx.x;
  int tx = tid % 16, ty = tid / 16;
  int bm = blockIdx.x, bn = blockIdx.y;
  float acc[4][4] = {};
  for (int k0 = 0; k0 < 2048; k0 += 16) {
    {
      int rr = tid >> 2, kk4 = (tid & 3) << 2;
      int r = bm * 64 + rr;
      int t = r >> 6, b = r & 63;
      int tt = rev ? 31 - t : t;
      const float4 a4 = *(const float4*)(src + (long)b * 65536 + (long)tt * 2048 + k0 + kk4);
      As[kk4 + 0][rr] = a4.x; As[kk4 + 1][rr] = a4.y;
      As[kk4 + 2][rr] = a4.z; As[kk4 + 3][rr] = a4.w;
    }
    {
      int kk = tid >> 4, nn = (tid & 15) << 2;
      *(float4*)&Bs[kk][nn] = *(const float4*)(Wi + (long)(k0 + kk) * 2048 + bn * 64 + nn);
    }
    __syncthreads();
    #pragma unroll
    for (int kk = 0; kk < 16; ++kk) {
      float a[4], bb[4];
      #pragma unroll
      for (int i = 0; i < 4; ++i) a[i] = As[kk][ty * 4 + i];
      #pragma unroll
      for (int j = 0; j < 4; ++j) bb[j] = Bs[kk][tx * 4 + j];
      #pragma unroll
      for (int i = 0; i < 4; ++i)
        #pragma unroll
        for (int j = 0; j < 4; ++j)
          acc[i][j] = fmaf(a[i], bb[j], acc[i][j]);
    }
    __syncthreads();
  }
  #pragma unroll
  for (int i = 0; i < 4; ++i) {
    int r = bm * 64 + ty * 4 + i;
    #pragma unroll
    for (int j = 0; j < 4; ++j) {
      int n = bn * 64 + tx * 4 + j;
      xw[(long)r * 2048 + n] = acc[i][j] + bvec[n];
    }
  }
}

// ---------------- one LSTM step (both directions) ----------------
// grid: (16 u-tiles of 32, 4 b-quads of 16, 2 dirs), block 256
__global__ __launch_bounds__(256) void lstm_step(
    int t,
    const float* __restrict__ xwF, const float* __restrict__ xwB,
    const float* __restrict__ WhF, const float* __restrict__ WhB,
    const float* __restrict__ zslab,
    float* __restrict__ cF, float* __restrict__ cB,
    float* __restrict__ hsF, float* __restrict__ hsB) {
  const int dir = blockIdx.z;
  const float* xw = dir ? xwB : xwF;
  const float* Wh = dir ? WhB : WhF;
  float* cst = dir ? cB : cF;
  float* hs  = dir ? hsB : hsF;
  const float* hprev = (t == 0) ? zslab : (hs + (long)(t - 1) * 64 * 512);

  const int u0 = blockIdx.x * 32;
  const int b0 = blockIdx.y * 16;
  __shared__ float Hs[16][512];
  __shared__ float Ws[32][128];
  __shared__ float Zs[16][128];
  const int tid = threadIdx.x;

  // stage hprev[b0..b0+15][0..511]
  {
    int r = tid >> 4;
    int cbase = (tid & 15) << 5;
    const float* hp = hprev + (long)(b0 + r) * 512 + cbase;
    #pragma unroll
    for (int i = 0; i < 32; i += 4)
      *(float4*)&Hs[r][cbase + i] = *(const float4*)(hp + i);
  }

  const int jq = tid & 31;           // cols jq*4 .. jq*4+3 (within one gate chunk)
  const int br = tid >> 5;           // 0..7 -> rows b0+br*2, b0+br*2+1
  const int g  = (jq * 4) >> 5;      // gate 0..3
  const int uu = (jq * 4) & 31;
  const int wcol = g * 512 + u0 + uu;
  float acc[2][4] = {};

  for (int k0 = 0; k0 < 512; k0 += 32) {
    __syncthreads();                 // also covers initial Hs staging
    {
      int kk = tid >> 3;
      int sub = tid & 7;
      int gch = sub >> 1, half = sub & 1;
      const float* wp = Wh + (long)(k0 + kk) * 2048 + gch * 512 + u0 + half * 16;
      #pragma unroll
      for (int i = 0; i < 16; i += 4)
        *(float4*)&Ws[kk][sub * 16 + i] = *(const float4*)(wp + i);
    }
    __syncthreads();
    #pragma unroll
    for (int kk = 0; kk < 32; ++kk) {
      float h0 = Hs[br * 2 + 0][k0 + kk];
      float h1 = Hs[br * 2 + 1][k0 + kk];
      float4 w4 = *(const float4*)&Ws[kk][jq * 4];
      acc[0][0] = fmaf(h0, w4.x, acc[0][0]);
      acc[0][1] = fmaf(h0, w4.y, acc[0][1]);
      acc[0][2] = fmaf(h0, w4.z, acc[0][2]);
      acc[0][3] = fmaf(h0, w4.w, acc[0][3]);
      acc[1][0] = fmaf(h1, w4.x, acc[1][0]);
      acc[1][1] = fmaf(h1, w4.y, acc[1][1]);
      acc[1][2] = fmaf(h1, w4.z, acc[1][2]);
      acc[1][3] = fmaf(h1, w4.w, acc[1][3]);
    }
  }

  // add xw and park z in LDS
  #pragma unroll
  for (int i = 0; i < 2; ++i) {
    int brow = b0 + br * 2 + i;
    const float* xp = xw + (long)(t * 64 + brow) * 2048 + wcol;
    #pragma unroll
    for (int j = 0; j < 4; ++j)
      Zs[br * 2 + i][jq * 4 + j] = acc[i][j] + xp[j];
  }
  __syncthreads();

  // state update: 16 b x 32 u = 512 pairs
  for (int p = tid; p < 512; p += 256) {
    int b = p >> 5, u = p & 31;
    float zi = Zs[b][u];
    float zf = Zs[b][32 + u];
    float zg = Zs[b][64 + u];
    float zo = Zs[b][96 + u];
    long cidx = (long)(b0 + b) * 512 + u0 + u;
    float c_old = cst[cidx];
    float ii = 1.f / (1.f + expf(-zi));
    float ff = 1.f / (1.f + expf(-zf));
    float gg = tanhf(zg);
    float oo = 1.f / (1.f + expf(-zo));
    float cn = ff * c_old + ii * gg;
    float hn = oo * tanhf(cn);
    cst[cidx] = cn;
    hs[((long)t * 64 + b0 + b) * 512 + u0 + u] = hn;
  }
}

// ---------------- FC + log_softmax ----------------
__global__ __launch_bounds__(128) void fc_logsoftmax(
    const float* __restrict__ hsF, const float* __restrict__ hsB,
    const float* __restrict__ W, const float* __restrict__ bias,
    float* __restrict__ out) {
  int bt = blockIdx.x;          // 0..2047, b-major: bt = b*32 + t
  int b = bt >> 5, t = bt & 31;
  __shared__ float vbuf[1024];
  __shared__ float sl[80];
  __shared__ float red[2];
  int tid = threadIdx.x;
  const float* fv = hsF + ((long)t * 64 + b) * 512;
  const float* bv = hsB + ((long)t * 64 + b) * 512;
  for (int i = tid; i < 512; i += 128) vbuf[i] = fv[i];
  for (int i = tid; i < 512; i += 128) vbuf[512 + i] = bv[i];
  __syncthreads();
  if (tid < 80) {
    float acc = bias[tid];
    for (int k = 0; k < 1024; ++k)
      acc = fmaf(vbuf[k], W[(long)k * 80 + tid], acc);
    sl[tid] = acc;
  }
  __syncthreads();
  if (tid == 0) {
    float mx = -1e30f;
    for (int j = 0; j < 80; ++j) mx = fmaxf(mx, sl[j]);
    float s = 0.f;
    for (int j = 0; j < 80; ++j) s += expf(sl[j] - mx);
    red[0] = mx;
    red[1] = logf(s);
  }
  __syncthreads();
  if (tid < 80)
    out[(long)bt * 80 + tid] = sl[tid] - red[0] - red[1];
}

__global__ __launch_bounds__(256) void zero_kernel(float* p, int n) {
  int i = blockIdx.x * 256 + threadIdx.x;
  if (i < n) p[i] = 0.f;
}

extern "C" void kernel_launch(void* const* d_in, const int* in_sizes, int n_in,
                              void* d_out, int out_size, void* d_ws, size_t ws_size,
                              hipStream_t stream) {
  const float* x  = (const float*)d_in[0];
  const float* k1 = (const float*)d_in[1];  const float* b1 = (const float*)d_in[2];
  const float* s1 = (const float*)d_in[3];  const float* o1 = (const float*)d_in[4];
  const float* m1 = (const float*)d_in[5];  const float* v1 = (const float*)d_in[6];
  const float* k2 = (const float*)d_in[7];  const float* b2 = (const float*)d_in[8];
  const float* s2 = (const float*)d_in[9];  const float* o2 = (const float*)d_in[10];
  const float* m2 = (const float*)d_in[11]; const float* v2 = (const float*)d_in[12];
  const float* k3 = (const float*)d_in[13]; const float* b3 = (const float*)d_in[14];
  const float* s3 = (const float*)d_in[15]; const float* o3 = (const float*)d_in[16];
  const float* m3 = (const float*)d_in[17]; const float* v3 = (const float*)d_in[18];
  const float* k4 = (const float*)d_in[19]; const float* b4 = (const float*)d_in[20];
  const float* s4 = (const float*)d_in[21]; const float* o4 = (const float*)d_in[22];
  const float* m4 = (const float*)d_in[23]; const float* v4 = (const float*)d_in[24];
  const float* k5 = (const float*)d_in[25]; const float* b5 = (const float*)d_in[26];
  const float* s5 = (const float*)d_in[27]; const float* o5 = (const float*)d_in[28];
  const float* m5 = (const float*)d_in[29]; const float* v5 = (const float*)d_in[30];
  const float* fwWi = (const float*)d_in[31];
  const float* fwWh = (const float*)d_in[32];
  const float* fwb  = (const float*)d_in[33];
  const float* bwWi = (const float*)d_in[34];
  const float* bwWh = (const float*)d_in[35];
  const float* bwb  = (const float*)d_in[36];
  const float* fcW  = (const float*)d_in[37];
  const float* fcb  = (const float*)d_in[38];

  float* ws = (float*)d_ws;
  float* A = ws;                       // up to 33,554,432 floats
  float* B = ws + 33554432;            // up to  8,388,608 floats
  float* S = ws + 41943040;
  float* cF = S;
  float* cB = S + 32768;
  float* zslab = S + 65536;
  float* hsF = S + 98304;              // [32][64][512]
  float* hsB = hsF + 1048576;

  zero_kernel<<<384, 256, 0, stream>>>(S, 98304);

  // conv1: [64,32,256,1] -> A [64,32,256,64]
  conv_bn_relu<1, 64, 64, 4><<<dim3(524288 / 4, 1), 256, 0, stream>>>(
      x, k1, b1, s1, o1, m1, v1, A, 32, 256);
  maxpool2<<<(8388608 + 255) / 256, 256, 0, stream>>>(A, B, 32, 256, 64, 8388608);

  // conv2: B [64,16,128,64] -> A [64,16,128,128]
  conv_bn_relu<64, 128, 128, 2><<<dim3(131072 / 2, 1), 256, 0, stream>>>(
      B, k2, b2, s2, o2, m2, v2, A, 16, 128);
  maxpool2<<<(4194304 + 255) / 256, 256, 0, stream>>>(A, B, 16, 128, 128, 4194304);

  // conv3: B [64,8,64,128] -> A [64,8,64,256]
  conv_bn_relu<128, 256, 256, 1><<<dim3(32768, 1), 256, 0, stream>>>(
      B, k3, b3, s3, o3, m3, v3, A, 8, 64);
  maxpool2<<<(2097152 + 255) / 256, 256, 0, stream>>>(A, B, 8, 64, 256, 2097152);

  // conv4: B [64,4,32,256] -> A [64,4,32,256]
  conv_bn_relu<256, 256, 256, 1><<<dim3(8192, 1), 256, 0, stream>>>(
      B, k4, b4, s4, o4, m4, v4, A, 4, 32);

  // conv5: A [64,4,32,256] -> B [64,4,32,512]
  conv_bn_relu<256, 512, 256, 1><<<dim3(8192, 2), 256, 0, stream>>>(
      A, k5, b5, s5, o5, m5, v5, B, 4, 32);

  // xw precompute (layer index 1 only — reference bug keeps only last layer)
  float* xwF = A;
  float* xwB = A + 4194304;
  gemm_xw<<<dim3(32, 32), 256, 0, stream>>>(B, fwWi + 4194304, fwb + 2048, xwF, 0);
  gemm_xw<<<dim3(32, 32), 256, 0, stream>>>(B, bwWi + 4194304, bwb + 2048, xwB, 1);

  const float* WhF = fwWh + 1048576;
  const float* WhB = bwWh + 1048576;
  for (int t = 0; t < 32; ++t) {
    lstm_step<<<dim3(16, 4, 2), 256, 0, stream>>>(
        t, xwF, xwB, WhF, WhB, zslab, cF, cB, hsF, hsB);
  }

  fc_logsoftmax<<<2048, 128, 0, stream>>>(hsF, hsB, fcW, fcb, (float*)d_out);
}

// Round 2
// 1195.476 us; speedup vs baseline: 6.5087x; 6.5087x over previous
//
#include <hip/hip_runtime.h>
#include <hip/hip_bf16.h>
#include <math.h>

#define EPSBN 1e-5f

using short8 = __attribute__((ext_vector_type(8))) short;
using f32x4  = __attribute__((ext_vector_type(4))) float;
using us4    = __attribute__((ext_vector_type(4))) unsigned short;

#define MFMA16(a, b, c) __builtin_amdgcn_mfma_f32_16x16x32_bf16(a, b, c, 0, 0, 0)

__device__ __forceinline__ float bf2f(unsigned short u) {
  unsigned int v = ((unsigned int)u) << 16;
  float f;
  __builtin_memcpy(&f, &v, 4);
  return f;
}
__device__ __forceinline__ unsigned short f2bf(float f) {
  __hip_bfloat16 h = __float2bfloat16(f);
  unsigned short u;
  __builtin_memcpy(&u, &h, 2);
  return u;
}

// ---------------- conv1: direct fp32 (CIN=1), bf16 out ----------------
template<int CIN, int COUT, int COB, int PX>
__global__ __launch_bounds__(256) void conv_bn_relu_f32(
    const float* __restrict__ in, const float* __restrict__ w,
    const float* __restrict__ bias, const float* __restrict__ sc,
    const float* __restrict__ of, const float* __restrict__ mn,
    const float* __restrict__ vr, unsigned short* __restrict__ out, int H, int W) {
  int tid = threadIdx.x;
  int col = tid % COB;
  int px  = tid / COB;
  int co  = blockIdx.y * COB + col;
  long p  = (long)blockIdx.x * PX + px;
  long hw = (long)H * W;
  int b = (int)(p / hw);
  long rem = p - (long)b * hw;
  int y = (int)(rem / W);
  int x = (int)(rem % W);
  float scale = sc[co] * rsqrtf(vr[co] + EPSBN);
  float shift = of[co] - mn[co] * scale;
  float acc = bias[co];
  #pragma unroll
  for (int dy = 0; dy < 3; ++dy) {
    int iy = y + dy - 1;
    if ((unsigned)iy >= (unsigned)H) continue;
    #pragma unroll
    for (int dx = 0; dx < 3; ++dx) {
      int ix = x + dx - 1;
      if ((unsigned)ix >= (unsigned)W) continue;
      const float* ip = in + ((long)(b * H + iy) * W + ix) * CIN;
      const float* wp = w + (long)((dy * 3 + dx) * CIN) * COUT + co;
      #pragma unroll
      for (int ci = 0; ci < CIN; ++ci)
        acc = fmaf(ip[ci], wp[(long)ci * COUT], acc);
    }
  }
  acc = fmaxf(acc, 0.f);
  out[p * COUT + co] = f2bf(acc * scale + shift);
}

// ---------------- 2x2 maxpool stride 2 on bf16 ----------------
__global__ __launch_bounds__(256) void maxpool2_bf16(
    const unsigned short* __restrict__ in, unsigned short* __restrict__ out,
    int H, int W, int C, long total) {
  long i = (long)blockIdx.x * 256 + threadIdx.x;
  if (i >= total) return;
  int W2 = W >> 1, H2 = H >> 1;
  int c = (int)(i % C);
  long r = i / C;
  int x = (int)(r % W2); r /= W2;
  int y = (int)(r % H2);
  int b = (int)(r / H2);
  const unsigned short* p0 = in + ((long)(b * H + 2 * y) * W + 2 * x) * C + c;
  long rs = (long)W * C;
  unsigned short u0 = p0[0], u1 = p0[C], u2 = p0[rs], u3 = p0[rs + C];
  unsigned short a = (bf2f(u0) >= bf2f(u1)) ? u0 : u1;
  unsigned short bmx = (bf2f(u2) >= bf2f(u3)) ? u2 : u3;
  out[i] = (bf2f(a) >= bf2f(bmx)) ? a : bmx;
}

// ---------------- generic transpose: fp32 [K][N] -> bf16 [N][K] ----------------
__global__ __launch_bounds__(256) void transpose_f32_bf16(
    const float* __restrict__ in, unsigned short* __restrict__ out, int K, int N) {
  __shared__ float T[32][33];
  int k0 = blockIdx.x * 32, n0 = blockIdx.y * 32;
  int tid = threadIdx.x;
  int r = tid >> 3, c4 = (tid & 7) * 4;
  float4 v = *(const float4*)(in + (long)(k0 + r) * N + n0 + c4);
  T[r][c4 + 0] = v.x; T[r][c4 + 1] = v.y; T[r][c4 + 2] = v.z; T[r][c4 + 3] = v.w;
  __syncthreads();
  us4 o;
  #pragma unroll
  for (int i = 0; i < 4; ++i) o[i] = f2bf(T[c4 + i][r]);
  *(us4*)(out + (long)(n0 + r) * K + k0 + c4) = o;
}

// ---------------- MFMA implicit-GEMM conv 3x3 SAME + bias+relu+BN ----------------
// A[m][k]: m = pixel (b,y,x), k = tap*CIN + ci, zero-padded borders.
// B rows = wT[cout][k] (pre-transposed bf16). Tile 64x64, BK=32, 4 waves 2x2.
template<int CIN, int COUT>
__global__ __launch_bounds__(256) void conv_mfma(
    const unsigned short* __restrict__ act, const unsigned short* __restrict__ wT,
    const float* __restrict__ bias, const float* __restrict__ sc,
    const float* __restrict__ of, const float* __restrict__ mn,
    const float* __restrict__ vr, unsigned short* __restrict__ out,
    int H, int W) {
  constexpr int K9 = 9 * CIN;
  __shared__ unsigned short As[4][64][8];
  __shared__ unsigned short Bs[4][64][8];
  const int tid = threadIdx.x;
  const int m0 = blockIdx.x * 64;
  const int n0 = blockIdx.y * 64;
  const int srow = tid >> 2, sseg = tid & 3;
  const int m = m0 + srow;
  const int HW = H * W;
  const int bb = m / HW;
  const int rem = m % HW;
  const int y = rem / W, x = rem % W;
  const int lane = tid & 63, wave = tid >> 6;
  const int msub = (wave >> 1) * 32, nsub = (wave & 1) * 32;
  const unsigned short* browp = wT + (long)(n0 + srow) * K9 + sseg * 8;
  f32x4 acc[2][2] = {};

  for (int k0 = 0; k0 < K9; k0 += 32) {
    const int tap = k0 / CIN;
    const int ci = k0 - tap * CIN + sseg * 8;
    const int iy = y + tap / 3 - 1;
    const int ix = x + tap % 3 - 1;
    short8 aval = {};
    if ((unsigned)iy < (unsigned)H && (unsigned)ix < (unsigned)W)
      aval = *(const short8*)(act + ((long)(bb * H + iy) * W + ix) * CIN + ci);
    short8 bval = *(const short8*)(browp + k0);
    __syncthreads();
    *(short8*)&As[sseg][srow][0] = aval;
    *(short8*)&Bs[sseg][srow][0] = bval;
    __syncthreads();
    short8 a0 = *(const short8*)&As[lane >> 4][msub + (lane & 15)][0];
    short8 a1 = *(const short8*)&As[lane >> 4][msub + 16 + (lane & 15)][0];
    short8 b0 = *(const short8*)&Bs[lane >> 4][nsub + (lane & 15)][0];
    short8 b1 = *(const short8*)&Bs[lane >> 4][nsub + 16 + (lane & 15)][0];
    acc[0][0] = MFMA16(a0, b0, acc[0][0]);
    acc[0][1] = MFMA16(a0, b1, acc[0][1]);
    acc[1][0] = MFMA16(a1, b0, acc[1][0]);
    acc[1][1] = MFMA16(a1, b1, acc[1][1]);
  }

  #pragma unroll
  for (int j = 0; j < 2; ++j) {
    const int col = n0 + nsub + j * 16 + (lane & 15);
    const float scale = sc[col] * rsqrtf(vr[col] + EPSBN);
    const float shift = of[col] - mn[col] * scale;
    const float bs = bias[col];
    #pragma unroll
    for (int i = 0; i < 2; ++i) {
      #pragma unroll
      for (int r = 0; r < 4; ++r) {
        const int row = m0 + msub + i * 16 + (lane >> 4) * 4 + r;
        const float v = fmaxf(acc[i][j][r] + bs, 0.f) * scale + shift;
        out[(long)row * COUT + col] = f2bf(v);
      }
    }
  }
}

// ---------------- MFMA GEMM: xw = gather(x_seq) @ WiT^T + b ----------------
// M=2048 (r = t*64+b), N=2048, K=2048. A row: src[b*65536 + tt*2048 + k] (bf16).
__global__ __launch_bounds__(256) void gemm_xw_mfma(
    const unsigned short* __restrict__ src, const unsigned short* __restrict__ WiT,
    const float* __restrict__ bvec, float* __restrict__ xw, int rev) {
  __shared__ unsigned short As[4][64][8];
  __shared__ unsigned short Bs[4][64][8];
  const int tid = threadIdx.x;
  const int m0 = blockIdx.x * 64, n0 = blockIdx.y * 64;
  const int srow = tid >> 2, sseg = tid & 3;
  const int r = m0 + srow;
  const int tseq = r >> 6, bidx = r & 63;
  const int tt = rev ? 31 - tseq : tseq;
  const unsigned short* arow = src + (long)bidx * 65536 + (long)tt * 2048 + sseg * 8;
  const unsigned short* browp = WiT + (long)(n0 + srow) * 2048 + sseg * 8;
  const int lane = tid & 63, wave = tid >> 6;
  const int msub = (wave >> 1) * 32, nsub = (wave & 1) * 32;
  f32x4 acc[2][2] = {};

  for (int k0 = 0; k0 < 2048; k0 += 32) {
    short8 av = *(const short8*)(arow + k0);
    short8 bv = *(const short8*)(browp + k0);
    __syncthreads();
    *(short8*)&As[sseg][srow][0] = av;
    *(short8*)&Bs[sseg][srow][0] = bv;
    __syncthreads();
    short8 a0 = *(const short8*)&As[lane >> 4][msub + (lane & 15)][0];
    short8 a1 = *(const short8*)&As[lane >> 4][msub + 16 + (lane & 15)][0];
    short8 b0 = *(const short8*)&Bs[lane >> 4][nsub + (lane & 15)][0];
    short8 b1 = *(const short8*)&Bs[lane >> 4][nsub + 16 + (lane & 15)][0];
    acc[0][0] = MFMA16(a0, b0, acc[0][0]);
    acc[0][1] = MFMA16(a0, b1, acc[0][1]);
    acc[1][0] = MFMA16(a1, b0, acc[1][0]);
    acc[1][1] = MFMA16(a1, b1, acc[1][1]);
  }

  #pragma unroll
  for (int j = 0; j < 2; ++j) {
    const int col = n0 + nsub + j * 16 + (lane & 15);
    const float bs = bvec[col];
    #pragma unroll
    for (int i = 0; i < 2; ++i) {
      #pragma unroll
      for (int rr = 0; rr < 4; ++rr) {
        const int row = m0 + msub + i * 16 + (lane >> 4) * 4 + rr;
        xw[(long)row * 2048 + col] = acc[i][j][rr] + bs;
      }
    }
  }
}

// ---------------- one LSTM step (both directions), fp32 ----------------
__global__ __launch_bounds__(256) void lstm_step(
    int t,
    const float* __restrict__ xwF, const float* __restrict__ xwB,
    const float* __restrict__ WhF, const float* __restrict__ WhB,
    const float* __restrict__ zslab,
    float* __restrict__ cF, float* __restrict__ cB,
    float* __restrict__ hsF, float* __restrict__ hsB) {
  const int dir = blockIdx.z;
  const float* xw = dir ? xwB : xwF;
  const float* Wh = dir ? WhB : WhF;
  float* cst = dir ? cB : cF;
  float* hs  = dir ? hsB : hsF;
  const float* hprev = (t == 0) ? zslab : (hs + (long)(t - 1) * 64 * 512);

  const int u0 = blockIdx.x * 32;
  const int b0 = blockIdx.y * 16;
  __shared__ float Hs[16][512];
  __shared__ float Ws[32][128];
  __shared__ float Zs[16][128];
  const int tid = threadIdx.x;

  {
    int r = tid >> 4;
    int cbase = (tid & 15) << 5;
    const float* hp = hprev + (long)(b0 + r) * 512 + cbase;
    #pragma unroll
    for (int i = 0; i < 32; i += 4)
      *(float4*)&Hs[r][cbase + i] = *(const float4*)(hp + i);
  }

  const int jq = tid & 31;
  const int br = tid >> 5;
  const int g  = (jq * 4) >> 5;
  const int uu = (jq * 4) & 31;
  const int wcol = g * 512 + u0 + uu;
  float acc[2][4] = {};

  for (int k0 = 0; k0 < 512; k0 += 32) {
    __syncthreads();
    {
      int kk = tid >> 3;
      int sub = tid & 7;
      int gch = sub >> 1, half = sub & 1;
      const float* wp = Wh + (long)(k0 + kk) * 2048 + gch * 512 + u0 + half * 16;
      #pragma unroll
      for (int i = 0; i < 16; i += 4)
        *(float4*)&Ws[kk][sub * 16 + i] = *(const float4*)(wp + i);
    }
    __syncthreads();
    #pragma unroll
    for (int kk = 0; kk < 32; ++kk) {
      float h0 = Hs[br * 2 + 0][k0 + kk];
      float h1 = Hs[br * 2 + 1][k0 + kk];
      float4 w4 = *(const float4*)&Ws[kk][jq * 4];
      acc[0][0] = fmaf(h0, w4.x, acc[0][0]);
      acc[0][1] = fmaf(h0, w4.y, acc[0][1]);
      acc[0][2] = fmaf(h0, w4.z, acc[0][2]);
      acc[0][3] = fmaf(h0, w4.w, acc[0][3]);
      acc[1][0] = fmaf(h1, w4.x, acc[1][0]);
      acc[1][1] = fmaf(h1, w4.y, acc[1][1]);
      acc[1][2] = fmaf(h1, w4.z, acc[1][2]);
      acc[1][3] = fmaf(h1, w4.w, acc[1][3]);
    }
  }

  #pragma unroll
  for (int i = 0; i < 2; ++i) {
    int brow = b0 + br * 2 + i;
    const float* xp = xw + (long)(t * 64 + brow) * 2048 + wcol;
    #pragma unroll
    for (int j = 0; j < 4; ++j)
      Zs[br * 2 + i][jq * 4 + j] = acc[i][j] + xp[j];
  }
  __syncthreads();

  for (int p = tid; p < 512; p += 256) {
    int b = p >> 5, u = p & 31;
    float zi = Zs[b][u];
    float zf = Zs[b][32 + u];
    float zg = Zs[b][64 + u];
    float zo = Zs[b][96 + u];
    long cidx = (long)(b0 + b) * 512 + u0 + u;
    float c_old = cst[cidx];
    float ii = 1.f / (1.f + expf(-zi));
    float ff = 1.f / (1.f + expf(-zf));
    float gg = tanhf(zg);
    float oo = 1.f / (1.f + expf(-zo));
    float cn = ff * c_old + ii * gg;
    float hn = oo * tanhf(cn);
    cst[cidx] = cn;
    hs[((long)t * 64 + b0 + b) * 512 + u0 + u] = hn;
  }
}

// ---------------- FC + log_softmax ----------------
__global__ __launch_bounds__(128) void fc_logsoftmax(
    const float* __restrict__ hsF, const float* __restrict__ hsB,
    const float* __restrict__ W, const float* __restrict__ bias,
    float* __restrict__ out) {
  int bt = blockIdx.x;
  int b = bt >> 5, t = bt & 31;
  __shared__ float vbuf[1024];
  __shared__ float sl[80];
  __shared__ float red[2];
  int tid = threadIdx.x;
  const float* fv = hsF + ((long)t * 64 + b) * 512;
  const float* bv = hsB + ((long)t * 64 + b) * 512;
  for (int i = tid; i < 512; i += 128) vbuf[i] = fv[i];
  for (int i = tid; i < 512; i += 128) vbuf[512 + i] = bv[i];
  __syncthreads();
  if (tid < 80) {
    float acc = bias[tid];
    for (int k = 0; k < 1024; ++k)
      acc = fmaf(vbuf[k], W[(long)k * 80 + tid], acc);
    sl[tid] = acc;
  }
  __syncthreads();
  if (tid == 0) {
    float mx = -1e30f;
    for (int j = 0; j < 80; ++j) mx = fmaxf(mx, sl[j]);
    float s = 0.f;
    for (int j = 0; j < 80; ++j) s += expf(sl[j] - mx);
    red[0] = mx;
    red[1] = logf(s);
  }
  __syncthreads();
  if (tid < 80)
    out[(long)bt * 80 + tid] = sl[tid] - red[0] - red[1];
}

__global__ __launch_bounds__(256) void zero_kernel(float* p, int n) {
  int i = blockIdx.x * 256 + threadIdx.x;
  if (i < n) p[i] = 0.f;
}

extern "C" void kernel_launch(void* const* d_in, const int* in_sizes, int n_in,
                              void* d_out, int out_size, void* d_ws, size_t ws_size,
                              hipStream_t stream) {
  const float* x  = (const float*)d_in[0];
  const float* k1 = (const float*)d_in[1];  const float* b1 = (const float*)d_in[2];
  const float* s1 = (const float*)d_in[3];  const float* o1 = (const float*)d_in[4];
  const float* m1 = (const float*)d_in[5];  const float* v1 = (const float*)d_in[6];
  const float* k2 = (const float*)d_in[7];  const float* b2 = (const float*)d_in[8];
  const float* s2 = (const float*)d_in[9];  const float* o2 = (const float*)d_in[10];
  const float* m2 = (const float*)d_in[11]; const float* v2 = (const float*)d_in[12];
  const float* k3 = (const float*)d_in[13]; const float* b3 = (const float*)d_in[14];
  const float* s3 = (const float*)d_in[15]; const float* o3 = (const float*)d_in[16];
  const float* m3 = (const float*)d_in[17]; const float* v3 = (const float*)d_in[18];
  const float* k4 = (const float*)d_in[19]; const float* b4 = (const float*)d_in[20];
  const float* s4 = (const float*)d_in[21]; const float* o4 = (const float*)d_in[22];
  const float* m4 = (const float*)d_in[23]; const float* v4 = (const float*)d_in[24];
  const float* k5 = (const float*)d_in[25]; const float* b5 = (const float*)d_in[26];
  const float* s5 = (const float*)d_in[27]; const float* o5 = (const float*)d_in[28];
  const float* m5 = (const float*)d_in[29]; const float* v5 = (const float*)d_in[30];
  const float* fwWi = (const float*)d_in[31];
  const float* fwWh = (const float*)d_in[32];
  const float* fwb  = (const float*)d_in[33];
  const float* bwWi = (const float*)d_in[34];
  const float* bwWh = (const float*)d_in[35];
  const float* bwb  = (const float*)d_in[36];
  const float* fcW  = (const float*)d_in[37];
  const float* fcb  = (const float*)d_in[38];

  char* wsb = (char*)d_ws;
  unsigned short* A_act = (unsigned short*)(wsb);                 // 33.5M el bf16
  unsigned short* B_act = (unsigned short*)(wsb + 67108864);      // 16.8M el bf16
  unsigned short* wT    = (unsigned short*)(wsb + 100663296);     // 1.18M el bf16
  unsigned short* WiTF  = (unsigned short*)(wsb + 103022592);     // 4.19M el bf16
  unsigned short* WiTB  = (unsigned short*)(wsb + 111411200);     // 4.19M el bf16
  float* xwF = (float*)(wsb + 119799808);                         // 4.19M f32
  float* xwB = (float*)(wsb + 136577024);                         // 4.19M f32
  float* S   = (float*)(wsb + 153354240);
  float* cF = S;
  float* cB = S + 32768;
  float* zslab = S + 65536;
  float* hsF = S + 98304;              // [32][64][512]
  float* hsB = hsF + 1048576;

  zero_kernel<<<384, 256, 0, stream>>>(S, 98304);

  // conv1: x [64,32,256,1] -> A_act bf16 [64,32,256,64]
  conv_bn_relu_f32<1, 64, 64, 4><<<dim3(131072), 256, 0, stream>>>(
      x, k1, b1, s1, o1, m1, v1, A_act, 32, 256);
  maxpool2_bf16<<<(8388608 + 255) / 256, 256, 0, stream>>>(A_act, B_act, 32, 256, 64, 8388608);

  // conv2: B [64,16,128,64] -> A [.,128]
  transpose_f32_bf16<<<dim3(18, 4), 256, 0, stream>>>(k2, wT, 576, 128);
  conv_mfma<64, 128><<<dim3(2048, 2), 256, 0, stream>>>(
      B_act, wT, b2, s2, o2, m2, v2, A_act, 16, 128);
  maxpool2_bf16<<<(4194304 + 255) / 256, 256, 0, stream>>>(A_act, B_act, 16, 128, 128, 4194304);

  // conv3: B [64,8,64,128] -> A [.,256]
  transpose_f32_bf16<<<dim3(36, 8), 256, 0, stream>>>(k3, wT, 1152, 256);
  conv_mfma<128, 256><<<dim3(512, 4), 256, 0, stream>>>(
      B_act, wT, b3, s3, o3, m3, v3, A_act, 8, 64);
  maxpool2_bf16<<<(2097152 + 255) / 256, 256, 0, stream>>>(A_act, B_act, 8, 64, 256, 2097152);

  // conv4: B [64,4,32,256] -> A [.,256]
  transpose_f32_bf16<<<dim3(72, 8), 256, 0, stream>>>(k4, wT, 2304, 256);
  conv_mfma<256, 256><<<dim3(128, 4), 256, 0, stream>>>(
      B_act, wT, b4, s4, o4, m4, v4, A_act, 4, 32);

  // conv5: A [64,4,32,256] -> B [.,512]
  transpose_f32_bf16<<<dim3(72, 16), 256, 0, stream>>>(k5, wT, 2304, 512);
  conv_mfma<256, 512><<<dim3(128, 8), 256, 0, stream>>>(
      A_act, wT, b5, s5, o5, m5, v5, B_act, 4, 32);

  // xw precompute (layer 1 only — reference keeps only last layer)
  transpose_f32_bf16<<<dim3(64, 64), 256, 0, stream>>>(fwWi + 4194304, WiTF, 2048, 2048);
  transpose_f32_bf16<<<dim3(64, 64), 256, 0, stream>>>(bwWi + 4194304, WiTB, 2048, 2048);
  gemm_xw_mfma<<<dim3(32, 32), 256, 0, stream>>>(B_act, WiTF, fwb + 2048, xwF, 0);
  gemm_xw_mfma<<<dim3(32, 32), 256, 0, stream>>>(B_act, WiTB, bwb + 2048, xwB, 1);

  const float* WhF = fwWh + 1048576;
  const float* WhB = bwWh + 1048576;
  for (int t = 0; t < 32; ++t) {
    lstm_step<<<dim3(16, 4, 2), 256, 0, stream>>>(
        t, xwF, xwB, WhF, WhB, zslab, cF, cB, hsF, hsB);
  }

  fc_logsoftmax<<<2048, 128, 0, stream>>>(hsF, hsB, fcW, fcb, (float*)d_out);
}

// Round 3
// 700.955 us; speedup vs baseline: 11.1006x; 1.7055x over previous
//
#include <hip/hip_runtime.h>
#include <hip/hip_bf16.h>
#include <math.h>

#define EPSBN 1e-5f

using short8 = __attribute__((ext_vector_type(8))) short;
using f32x4  = __attribute__((ext_vector_type(4))) float;
using us4    = __attribute__((ext_vector_type(4))) unsigned short;

#define MFMA16(a, b, c) __builtin_amdgcn_mfma_f32_16x16x32_bf16(a, b, c, 0, 0, 0)

__device__ __forceinline__ float bf2f(unsigned short u) {
  unsigned int v = ((unsigned int)u) << 16;
  float f;
  __builtin_memcpy(&f, &v, 4);
  return f;
}
__device__ __forceinline__ unsigned short f2bf(float f) {
  __hip_bfloat16 h = __float2bfloat16(f);
  unsigned short u;
  __builtin_memcpy(&u, &h, 2);
  return u;
}
__device__ __forceinline__ float fast_sigmoid(float z) {
  return __builtin_amdgcn_rcpf(1.f + __expf(-z));
}
__device__ __forceinline__ float fast_tanh(float z) {
  float x2 = fminf(fmaxf(2.f * z, -30.f), 30.f);
  float e = __expf(x2);
  return (e - 1.f) * __builtin_amdgcn_rcpf(e + 1.f);
}

// ---------------- conv1: direct, H=32 W=256 CIN=1 COUT=64, LDS row staging ----------------
__global__ __launch_bounds__(256) void conv1_direct(
    const float* __restrict__ in, const float* __restrict__ w,
    const float* __restrict__ bias, const float* __restrict__ sc,
    const float* __restrict__ of, const float* __restrict__ mn,
    const float* __restrict__ vr, unsigned short* __restrict__ out) {
  __shared__ float lds[3][260];
  const int blk = blockIdx.x;          // 0..2047 = b*32 + y
  const int b = blk >> 5, y = blk & 31;
  const int tid = threadIdx.x;
  for (int i = tid; i < 780; i += 256) {
    int row = i / 260, c = i - row * 260;
    int iy = y + row - 1, xx = c - 1;
    float v = 0.f;
    if ((unsigned)iy < 32u && (unsigned)xx < 256u)
      v = in[((b << 5) + iy) * 256 + xx];
    lds[row][c] = v;
  }
  __syncthreads();
  const int co = tid & 63, xg = tid >> 6;
  float w9[9];
  #pragma unroll
  for (int t = 0; t < 9; ++t) w9[t] = w[t * 64 + co];
  const float scale = sc[co] * rsqrtf(vr[co] + EPSBN);
  const float shift = of[co] - mn[co] * scale;
  const float bs = bias[co];
  const int x0 = xg * 64;
  float a0 = lds[0][x0],     a1 = lds[1][x0],     a2 = lds[2][x0];
  float b0 = lds[0][x0 + 1], b1 = lds[1][x0 + 1], b2 = lds[2][x0 + 1];
  unsigned short* op = out + (((long)blk * 256 + x0) << 6) + co;
  #pragma unroll 4
  for (int i = 0; i < 64; ++i) {
    float c0 = lds[0][x0 + i + 2], c1 = lds[1][x0 + i + 2], c2 = lds[2][x0 + i + 2];
    float acc = bs;
    acc = fmaf(a0, w9[0], acc); acc = fmaf(a1, w9[3], acc); acc = fmaf(a2, w9[6], acc);
    acc = fmaf(b0, w9[1], acc); acc = fmaf(b1, w9[4], acc); acc = fmaf(b2, w9[7], acc);
    acc = fmaf(c0, w9[2], acc); acc = fmaf(c1, w9[5], acc); acc = fmaf(c2, w9[8], acc);
    acc = fmaxf(acc, 0.f) * scale + shift;
    op[(long)i << 6] = f2bf(acc);
    a0 = b0; a1 = b1; a2 = b2; b0 = c0; b1 = c1; b2 = c2;
  }
}

// ---------------- 2x2 maxpool stride 2 on bf16 ----------------
__global__ __launch_bounds__(256) void maxpool2_bf16(
    const unsigned short* __restrict__ in, unsigned short* __restrict__ out,
    int H, int W, int C, long total) {
  long i = (long)blockIdx.x * 256 + threadIdx.x;
  if (i >= total) return;
  int W2 = W >> 1, H2 = H >> 1;
  int c = (int)(i % C);
  long r = i / C;
  int x = (int)(r % W2); r /= W2;
  int y = (int)(r % H2);
  int b = (int)(r / H2);
  const unsigned short* p0 = in + ((long)(b * H + 2 * y) * W + 2 * x) * C + c;
  long rs = (long)W * C;
  unsigned short u0 = p0[0], u1 = p0[C], u2 = p0[rs], u3 = p0[rs + C];
  unsigned short a = (bf2f(u0) >= bf2f(u1)) ? u0 : u1;
  unsigned short bmx = (bf2f(u2) >= bf2f(u3)) ? u2 : u3;
  out[i] = (bf2f(a) >= bf2f(bmx)) ? a : bmx;
}

// ---------------- generic transpose: fp32 [K][N] -> bf16 [N][K] ----------------
__global__ __launch_bounds__(256) void transpose_f32_bf16(
    const float* __restrict__ in, unsigned short* __restrict__ out, int K, int N) {
  __shared__ float T[32][33];
  int k0 = blockIdx.x * 32, n0 = blockIdx.y * 32;
  int tid = threadIdx.x;
  int r = tid >> 3, c4 = (tid & 7) * 4;
  float4 v = *(const float4*)(in + (long)(k0 + r) * N + n0 + c4);
  T[r][c4 + 0] = v.x; T[r][c4 + 1] = v.y; T[r][c4 + 2] = v.z; T[r][c4 + 3] = v.w;
  __syncthreads();
  us4 o;
  #pragma unroll
  for (int i = 0; i < 4; ++i) o[i] = f2bf(T[c4 + i][r]);
  *(us4*)(out + (long)(n0 + r) * K + k0 + c4) = o;
}

// ---------------- MFMA implicit-GEMM conv 3x3 SAME + bias+relu+BN ----------------
template<int CIN, int COUT>
__global__ __launch_bounds__(256) void conv_mfma(
    const unsigned short* __restrict__ act, const unsigned short* __restrict__ wT,
    const float* __restrict__ bias, const float* __restrict__ sc,
    const float* __restrict__ of, const float* __restrict__ mn,
    const float* __restrict__ vr, unsigned short* __restrict__ out,
    int H, int W) {
  constexpr int K9 = 9 * CIN;
  __shared__ unsigned short As[4][64][8];
  __shared__ unsigned short Bs[4][64][8];
  const int tid = threadIdx.x;
  const int m0 = blockIdx.x * 64;
  const int n0 = blockIdx.y * 64;
  const int srow = tid >> 2, sseg = tid & 3;
  const int m = m0 + srow;
  const int HW = H * W;
  const int bb = m / HW;
  const int rem = m % HW;
  const int y = rem / W, x = rem % W;
  const int lane = tid & 63, wave = tid >> 6;
  const int msub = (wave >> 1) * 32, nsub = (wave & 1) * 32;
  const unsigned short* browp = wT + (long)(n0 + srow) * K9 + sseg * 8;
  f32x4 acc[2][2] = {};

  for (int k0 = 0; k0 < K9; k0 += 32) {
    const int tap = k0 / CIN;
    const int ci = k0 - tap * CIN + sseg * 8;
    const int iy = y + tap / 3 - 1;
    const int ix = x + tap % 3 - 1;
    short8 aval = {};
    if ((unsigned)iy < (unsigned)H && (unsigned)ix < (unsigned)W)
      aval = *(const short8*)(act + ((long)(bb * H + iy) * W + ix) * CIN + ci);
    short8 bval = *(const short8*)(browp + k0);
    __syncthreads();
    *(short8*)&As[sseg][srow][0] = aval;
    *(short8*)&Bs[sseg][srow][0] = bval;
    __syncthreads();
    short8 a0 = *(const short8*)&As[lane >> 4][msub + (lane & 15)][0];
    short8 a1 = *(const short8*)&As[lane >> 4][msub + 16 + (lane & 15)][0];
    short8 b0 = *(const short8*)&Bs[lane >> 4][nsub + (lane & 15)][0];
    short8 b1 = *(const short8*)&Bs[lane >> 4][nsub + 16 + (lane & 15)][0];
    acc[0][0] = MFMA16(a0, b0, acc[0][0]);
    acc[0][1] = MFMA16(a0, b1, acc[0][1]);
    acc[1][0] = MFMA16(a1, b0, acc[1][0]);
    acc[1][1] = MFMA16(a1, b1, acc[1][1]);
  }

  #pragma unroll
  for (int j = 0; j < 2; ++j) {
    const int col = n0 + nsub + j * 16 + (lane & 15);
    const float scale = sc[col] * rsqrtf(vr[col] + EPSBN);
    const float shift = of[col] - mn[col] * scale;
    const float bs = bias[col];
    #pragma unroll
    for (int i = 0; i < 2; ++i) {
      #pragma unroll
      for (int r = 0; r < 4; ++r) {
        const int row = m0 + msub + i * 16 + (lane >> 4) * 4 + r;
        const float v = fmaxf(acc[i][j][r] + bs, 0.f) * scale + shift;
        out[(long)row * COUT + col] = f2bf(v);
      }
    }
  }
}

// ---------------- MFMA GEMM: xw = gather(x_seq) @ WiT^T + b ----------------
__global__ __launch_bounds__(256) void gemm_xw_mfma(
    const unsigned short* __restrict__ src, const unsigned short* __restrict__ WiT,
    const float* __restrict__ bvec, float* __restrict__ xw, int rev) {
  __shared__ unsigned short As[4][64][8];
  __shared__ unsigned short Bs[4][64][8];
  const int tid = threadIdx.x;
  const int m0 = blockIdx.x * 64, n0 = blockIdx.y * 64;
  const int srow = tid >> 2, sseg = tid & 3;
  const int r = m0 + srow;
  const int tseq = r >> 6, bidx = r & 63;
  const int tt = rev ? 31 - tseq : tseq;
  const unsigned short* arow = src + (long)bidx * 65536 + (long)tt * 2048 + sseg * 8;
  const unsigned short* browp = WiT + (long)(n0 + srow) * 2048 + sseg * 8;
  const int lane = tid & 63, wave = tid >> 6;
  const int msub = (wave >> 1) * 32, nsub = (wave & 1) * 32;
  f32x4 acc[2][2] = {};

  for (int k0 = 0; k0 < 2048; k0 += 32) {
    short8 av = *(const short8*)(arow + k0);
    short8 bv = *(const short8*)(browp + k0);
    __syncthreads();
    *(short8*)&As[sseg][srow][0] = av;
    *(short8*)&Bs[sseg][srow][0] = bv;
    __syncthreads();
    short8 a0 = *(const short8*)&As[lane >> 4][msub + (lane & 15)][0];
    short8 a1 = *(const short8*)&As[lane >> 4][msub + 16 + (lane & 15)][0];
    short8 b0 = *(const short8*)&Bs[lane >> 4][nsub + (lane & 15)][0];
    short8 b1 = *(const short8*)&Bs[lane >> 4][nsub + 16 + (lane & 15)][0];
    acc[0][0] = MFMA16(a0, b0, acc[0][0]);
    acc[0][1] = MFMA16(a0, b1, acc[0][1]);
    acc[1][0] = MFMA16(a1, b0, acc[1][0]);
    acc[1][1] = MFMA16(a1, b1, acc[1][1]);
  }

  #pragma unroll
  for (int j = 0; j < 2; ++j) {
    const int col = n0 + nsub + j * 16 + (lane & 15);
    const float bs = bvec[col];
    #pragma unroll
    for (int i = 0; i < 2; ++i) {
      #pragma unroll
      for (int rr = 0; rr < 4; ++rr) {
        const int row = m0 + msub + i * 16 + (lane >> 4) * 4 + rr;
        xw[(long)row * 2048 + col] = acc[i][j][rr] + bs;
      }
    }
  }
}

// ---------------- persistent bidirectional LSTM (all 32 steps, one launch) ----------------
// grid 64 blocks x 256 threads: dir = bid>>5, u-tile = (bid&31)*16.
// z = hprev(bf16) @ WhT(bf16) via MFMA; c lives in registers; grid barrier per step.
__global__ __launch_bounds__(256) void lstm_persist(
    const unsigned short* __restrict__ WhTF, const unsigned short* __restrict__ WhTB,
    const float* __restrict__ xwF, const float* __restrict__ xwB,
    unsigned short* __restrict__ hsF, unsigned short* __restrict__ hsB,
    int* __restrict__ bar) {
  const int bid = blockIdx.x;
  const int dir = bid >> 5;
  const int u0 = (bid & 31) * 16;
  const unsigned short* WhT = dir ? WhTB : WhTF;
  const float* xw = dir ? xwB : xwF;
  unsigned short* hs = dir ? hsB : hsF;
  const int tid = threadIdx.x;
  const int lane = tid & 63, wave = tid >> 6;
  const int m0 = wave * 16;
  const int lr = lane & 15;
  const int lk = lane >> 4;

  const unsigned short* brow0 = WhT + (long)(0 * 512 + u0 + lr) * 512 + lk * 8;
  const unsigned short* brow1 = WhT + (long)(1 * 512 + u0 + lr) * 512 + lk * 8;
  const unsigned short* brow2 = WhT + (long)(2 * 512 + u0 + lr) * 512 + lk * 8;
  const unsigned short* brow3 = WhT + (long)(3 * 512 + u0 + lr) * 512 + lk * 8;

  float creg[4] = {0.f, 0.f, 0.f, 0.f};

  #pragma unroll 1
  for (int t = 0; t < 32; ++t) {
    const unsigned short* hp = hs + (long)t * 32768 + (long)(m0 + lr) * 512 + lk * 8;
    f32x4 acc0 = {}, acc1 = {}, acc2 = {}, acc3 = {};
    #pragma unroll
    for (int kk = 0; kk < 16; ++kk) {
      short8 a = *(const short8*)(hp + kk * 32);
      acc0 = MFMA16(a, *(const short8*)(brow0 + kk * 32), acc0);
      acc1 = MFMA16(a, *(const short8*)(brow1 + kk * 32), acc1);
      acc2 = MFMA16(a, *(const short8*)(brow2 + kk * 32), acc2);
      acc3 = MFMA16(a, *(const short8*)(brow3 + kk * 32), acc3);
    }
    #pragma unroll
    for (int r = 0; r < 4; ++r) {
      const int row = m0 + lk * 4 + r;
      const float* xr = xw + ((long)t * 64 + row) * 2048 + u0 + lr;
      float zi = acc0[r] + xr[0];
      float zf = acc1[r] + xr[512];
      float zg = acc2[r] + xr[1024];
      float zo = acc3[r] + xr[1536];
      float ii = fast_sigmoid(zi);
      float ff = fast_sigmoid(zf);
      float gg = fast_tanh(zg);
      float oo = fast_sigmoid(zo);
      creg[r] = ff * creg[r] + ii * gg;
      float hn = oo * fast_tanh(creg[r]);
      hs[(long)(t + 1) * 32768 + (long)row * 512 + u0 + lr] = f2bf(hn);
    }
    if (t < 31) {
      __syncthreads();
      if (tid == 0) {
        __threadfence();
        __hip_atomic_fetch_add(&bar[t], 1, __ATOMIC_RELEASE, __HIP_MEMORY_SCOPE_AGENT);
        while (__hip_atomic_load(&bar[t], __ATOMIC_ACQUIRE, __HIP_MEMORY_SCOPE_AGENT) < 64) {}
      }
      __syncthreads();
    }
  }
}

// ---------------- FC + log_softmax (bf16 h inputs) ----------------
__global__ __launch_bounds__(128) void fc_logsoftmax(
    const unsigned short* __restrict__ hsF, const unsigned short* __restrict__ hsB,
    const float* __restrict__ W, const float* __restrict__ bias,
    float* __restrict__ out) {
  int bt = blockIdx.x;
  int b = bt >> 5, t = bt & 31;
  __shared__ float vbuf[1024];
  __shared__ float sl[80];
  __shared__ float red[2];
  int tid = threadIdx.x;
  const unsigned short* fv = hsF + (long)(t + 1) * 32768 + (long)b * 512;
  const unsigned short* bv = hsB + (long)(t + 1) * 32768 + (long)b * 512;
  for (int i = tid; i < 512; i += 128) vbuf[i] = bf2f(fv[i]);
  for (int i = tid; i < 512; i += 128) vbuf[512 + i] = bf2f(bv[i]);
  __syncthreads();
  if (tid < 80) {
    float a0 = 0.f, a1 = 0.f, a2 = 0.f, a3 = 0.f;
    for (int k = 0; k < 1024; k += 4) {
      a0 = fmaf(vbuf[k + 0], W[(long)(k + 0) * 80 + tid], a0);
      a1 = fmaf(vbuf[k + 1], W[(long)(k + 1) * 80 + tid], a1);
      a2 = fmaf(vbuf[k + 2], W[(long)(k + 2) * 80 + tid], a2);
      a3 = fmaf(vbuf[k + 3], W[(long)(k + 3) * 80 + tid], a3);
    }
    sl[tid] = bias[tid] + ((a0 + a1) + (a2 + a3));
  }
  __syncthreads();
  if (tid == 0) {
    float mx = -1e30f;
    for (int j = 0; j < 80; ++j) mx = fmaxf(mx, sl[j]);
    float s = 0.f;
    for (int j = 0; j < 80; ++j) s += expf(sl[j] - mx);
    red[0] = mx;
    red[1] = logf(s);
  }
  __syncthreads();
  if (tid < 80)
    out[(long)bt * 80 + tid] = sl[tid] - red[0] - red[1];
}

__global__ __launch_bounds__(256) void zero_kernel(float* p, int n) {
  int i = blockIdx.x * 256 + threadIdx.x;
  if (i < n) p[i] = 0.f;
}

extern "C" void kernel_launch(void* const* d_in, const int* in_sizes, int n_in,
                              void* d_out, int out_size, void* d_ws, size_t ws_size,
                              hipStream_t stream) {
  const float* x  = (const float*)d_in[0];
  const float* k1 = (const float*)d_in[1];  const float* b1 = (const float*)d_in[2];
  const float* s1 = (const float*)d_in[3];  const float* o1 = (const float*)d_in[4];
  const float* m1 = (const float*)d_in[5];  const float* v1 = (const float*)d_in[6];
  const float* k2 = (const float*)d_in[7];  const float* b2 = (const float*)d_in[8];
  const float* s2 = (const float*)d_in[9];  const float* o2 = (const float*)d_in[10];
  const float* m2 = (const float*)d_in[11]; const float* v2 = (const float*)d_in[12];
  const float* k3 = (const float*)d_in[13]; const float* b3 = (const float*)d_in[14];
  const float* s3 = (const float*)d_in[15]; const float* o3 = (const float*)d_in[16];
  const float* m3 = (const float*)d_in[17]; const float* v3 = (const float*)d_in[18];
  const float* k4 = (const float*)d_in[19]; const float* b4 = (const float*)d_in[20];
  const float* s4 = (const float*)d_in[21]; const float* o4 = (const float*)d_in[22];
  const float* m4 = (const float*)d_in[23]; const float* v4 = (const float*)d_in[24];
  const float* k5 = (const float*)d_in[25]; const float* b5 = (const float*)d_in[26];
  const float* s5 = (const float*)d_in[27]; const float* o5 = (const float*)d_in[28];
  const float* m5 = (const float*)d_in[29]; const float* v5 = (const float*)d_in[30];
  const float* fwWi = (const float*)d_in[31];
  const float* fwWh = (const float*)d_in[32];
  const float* fwb  = (const float*)d_in[33];
  const float* bwWi = (const float*)d_in[34];
  const float* bwWh = (const float*)d_in[35];
  const float* bwb  = (const float*)d_in[36];
  const float* fcW  = (const float*)d_in[37];
  const float* fcb  = (const float*)d_in[38];

  char* wsb = (char*)d_ws;
  unsigned short* A_act = (unsigned short*)(wsb);                  // 33.55M el
  unsigned short* B_act = (unsigned short*)(wsb + 67108864);       // 8.39M el
  unsigned short* wT    = (unsigned short*)(wsb + 83886080);       // conv wT
  unsigned short* WiTF  = (unsigned short*)(wsb + 86245376);
  unsigned short* WiTB  = (unsigned short*)(wsb + 94633984);
  unsigned short* WhTF  = (unsigned short*)(wsb + 103022592);      // [2048][512] bf16
  unsigned short* WhTB  = (unsigned short*)(wsb + 105119744);
  float* xwF = (float*)(wsb + 107216896);                          // [2048][2048] f32
  float* xwB = (float*)(wsb + 123994112);
  int*   bar = (int*)(wsb + 140771328);                            // 64 ints
  unsigned short* hsF = (unsigned short*)(wsb + 140771584);        // [33][64][512]
  unsigned short* hsB = (unsigned short*)(wsb + 142934272);

  // zero: bar + hsF slab0 (contiguous), hsB slab0
  zero_kernel<<<(16448 + 255) / 256, 256, 0, stream>>>((float*)(wsb + 140771328), 16448);
  zero_kernel<<<(16384 + 255) / 256, 256, 0, stream>>>((float*)(wsb + 142934272), 16384);

  // conv1: x [64,32,256,1] -> A_act bf16 [64,32,256,64]
  conv1_direct<<<2048, 256, 0, stream>>>(x, k1, b1, s1, o1, m1, v1, A_act);
  maxpool2_bf16<<<(8388608 + 255) / 256, 256, 0, stream>>>(A_act, B_act, 32, 256, 64, 8388608);

  // conv2: B [64,16,128,64] -> A [.,128]
  transpose_f32_bf16<<<dim3(18, 4), 256, 0, stream>>>(k2, wT, 576, 128);
  conv_mfma<64, 128><<<dim3(2048, 2), 256, 0, stream>>>(
      B_act, wT, b2, s2, o2, m2, v2, A_act, 16, 128);
  maxpool2_bf16<<<(4194304 + 255) / 256, 256, 0, stream>>>(A_act, B_act, 16, 128, 128, 4194304);

  // conv3: B [64,8,64,128] -> A [.,256]
  transpose_f32_bf16<<<dim3(36, 8), 256, 0, stream>>>(k3, wT, 1152, 256);
  conv_mfma<128, 256><<<dim3(512, 4), 256, 0, stream>>>(
      B_act, wT, b3, s3, o3, m3, v3, A_act, 8, 64);
  maxpool2_bf16<<<(2097152 + 255) / 256, 256, 0, stream>>>(A_act, B_act, 8, 64, 256, 2097152);

  // conv4: B [64,4,32,256] -> A [.,256]
  transpose_f32_bf16<<<dim3(72, 8), 256, 0, stream>>>(k4, wT, 2304, 256);
  conv_mfma<256, 256><<<dim3(128, 4), 256, 0, stream>>>(
      B_act, wT, b4, s4, o4, m4, v4, A_act, 4, 32);

  // conv5: A [64,4,32,256] -> B [.,512]
  transpose_f32_bf16<<<dim3(72, 16), 256, 0, stream>>>(k5, wT, 2304, 512);
  conv_mfma<256, 512><<<dim3(128, 8), 256, 0, stream>>>(
      A_act, wT, b5, s5, o5, m5, v5, B_act, 4, 32);

  // xw precompute (layer 1 only — reference keeps only last layer)
  transpose_f32_bf16<<<dim3(64, 64), 256, 0, stream>>>(fwWi + 4194304, WiTF, 2048, 2048);
  transpose_f32_bf16<<<dim3(64, 64), 256, 0, stream>>>(bwWi + 4194304, WiTB, 2048, 2048);
  gemm_xw_mfma<<<dim3(32, 32), 256, 0, stream>>>(B_act, WiTF, fwb + 2048, xwF, 0);
  gemm_xw_mfma<<<dim3(32, 32), 256, 0, stream>>>(B_act, WiTB, bwb + 2048, xwB, 1);

  // Wh transposed bf16 (layer 1)
  transpose_f32_bf16<<<dim3(16, 64), 256, 0, stream>>>(fwWh + 1048576, WhTF, 512, 2048);
  transpose_f32_bf16<<<dim3(16, 64), 256, 0, stream>>>(bwWh + 1048576, WhTB, 512, 2048);

  // all 32 LSTM steps, both directions, single launch
  lstm_persist<<<64, 256, 0, stream>>>(WhTF, WhTB, xwF, xwB, hsF, hsB, bar);

  fc_logsoftmax<<<2048, 128, 0, stream>>>(hsF, hsB, fcW, fcb, (float*)d_out);
}

// Round 4
// 630.186 us; speedup vs baseline: 12.3472x; 1.1123x over previous
//
#include <hip/hip_runtime.h>
#include <hip/hip_bf16.h>
#include <math.h>

#define EPSBN 1e-5f

using short8 = __attribute__((ext_vector_type(8))) short;
using f32x4  = __attribute__((ext_vector_type(4))) float;
using us4    = __attribute__((ext_vector_type(4))) unsigned short;

#define MFMA16(a, b, c) __builtin_amdgcn_mfma_f32_16x16x32_bf16(a, b, c, 0, 0, 0)

__device__ __forceinline__ float bf2f(unsigned short u) {
  unsigned int v = ((unsigned int)u) << 16;
  float f;
  __builtin_memcpy(&f, &v, 4);
  return f;
}
__device__ __forceinline__ unsigned short f2bf(float f) {
  __hip_bfloat16 h = __float2bfloat16(f);
  unsigned short u;
  __builtin_memcpy(&u, &h, 2);
  return u;
}
__device__ __forceinline__ float fast_sigmoid(float z) {
  return __builtin_amdgcn_rcpf(1.f + __expf(-z));
}
__device__ __forceinline__ float fast_tanh(float z) {
  float x2 = fminf(fmaxf(2.f * z, -30.f), 30.f);
  float e = __expf(x2);
  return (e - 1.f) * __builtin_amdgcn_rcpf(e + 1.f);
}

// ---------------- conv1: direct, H=32 W=256 CIN=1 COUT=64, LDS row staging ----------------
__global__ __launch_bounds__(256) void conv1_direct(
    const float* __restrict__ in, const float* __restrict__ w,
    const float* __restrict__ bias, const float* __restrict__ sc,
    const float* __restrict__ of, const float* __restrict__ mn,
    const float* __restrict__ vr, unsigned short* __restrict__ out) {
  __shared__ float lds[3][260];
  const int blk = blockIdx.x;          // 0..2047 = b*32 + y
  const int b = blk >> 5, y = blk & 31;
  const int tid = threadIdx.x;
  for (int i = tid; i < 780; i += 256) {
    int row = i / 260, c = i - row * 260;
    int iy = y + row - 1, xx = c - 1;
    float v = 0.f;
    if ((unsigned)iy < 32u && (unsigned)xx < 256u)
      v = in[((b << 5) + iy) * 256 + xx];
    lds[row][c] = v;
  }
  __syncthreads();
  const int co = tid & 63, xg = tid >> 6;
  float w9[9];
  #pragma unroll
  for (int t = 0; t < 9; ++t) w9[t] = w[t * 64 + co];
  const float scale = sc[co] * rsqrtf(vr[co] + EPSBN);
  const float shift = of[co] - mn[co] * scale;
  const float bs = bias[co];
  const int x0 = xg * 64;
  float a0 = lds[0][x0],     a1 = lds[1][x0],     a2 = lds[2][x0];
  float b0 = lds[0][x0 + 1], b1 = lds[1][x0 + 1], b2 = lds[2][x0 + 1];
  unsigned short* op = out + (((long)blk * 256 + x0) << 6) + co;
  #pragma unroll 4
  for (int i = 0; i < 64; ++i) {
    float c0 = lds[0][x0 + i + 2], c1 = lds[1][x0 + i + 2], c2 = lds[2][x0 + i + 2];
    float acc = bs;
    acc = fmaf(a0, w9[0], acc); acc = fmaf(a1, w9[3], acc); acc = fmaf(a2, w9[6], acc);
    acc = fmaf(b0, w9[1], acc); acc = fmaf(b1, w9[4], acc); acc = fmaf(b2, w9[7], acc);
    acc = fmaf(c0, w9[2], acc); acc = fmaf(c1, w9[5], acc); acc = fmaf(c2, w9[8], acc);
    acc = fmaxf(acc, 0.f) * scale + shift;
    op[(long)i << 6] = f2bf(acc);
    a0 = b0; a1 = b1; a2 = b2; b0 = c0; b1 = c1; b2 = c2;
  }
}

// ---------------- 2x2 maxpool stride 2 on bf16 ----------------
__global__ __launch_bounds__(256) void maxpool2_bf16(
    const unsigned short* __restrict__ in, unsigned short* __restrict__ out,
    int H, int W, int C, long total) {
  long i = (long)blockIdx.x * 256 + threadIdx.x;
  if (i >= total) return;
  int W2 = W >> 1, H2 = H >> 1;
  int c = (int)(i % C);
  long r = i / C;
  int x = (int)(r % W2); r /= W2;
  int y = (int)(r % H2);
  int b = (int)(r / H2);
  const unsigned short* p0 = in + ((long)(b * H + 2 * y) * W + 2 * x) * C + c;
  long rs = (long)W * C;
  unsigned short u0 = p0[0], u1 = p0[C], u2 = p0[rs], u3 = p0[rs + C];
  unsigned short a = (bf2f(u0) >= bf2f(u1)) ? u0 : u1;
  unsigned short bmx = (bf2f(u2) >= bf2f(u3)) ? u2 : u3;
  out[i] = (bf2f(a) >= bf2f(bmx)) ? a : bmx;
}

// ---------------- generic transpose: fp32 [K][N] -> bf16 [N][K] ----------------
__global__ __launch_bounds__(256) void transpose_f32_bf16(
    const float* __restrict__ in, unsigned short* __restrict__ out, int K, int N) {
  __shared__ float T[32][33];
  int k0 = blockIdx.x * 32, n0 = blockIdx.y * 32;
  int tid = threadIdx.x;
  int r = tid >> 3, c4 = (tid & 7) * 4;
  float4 v = *(const float4*)(in + (long)(k0 + r) * N + n0 + c4);
  T[r][c4 + 0] = v.x; T[r][c4 + 1] = v.y; T[r][c4 + 2] = v.z; T[r][c4 + 3] = v.w;
  __syncthreads();
  us4 o;
  #pragma unroll
  for (int i = 0; i < 4; ++i) o[i] = f2bf(T[c4 + i][r]);
  *(us4*)(out + (long)(n0 + r) * K + k0 + c4) = o;
}

// ---------------- MFMA implicit-GEMM conv 3x3 SAME + bias+relu+BN ----------------
template<int CIN, int COUT>
__global__ __launch_bounds__(256) void conv_mfma(
    const unsigned short* __restrict__ act, const unsigned short* __restrict__ wT,
    const float* __restrict__ bias, const float* __restrict__ sc,
    const float* __restrict__ of, const float* __restrict__ mn,
    const float* __restrict__ vr, unsigned short* __restrict__ out,
    int H, int W) {
  constexpr int K9 = 9 * CIN;
  __shared__ unsigned short As[4][64][8];
  __shared__ unsigned short Bs[4][64][8];
  const int tid = threadIdx.x;
  const int m0 = blockIdx.x * 64;
  const int n0 = blockIdx.y * 64;
  const int srow = tid >> 2, sseg = tid & 3;
  const int m = m0 + srow;
  const int HW = H * W;
  const int bb = m / HW;
  const int rem = m % HW;
  const int y = rem / W, x = rem % W;
  const int lane = tid & 63, wave = tid >> 6;
  const int msub = (wave >> 1) * 32, nsub = (wave & 1) * 32;
  const unsigned short* browp = wT + (long)(n0 + srow) * K9 + sseg * 8;
  f32x4 acc[2][2] = {};

  for (int k0 = 0; k0 < K9; k0 += 32) {
    const int tap = k0 / CIN;
    const int ci = k0 - tap * CIN + sseg * 8;
    const int iy = y + tap / 3 - 1;
    const int ix = x + tap % 3 - 1;
    short8 aval = {};
    if ((unsigned)iy < (unsigned)H && (unsigned)ix < (unsigned)W)
      aval = *(const short8*)(act + ((long)(bb * H + iy) * W + ix) * CIN + ci);
    short8 bval = *(const short8*)(browp + k0);
    __syncthreads();
    *(short8*)&As[sseg][srow][0] = aval;
    *(short8*)&Bs[sseg][srow][0] = bval;
    __syncthreads();
    short8 a0 = *(const short8*)&As[lane >> 4][msub + (lane & 15)][0];
    short8 a1 = *(const short8*)&As[lane >> 4][msub + 16 + (lane & 15)][0];
    short8 b0 = *(const short8*)&Bs[lane >> 4][nsub + (lane & 15)][0];
    short8 b1 = *(const short8*)&Bs[lane >> 4][nsub + 16 + (lane & 15)][0];
    acc[0][0] = MFMA16(a0, b0, acc[0][0]);
    acc[0][1] = MFMA16(a0, b1, acc[0][1]);
    acc[1][0] = MFMA16(a1, b0, acc[1][0]);
    acc[1][1] = MFMA16(a1, b1, acc[1][1]);
  }

  #pragma unroll
  for (int j = 0; j < 2; ++j) {
    const int col = n0 + nsub + j * 16 + (lane & 15);
    const float scale = sc[col] * rsqrtf(vr[col] + EPSBN);
    const float shift = of[col] - mn[col] * scale;
    const float bs = bias[col];
    #pragma unroll
    for (int i = 0; i < 2; ++i) {
      #pragma unroll
      for (int r = 0; r < 4; ++r) {
        const int row = m0 + msub + i * 16 + (lane >> 4) * 4 + r;
        const float v = fmaxf(acc[i][j][r] + bs, 0.f) * scale + shift;
        out[(long)row * COUT + col] = f2bf(v);
      }
    }
  }
}

// ---------------- MFMA GEMM: xw = gather(x_seq) @ WiT^T + b ----------------
__global__ __launch_bounds__(256) void gemm_xw_mfma(
    const unsigned short* __restrict__ src, const unsigned short* __restrict__ WiT,
    const float* __restrict__ bvec, float* __restrict__ xw, int rev) {
  __shared__ unsigned short As[4][64][8];
  __shared__ unsigned short Bs[4][64][8];
  const int tid = threadIdx.x;
  const int m0 = blockIdx.x * 64, n0 = blockIdx.y * 64;
  const int srow = tid >> 2, sseg = tid & 3;
  const int r = m0 + srow;
  const int tseq = r >> 6, bidx = r & 63;
  const int tt = rev ? 31 - tseq : tseq;
  const unsigned short* arow = src + (long)bidx * 65536 + (long)tt * 2048 + sseg * 8;
  const unsigned short* browp = WiT + (long)(n0 + srow) * 2048 + sseg * 8;
  const int lane = tid & 63, wave = tid >> 6;
  const int msub = (wave >> 1) * 32, nsub = (wave & 1) * 32;
  f32x4 acc[2][2] = {};

  for (int k0 = 0; k0 < 2048; k0 += 32) {
    short8 av = *(const short8*)(arow + k0);
    short8 bv = *(const short8*)(browp + k0);
    __syncthreads();
    *(short8*)&As[sseg][srow][0] = av;
    *(short8*)&Bs[sseg][srow][0] = bv;
    __syncthreads();
    short8 a0 = *(const short8*)&As[lane >> 4][msub + (lane & 15)][0];
    short8 a1 = *(const short8*)&As[lane >> 4][msub + 16 + (lane & 15)][0];
    short8 b0 = *(const short8*)&Bs[lane >> 4][nsub + (lane & 15)][0];
    short8 b1 = *(const short8*)&Bs[lane >> 4][nsub + 16 + (lane & 15)][0];
    acc[0][0] = MFMA16(a0, b0, acc[0][0]);
    acc[0][1] = MFMA16(a0, b1, acc[0][1]);
    acc[1][0] = MFMA16(a1, b0, acc[1][0]);
    acc[1][1] = MFMA16(a1, b1, acc[1][1]);
  }

  #pragma unroll
  for (int j = 0; j < 2; ++j) {
    const int col = n0 + nsub + j * 16 + (lane & 15);
    const float bs = bvec[col];
    #pragma unroll
    for (int i = 0; i < 2; ++i) {
      #pragma unroll
      for (int rr = 0; rr < 4; ++rr) {
        const int row = m0 + msub + i * 16 + (lane >> 4) * 4 + rr;
        xw[(long)row * 2048 + col] = acc[i][j][rr] + bs;
      }
    }
  }
}

// ---------------- persistent bidirectional LSTM, LDS-cached Wh ----------------
// grid 64 = 2 dirs x 32 u-tiles of 16 units. 256 threads (4 waves, 2x2 tiles).
// LDS: Whs 64KB (once) + Hs 64KB (per step) + Zs 16KB. XOR-swizzled b128 reads.
__global__ __launch_bounds__(256) void lstm_persist(
    const unsigned short* __restrict__ WhTF, const unsigned short* __restrict__ WhTB,
    const float* __restrict__ xwF, const float* __restrict__ xwB,
    unsigned short* __restrict__ hsF, unsigned short* __restrict__ hsB,
    int* __restrict__ bar) {
  __shared__ unsigned short Whs[64 * 512];
  __shared__ unsigned short Hs[64 * 512];
  __shared__ float Zs[4 * 64 * 16];
  const int bid = blockIdx.x;
  const int dir = bid >> 5;
  const int nb = bid & 31;
  const int u0 = nb * 16;
  const unsigned short* WhT = dir ? WhTB : WhTF;
  const float* xw = dir ? xwB : xwF;
  unsigned short* hs = dir ? hsB : hsF;
  int* mybar = bar + dir * 32;
  const int tid = threadIdx.x;
  const int lane = tid & 63, wave = tid >> 6;
  const int lr = lane & 15, lk = lane >> 4;
  const int mp = wave >> 1, gp = wave & 1;

  // stage Whs once: LDS row = g*16+u  <-  WhT[g*512+u0+u][.] (swizzled groups)
  #pragma unroll
  for (int i = 0; i < 16; ++i) {
    const int G = i * 256 + tid;
    const int row = G >> 6, g8 = G & 63;
    const int g = row >> 4, u = row & 15;
    short8 v = *(const short8*)(WhT + ((long)(g * 512 + u0 + u) << 9) + g8 * 8);
    *(short8*)(Whs + row * 512 + ((g8 ^ (row & 7)) << 3)) = v;
  }

  const int prow = tid >> 2;       // pointwise row 0..63
  const int pu4 = (tid & 3) * 4;   // pointwise u start (within tile)
  float c4[4] = {0.f, 0.f, 0.f, 0.f};

  for (int t = 0; t < 32; ++t) {
    // prefetch xw (independent of h) — 4 gates x float4
    float4 xq[4];
    #pragma unroll
    for (int g = 0; g < 4; ++g)
      xq[g] = *(const float4*)(xw + (long)(t * 64 + prow) * 2048 + g * 512 + u0 + pu4);
    // stage h_{t-1} (slab t) into LDS, swizzled
    const unsigned short* hsrc = hs + (long)t * 32768;
    #pragma unroll
    for (int i = 0; i < 16; ++i) {
      const int G = i * 256 + tid;
      const int row = G >> 6, g8 = G & 63;
      short8 v = *(const short8*)(hsrc + G * 8);
      *(short8*)(Hs + row * 512 + ((g8 ^ (row & 7)) << 3)) = v;
    }
    __syncthreads();

    f32x4 acc[2][2] = {};
    #pragma unroll
    for (int kk = 0; kk < 16; ++kk) {
      const int sw = ((lk + kk * 4) ^ (lr & 7)) << 3;
      short8 a0 = *(const short8*)(Hs + (mp * 32 + lr) * 512 + sw);
      short8 a1 = *(const short8*)(Hs + (mp * 32 + 16 + lr) * 512 + sw);
      short8 b0 = *(const short8*)(Whs + (gp * 32 + lr) * 512 + sw);
      short8 b1 = *(const short8*)(Whs + (gp * 32 + 16 + lr) * 512 + sw);
      acc[0][0] = MFMA16(a0, b0, acc[0][0]);
      acc[0][1] = MFMA16(a0, b1, acc[0][1]);
      acc[1][0] = MFMA16(a1, b0, acc[1][0]);
      acc[1][1] = MFMA16(a1, b1, acc[1][1]);
    }

    // park z tiles in LDS: Zs[g][row][u]
    #pragma unroll
    for (int im = 0; im < 2; ++im) {
      const int rowb = (mp * 2 + im) * 16 + lk * 4;
      #pragma unroll
      for (int ig = 0; ig < 2; ++ig) {
        const int g = gp * 2 + ig;
        #pragma unroll
        for (int r = 0; r < 4; ++r)
          Zs[g * 1024 + (rowb + r) * 16 + lr] = acc[im][ig][r];
      }
    }
    __syncthreads();

    // pointwise gates + state update; each thread owns (prow, pu4..pu4+3)
    {
      float4 zi = *(const float4*)(Zs + tid * 4);
      float4 zf = *(const float4*)(Zs + 1024 + tid * 4);
      float4 zg = *(const float4*)(Zs + 2048 + tid * 4);
      float4 zo = *(const float4*)(Zs + 3072 + tid * 4);
      const float* pzi = (const float*)&zi;
      const float* pzf = (const float*)&zf;
      const float* pzg = (const float*)&zg;
      const float* pzo = (const float*)&zo;
      const float* pxi = (const float*)&xq[0];
      const float* pxf = (const float*)&xq[1];
      const float* pxg = (const float*)&xq[2];
      const float* pxo = (const float*)&xq[3];
      us4 hv;
      #pragma unroll
      for (int r = 0; r < 4; ++r) {
        float ii = fast_sigmoid(pzi[r] + pxi[r]);
        float ff = fast_sigmoid(pzf[r] + pxf[r]);
        float gg = fast_tanh(pzg[r] + pxg[r]);
        float oo = fast_sigmoid(pzo[r] + pxo[r]);
        c4[r] = ff * c4[r] + ii * gg;
        hv[r] = f2bf(oo * fast_tanh(c4[r]));
      }
      *(us4*)(hs + (long)(t + 1) * 32768 + prow * 512 + u0 + pu4) = hv;
    }

    if (t < 31) {
      __syncthreads();
      if (tid == 0) {
        __threadfence();
        __hip_atomic_fetch_add(&mybar[t], 1, __ATOMIC_RELEASE, __HIP_MEMORY_SCOPE_AGENT);
        while (__hip_atomic_load(&mybar[t], __ATOMIC_ACQUIRE, __HIP_MEMORY_SCOPE_AGENT) < 32) {}
      }
      __syncthreads();
    }
  }
}

// ---------------- FC + log_softmax (bf16 h inputs) ----------------
__global__ __launch_bounds__(128) void fc_logsoftmax(
    const unsigned short* __restrict__ hsF, const unsigned short* __restrict__ hsB,
    const float* __restrict__ W, const float* __restrict__ bias,
    float* __restrict__ out) {
  int bt = blockIdx.x;
  int b = bt >> 5, t = bt & 31;
  __shared__ float vbuf[1024];
  __shared__ float sl[80];
  __shared__ float red[2];
  int tid = threadIdx.x;
  const unsigned short* fv = hsF + (long)(t + 1) * 32768 + (long)b * 512;
  const unsigned short* bv = hsB + (long)(t + 1) * 32768 + (long)b * 512;
  for (int i = tid; i < 512; i += 128) vbuf[i] = bf2f(fv[i]);
  for (int i = tid; i < 512; i += 128) vbuf[512 + i] = bf2f(bv[i]);
  __syncthreads();
  if (tid < 80) {
    float a0 = 0.f, a1 = 0.f, a2 = 0.f, a3 = 0.f;
    for (int k = 0; k < 1024; k += 4) {
      a0 = fmaf(vbuf[k + 0], W[(long)(k + 0) * 80 + tid], a0);
      a1 = fmaf(vbuf[k + 1], W[(long)(k + 1) * 80 + tid], a1);
      a2 = fmaf(vbuf[k + 2], W[(long)(k + 2) * 80 + tid], a2);
      a3 = fmaf(vbuf[k + 3], W[(long)(k + 3) * 80 + tid], a3);
    }
    sl[tid] = bias[tid] + ((a0 + a1) + (a2 + a3));
  }
  __syncthreads();
  if (tid == 0) {
    float mx = -1e30f;
    for (int j = 0; j < 80; ++j) mx = fmaxf(mx, sl[j]);
    float s = 0.f;
    for (int j = 0; j < 80; ++j) s += expf(sl[j] - mx);
    red[0] = mx;
    red[1] = logf(s);
  }
  __syncthreads();
  if (tid < 80)
    out[(long)bt * 80 + tid] = sl[tid] - red[0] - red[1];
}

__global__ __launch_bounds__(256) void zero_kernel(float* p, int n) {
  int i = blockIdx.x * 256 + threadIdx.x;
  if (i < n) p[i] = 0.f;
}

extern "C" void kernel_launch(void* const* d_in, const int* in_sizes, int n_in,
                              void* d_out, int out_size, void* d_ws, size_t ws_size,
                              hipStream_t stream) {
  const float* x  = (const float*)d_in[0];
  const float* k1 = (const float*)d_in[1];  const float* b1 = (const float*)d_in[2];
  const float* s1 = (const float*)d_in[3];  const float* o1 = (const float*)d_in[4];
  const float* m1 = (const float*)d_in[5];  const float* v1 = (const float*)d_in[6];
  const float* k2 = (const float*)d_in[7];  const float* b2 = (const float*)d_in[8];
  const float* s2 = (const float*)d_in[9];  const float* o2 = (const float*)d_in[10];
  const float* m2 = (const float*)d_in[11]; const float* v2 = (const float*)d_in[12];
  const float* k3 = (const float*)d_in[13]; const float* b3 = (const float*)d_in[14];
  const float* s3 = (const float*)d_in[15]; const float* o3 = (const float*)d_in[16];
  const float* m3 = (const float*)d_in[17]; const float* v3 = (const float*)d_in[18];
  const float* k4 = (const float*)d_in[19]; const float* b4 = (const float*)d_in[20];
  const float* s4 = (const float*)d_in[21]; const float* o4 = (const float*)d_in[22];
  const float* m4 = (const float*)d_in[23]; const float* v4 = (const float*)d_in[24];
  const float* k5 = (const float*)d_in[25]; const float* b5 = (const float*)d_in[26];
  const float* s5 = (const float*)d_in[27]; const float* o5 = (const float*)d_in[28];
  const float* m5 = (const float*)d_in[29]; const float* v5 = (const float*)d_in[30];
  const float* fwWi = (const float*)d_in[31];
  const float* fwWh = (const float*)d_in[32];
  const float* fwb  = (const float*)d_in[33];
  const float* bwWi = (const float*)d_in[34];
  const float* bwWh = (const float*)d_in[35];
  const float* bwb  = (const float*)d_in[36];
  const float* fcW  = (const float*)d_in[37];
  const float* fcb  = (const float*)d_in[38];

  char* wsb = (char*)d_ws;
  unsigned short* A_act = (unsigned short*)(wsb);                  // 33.55M el
  unsigned short* B_act = (unsigned short*)(wsb + 67108864);       // 8.39M el
  unsigned short* wT    = (unsigned short*)(wsb + 83886080);       // conv wT
  unsigned short* WiTF  = (unsigned short*)(wsb + 86245376);
  unsigned short* WiTB  = (unsigned short*)(wsb + 94633984);
  unsigned short* WhTF  = (unsigned short*)(wsb + 103022592);      // [2048][512] bf16
  unsigned short* WhTB  = (unsigned short*)(wsb + 105119744);
  float* xwF = (float*)(wsb + 107216896);                          // [2048][2048] f32
  float* xwB = (float*)(wsb + 123994112);
  int*   bar = (int*)(wsb + 140771328);                            // 64 ints
  unsigned short* hsF = (unsigned short*)(wsb + 140771584);        // [33][64][512]
  unsigned short* hsB = (unsigned short*)(wsb + 142934272);

  // zero: bar + hsF slab0 (contiguous), hsB slab0
  zero_kernel<<<(16448 + 255) / 256, 256, 0, stream>>>((float*)(wsb + 140771328), 16448);
  zero_kernel<<<(16384 + 255) / 256, 256, 0, stream>>>((float*)(wsb + 142934272), 16384);

  // conv1: x [64,32,256,1] -> A_act bf16 [64,32,256,64]
  conv1_direct<<<2048, 256, 0, stream>>>(x, k1, b1, s1, o1, m1, v1, A_act);
  maxpool2_bf16<<<(8388608 + 255) / 256, 256, 0, stream>>>(A_act, B_act, 32, 256, 64, 8388608);

  // conv2: B [64,16,128,64] -> A [.,128]
  transpose_f32_bf16<<<dim3(18, 4), 256, 0, stream>>>(k2, wT, 576, 128);
  conv_mfma<64, 128><<<dim3(2048, 2), 256, 0, stream>>>(
      B_act, wT, b2, s2, o2, m2, v2, A_act, 16, 128);
  maxpool2_bf16<<<(4194304 + 255) / 256, 256, 0, stream>>>(A_act, B_act, 16, 128, 128, 4194304);

  // conv3: B [64,8,64,128] -> A [.,256]
  transpose_f32_bf16<<<dim3(36, 8), 256, 0, stream>>>(k3, wT, 1152, 256);
  conv_mfma<128, 256><<<dim3(512, 4), 256, 0, stream>>>(
      B_act, wT, b3, s3, o3, m3, v3, A_act, 8, 64);
  maxpool2_bf16<<<(2097152 + 255) / 256, 256, 0, stream>>>(A_act, B_act, 8, 64, 256, 2097152);

  // conv4: B [64,4,32,256] -> A [.,256]
  transpose_f32_bf16<<<dim3(72, 8), 256, 0, stream>>>(k4, wT, 2304, 256);
  conv_mfma<256, 256><<<dim3(128, 4), 256, 0, stream>>>(
      B_act, wT, b4, s4, o4, m4, v4, A_act, 4, 32);

  // conv5: A [64,4,32,256] -> B [.,512]
  transpose_f32_bf16<<<dim3(72, 16), 256, 0, stream>>>(k5, wT, 2304, 512);
  conv_mfma<256, 512><<<dim3(128, 8), 256, 0, stream>>>(
      A_act, wT, b5, s5, o5, m5, v5, B_act, 4, 32);

  // xw precompute (layer 1 only — reference keeps only last layer)
  transpose_f32_bf16<<<dim3(64, 64), 256, 0, stream>>>(fwWi + 4194304, WiTF, 2048, 2048);
  transpose_f32_bf16<<<dim3(64, 64), 256, 0, stream>>>(bwWi + 4194304, WiTB, 2048, 2048);
  gemm_xw_mfma<<<dim3(32, 32), 256, 0, stream>>>(B_act, WiTF, fwb + 2048, xwF, 0);
  gemm_xw_mfma<<<dim3(32, 32), 256, 0, stream>>>(B_act, WiTB, bwb + 2048, xwB, 1);

  // Wh transposed bf16 (layer 1)
  transpose_f32_bf16<<<dim3(16, 64), 256, 0, stream>>>(fwWh + 1048576, WhTF, 512, 2048);
  transpose_f32_bf16<<<dim3(16, 64), 256, 0, stream>>>(bwWh + 1048576, WhTB, 512, 2048);

  // all 32 LSTM steps, both directions, single launch
  lstm_persist<<<64, 256, 0, stream>>>(WhTF, WhTB, xwF, xwB, hsF, hsB, bar);

  fc_logsoftmax<<<2048, 128, 0, stream>>>(hsF, hsB, fcW, fcb, (float*)d_out);
}

// Round 5
// 598.666 us; speedup vs baseline: 12.9973x; 1.0526x over previous
//
#include <hip/hip_runtime.h>
#include <hip/hip_bf16.h>
#include <math.h>

#define EPSBN 1e-5f

using short8 = __attribute__((ext_vector_type(8))) short;
using f32x4  = __attribute__((ext_vector_type(4))) float;
using us4    = __attribute__((ext_vector_type(4))) unsigned short;

#define MFMA16(a, b, c) __builtin_amdgcn_mfma_f32_16x16x32_bf16(a, b, c, 0, 0, 0)

__device__ __forceinline__ float bf2f(unsigned short u) {
  unsigned int v = ((unsigned int)u) << 16;
  float f;
  __builtin_memcpy(&f, &v, 4);
  return f;
}
__device__ __forceinline__ unsigned short f2bf(float f) {
  __hip_bfloat16 h = __float2bfloat16(f);
  unsigned short u;
  __builtin_memcpy(&u, &h, 2);
  return u;
}
__device__ __forceinline__ float fast_sigmoid(float z) {
  return __builtin_amdgcn_rcpf(1.f + __expf(-z));
}
__device__ __forceinline__ float fast_tanh(float z) {
  float x2 = fminf(fmaxf(2.f * z, -30.f), 30.f);
  float e = __expf(x2);
  return (e - 1.f) * __builtin_amdgcn_rcpf(e + 1.f);
}
// async global->LDS, 16B per lane, dest = wave-uniform base + lane*16
__device__ __forceinline__ void stage16(const unsigned short* g, unsigned short* l) {
  __builtin_amdgcn_global_load_lds(
      (const __attribute__((address_space(1))) void*)g,
      (__attribute__((address_space(3))) void*)l, 16, 0, 0);
}

// ---------------- conv1: direct, H=32 W=256 CIN=1 COUT=64 ----------------
__global__ __launch_bounds__(256) void conv1_direct(
    const float* __restrict__ in, const float* __restrict__ w,
    const float* __restrict__ bias, const float* __restrict__ sc,
    const float* __restrict__ of, const float* __restrict__ mn,
    const float* __restrict__ vr, unsigned short* __restrict__ out) {
  __shared__ float lds[3][260];
  const int blk = blockIdx.x;          // b*32 + y
  const int b = blk >> 5, y = blk & 31;
  const int tid = threadIdx.x;
  for (int i = tid; i < 780; i += 256) {
    int row = i / 260, c = i - row * 260;
    int iy = y + row - 1, xx = c - 1;
    float v = 0.f;
    if ((unsigned)iy < 32u && (unsigned)xx < 256u)
      v = in[((b << 5) + iy) * 256 + xx];
    lds[row][c] = v;
  }
  __syncthreads();
  const int co = tid & 63, xg = tid >> 6;
  float w9[9];
  #pragma unroll
  for (int t = 0; t < 9; ++t) w9[t] = w[t * 64 + co];
  const float scale = sc[co] * rsqrtf(vr[co] + EPSBN);
  const float shift = of[co] - mn[co] * scale;
  const float bs = bias[co];
  const int x0 = xg * 64;
  float a0 = lds[0][x0],     a1 = lds[1][x0],     a2 = lds[2][x0];
  float b0 = lds[0][x0 + 1], b1 = lds[1][x0 + 1], b2 = lds[2][x0 + 1];
  unsigned short* op = out + (((long)blk * 256 + x0) << 6) + co;
  #pragma unroll 4
  for (int i = 0; i < 64; ++i) {
    float c0 = lds[0][x0 + i + 2], c1 = lds[1][x0 + i + 2], c2 = lds[2][x0 + i + 2];
    float acc = bs;
    acc = fmaf(a0, w9[0], acc); acc = fmaf(a1, w9[3], acc); acc = fmaf(a2, w9[6], acc);
    acc = fmaf(b0, w9[1], acc); acc = fmaf(b1, w9[4], acc); acc = fmaf(b2, w9[7], acc);
    acc = fmaf(c0, w9[2], acc); acc = fmaf(c1, w9[5], acc); acc = fmaf(c2, w9[8], acc);
    acc = fmaxf(acc, 0.f) * scale + shift;
    op[(long)i << 6] = f2bf(acc);
    a0 = b0; a1 = b1; a2 = b2; b0 = c0; b1 = c1; b2 = c2;
  }
}

// ---------------- 2x2 maxpool -> PADDED output (1-px zero halo) ----------------
// out: [B][H2+2][W2+2][C]; in: [B][2H2][2W2][C] unpadded
template<int C, int H2, int W2>
__global__ __launch_bounds__(256) void maxpool_pad(
    const unsigned short* __restrict__ in, unsigned short* __restrict__ out) {
  constexpr int W2P = W2 + 2, H2P = H2 + 2;
  const int y = blockIdx.y;
  const int b = y / H2P, yp = y - b * H2P;
  const int j = blockIdx.x * 256 + threadIdx.x;
  if (j >= W2P * C) return;
  const int xp = j / C, c = j - xp * C;
  unsigned short res = 0;
  if (yp >= 1 && yp <= H2 && xp >= 1 && xp <= W2) {
    const long rs = (long)(2 * W2) * C;
    const unsigned short* p0 =
        in + (((long)b * (2 * H2) + (yp - 1) * 2) * (2 * W2) + (xp - 1) * 2) * C + c;
    unsigned short u0 = p0[0], u1 = p0[C], u2 = p0[rs], u3 = p0[rs + C];
    unsigned short a = (bf2f(u0) >= bf2f(u1)) ? u0 : u1;
    unsigned short bmx = (bf2f(u2) >= bf2f(u3)) ? u2 : u3;
    res = (bf2f(a) >= bf2f(bmx)) ? a : bmx;
  }
  out[((long)y * W2P + xp) * C + c] = res;
}

// ---------------- generic transpose: fp32 [K][N] -> bf16 [N][K] ----------------
__global__ __launch_bounds__(256) void transpose_f32_bf16(
    const float* __restrict__ in, unsigned short* __restrict__ out, int K, int N) {
  __shared__ float T[32][33];
  int k0 = blockIdx.x * 32, n0 = blockIdx.y * 32;
  int tid = threadIdx.x;
  int r = tid >> 3, c4 = (tid & 7) * 4;
  float4 v = *(const float4*)(in + (long)(k0 + r) * N + n0 + c4);
  T[r][c4 + 0] = v.x; T[r][c4 + 1] = v.y; T[r][c4 + 2] = v.z; T[r][c4 + 3] = v.w;
  __syncthreads();
  us4 o;
  #pragma unroll
  for (int i = 0; i < 4; ++i) o[i] = f2bf(T[c4 + i][r]);
  *(us4*)(out + (long)(n0 + r) * K + k0 + c4) = o;
}

// ---------------- m97-style implicit-GEMM conv: 128x128 tile, BK=32 ----------------
// act: PADDED [B][H+2][W+2][CIN] bf16, halo zeros. wT: [COUT][9*CIN] bf16.
// 256 thr = 4 waves, each 64x64 acc (4x4 of 16x16x32). global_load_lds staging.
template<int CIN, int COUT, int H, int W, int OUTPAD>
__global__ __launch_bounds__(256) void conv_mfma128(
    const unsigned short* __restrict__ act, const unsigned short* __restrict__ wT,
    const float* __restrict__ bias, const float* __restrict__ sc,
    const float* __restrict__ of, const float* __restrict__ mn,
    const float* __restrict__ vr, unsigned short* __restrict__ out) {
  constexpr int K9 = 9 * CIN;
  constexpr int HW = H * W;
  constexpr int WP = W + 2;
  __shared__ unsigned short As[128 * 32];
  __shared__ unsigned short Bs[128 * 32];
  const int tid = threadIdx.x;
  const int lane = tid & 63, wave = tid >> 6;
  const int m0 = blockIdx.x * 128, n0 = blockIdx.y * 128;
  const int r0 = tid >> 2, seg = tid & 3;
  const int segp = (seg ^ (r0 & 3)) << 3;          // pre-swizzled k-seg (shorts)
  long pa0, pa1;
  {
    const int m = m0 + r0;
    const int b = m / HW, rem = m % HW;
    const int y = rem / W, x = rem % W;
    pa0 = (((long)b * (H + 2) + y) * WP + x) * CIN + segp;
  }
  {
    const int m = m0 + r0 + 64;
    const int b = m / HW, rem = m % HW;
    const int y = rem / W, x = rem % W;
    pa1 = (((long)b * (H + 2) + y) * WP + x) * CIN + segp;
  }
  const long pb0 = (long)(n0 + r0) * K9 + segp;
  const long pb1 = (long)(n0 + r0 + 64) * K9 + segp;
  unsigned short* AsW = As + wave * 512;
  unsigned short* BsW = Bs + wave * 512;
  const int swz = ((lane >> 4) ^ (lane & 3)) << 3;
  const int arow0 = (wave >> 1) * 64 + (lane & 15);
  const int brow0 = (wave & 1) * 64 + (lane & 15);
  f32x4 acc[4][4] = {};

  #pragma unroll 1
  for (int tap = 0; tap < 9; ++tap) {
    const long aoff = (long)((tap / 3) * WP + (tap % 3)) * CIN;
    #pragma unroll 1
    for (int cib = 0; cib < CIN; cib += 32) {
      const long ka = aoff + cib;
      const long kb = (long)tap * CIN + cib;
      stage16(act + pa0 + ka, AsW);
      stage16(act + pa1 + ka, AsW + 2048);
      stage16(wT + pb0 + kb, BsW);
      stage16(wT + pb1 + kb, BsW + 2048);
      __syncthreads();
      short8 a[4], b[4];
      #pragma unroll
      for (int i = 0; i < 4; ++i)
        a[i] = *(const short8*)(As + (arow0 + i * 16) * 32 + swz);
      #pragma unroll
      for (int j = 0; j < 4; ++j)
        b[j] = *(const short8*)(Bs + (brow0 + j * 16) * 32 + swz);
      #pragma unroll
      for (int i = 0; i < 4; ++i)
        #pragma unroll
        for (int j = 0; j < 4; ++j)
          acc[i][j] = MFMA16(a[i], b[j], acc[i][j]);
      __syncthreads();
    }
  }

  float scl[4], shf[4], bsv[4];
  #pragma unroll
  for (int j = 0; j < 4; ++j) {
    const int col = n0 + (wave & 1) * 64 + j * 16 + (lane & 15);
    scl[j] = sc[col] * rsqrtf(vr[col] + EPSBN);
    shf[j] = of[col] - mn[col] * scl[j];
    bsv[j] = bias[col];
  }
  #pragma unroll
  for (int i = 0; i < 4; ++i) {
    #pragma unroll
    for (int rr = 0; rr < 4; ++rr) {
      const int m = m0 + (wave >> 1) * 64 + i * 16 + (lane >> 4) * 4 + rr;
      const int b = m / HW, rem = m % HW;
      const int y = rem / W, x = rem % W;
      long obase;
      if (OUTPAD) obase = (((long)b * (H + 2) + y + 1) * WP + x + 1) * COUT;
      else        obase = (((long)b * H + y) * W + x) * COUT;
      const int colb = n0 + (wave & 1) * 64 + (lane & 15);
      #pragma unroll
      for (int j = 0; j < 4; ++j) {
        const float v = fmaxf(acc[i][j][rr] + bsv[j], 0.f) * scl[j] + shf[j];
        out[obase + colb + j * 16] = f2bf(v);
      }
    }
  }
}

// ---------------- m97-style GEMM: xw = gather(x_seq) @ WiT^T + b ----------------
// M=N=K=2048, 128x128 tile. A row r=t*64+b: src[b*65536 + tt*2048 + k] (bf16).
__global__ __launch_bounds__(256) void gemm_xw128(
    const unsigned short* __restrict__ src, const unsigned short* __restrict__ WiT,
    const float* __restrict__ bvec, float* __restrict__ xw, int rev) {
  __shared__ unsigned short As[128 * 32];
  __shared__ unsigned short Bs[128 * 32];
  const int tid = threadIdx.x;
  const int lane = tid & 63, wave = tid >> 6;
  const int m0 = blockIdx.x * 128, n0 = blockIdx.y * 128;
  const int r0 = tid >> 2, seg = tid & 3;
  const int segp = (seg ^ (r0 & 3)) << 3;
  long pa0, pa1;
  {
    const int r = m0 + r0;
    const int t = r >> 6, bb = r & 63;
    const int tt = rev ? 31 - t : t;
    pa0 = (long)bb * 65536 + (long)tt * 2048 + segp;
  }
  {
    const int r = m0 + r0 + 64;
    const int t = r >> 6, bb = r & 63;
    const int tt = rev ? 31 - t : t;
    pa1 = (long)bb * 65536 + (long)tt * 2048 + segp;
  }
  const long pb0 = (long)(n0 + r0) * 2048 + segp;
  const long pb1 = (long)(n0 + r0 + 64) * 2048 + segp;
  unsigned short* AsW = As + wave * 512;
  unsigned short* BsW = Bs + wave * 512;
  const int swz = ((lane >> 4) ^ (lane & 3)) << 3;
  const int arow0 = (wave >> 1) * 64 + (lane & 15);
  const int brow0 = (wave & 1) * 64 + (lane & 15);
  f32x4 acc[4][4] = {};

  #pragma unroll 1
  for (int ks = 0; ks < 64; ++ks) {
    const long k0 = (long)ks * 32;
    stage16(src + pa0 + k0, AsW);
    stage16(src + pa1 + k0, AsW + 2048);
    stage16(WiT + pb0 + k0, BsW);
    stage16(WiT + pb1 + k0, BsW + 2048);
    __syncthreads();
    short8 a[4], b[4];
    #pragma unroll
    for (int i = 0; i < 4; ++i)
      a[i] = *(const short8*)(As + (arow0 + i * 16) * 32 + swz);
    #pragma unroll
    for (int j = 0; j < 4; ++j)
      b[j] = *(const short8*)(Bs + (brow0 + j * 16) * 32 + swz);
    #pragma unroll
    for (int i = 0; i < 4; ++i)
      #pragma unroll
      for (int j = 0; j < 4; ++j)
        acc[i][j] = MFMA16(a[i], b[j], acc[i][j]);
    __syncthreads();
  }

  float bsv[4];
  #pragma unroll
  for (int j = 0; j < 4; ++j)
    bsv[j] = bvec[n0 + (wave & 1) * 64 + j * 16 + (lane & 15)];
  #pragma unroll
  for (int i = 0; i < 4; ++i) {
    #pragma unroll
    for (int rr = 0; rr < 4; ++rr) {
      const int row = m0 + (wave >> 1) * 64 + i * 16 + (lane >> 4) * 4 + rr;
      const int colb = n0 + (wave & 1) * 64 + (lane & 15);
      #pragma unroll
      for (int j = 0; j < 4; ++j)
        xw[(long)row * 2048 + colb + j * 16] = acc[i][j][rr] + bsv[j];
    }
  }
}

// ---------------- persistent bidirectional LSTM, LDS-cached Wh ----------------
__global__ __launch_bounds__(256) void lstm_persist(
    const unsigned short* __restrict__ WhTF, const unsigned short* __restrict__ WhTB,
    const float* __restrict__ xwF, const float* __restrict__ xwB,
    unsigned short* __restrict__ hsF, unsigned short* __restrict__ hsB,
    int* __restrict__ bar) {
  __shared__ unsigned short Whs[64 * 512];
  __shared__ unsigned short Hs[64 * 512];
  __shared__ float Zs[4 * 64 * 16];
  const int bid = blockIdx.x;
  const int dir = bid >> 5;
  const int nb = bid & 31;
  const int u0 = nb * 16;
  const unsigned short* WhT = dir ? WhTB : WhTF;
  const float* xw = dir ? xwB : xwF;
  unsigned short* hs = dir ? hsB : hsF;
  int* mybar = bar + dir * 32;
  const int tid = threadIdx.x;
  const int lane = tid & 63, wave = tid >> 6;
  const int lr = lane & 15, lk = lane >> 4;
  const int mp = wave >> 1, gp = wave & 1;

  #pragma unroll
  for (int i = 0; i < 16; ++i) {
    const int G = i * 256 + tid;
    const int row = G >> 6, g8 = G & 63;
    const int g = row >> 4, u = row & 15;
    short8 v = *(const short8*)(WhT + ((long)(g * 512 + u0 + u) << 9) + g8 * 8);
    *(short8*)(Whs + row * 512 + ((g8 ^ (row & 7)) << 3)) = v;
  }

  const int prow = tid >> 2;
  const int pu4 = (tid & 3) * 4;
  float c4[4] = {0.f, 0.f, 0.f, 0.f};
  float4 xq[4];
  #pragma unroll
  for (int g = 0; g < 4; ++g)
    xq[g] = *(const float4*)(xw + (long)prow * 2048 + g * 512 + u0 + pu4);

  for (int t = 0; t < 32; ++t) {
    const unsigned short* hsrc = hs + (long)t * 32768;
    #pragma unroll
    for (int i = 0; i < 16; ++i) {
      const int G = i * 256 + tid;
      const int row = G >> 6, g8 = G & 63;
      short8 v = *(const short8*)(hsrc + G * 8);
      *(short8*)(Hs + row * 512 + ((g8 ^ (row & 7)) << 3)) = v;
    }
    __syncthreads();

    f32x4 acc[2][2] = {};
    #pragma unroll
    for (int kk = 0; kk < 16; ++kk) {
      const int sw = ((lk + kk * 4) ^ (lr & 7)) << 3;
      short8 a0 = *(const short8*)(Hs + (mp * 32 + lr) * 512 + sw);
      short8 a1 = *(const short8*)(Hs + (mp * 32 + 16 + lr) * 512 + sw);
      short8 b0 = *(const short8*)(Whs + (gp * 32 + lr) * 512 + sw);
      short8 b1 = *(const short8*)(Whs + (gp * 32 + 16 + lr) * 512 + sw);
      acc[0][0] = MFMA16(a0, b0, acc[0][0]);
      acc[0][1] = MFMA16(a0, b1, acc[0][1]);
      acc[1][0] = MFMA16(a1, b0, acc[1][0]);
      acc[1][1] = MFMA16(a1, b1, acc[1][1]);
    }

    #pragma unroll
    for (int im = 0; im < 2; ++im) {
      const int rowb = (mp * 2 + im) * 16 + lk * 4;
      #pragma unroll
      for (int ig = 0; ig < 2; ++ig) {
        const int g = gp * 2 + ig;
        #pragma unroll
        for (int r = 0; r < 4; ++r)
          Zs[g * 1024 + (rowb + r) * 16 + lr] = acc[im][ig][r];
      }
    }
    __syncthreads();

    {
      float4 zi = *(const float4*)(Zs + tid * 4);
      float4 zf = *(const float4*)(Zs + 1024 + tid * 4);
      float4 zg = *(const float4*)(Zs + 2048 + tid * 4);
      float4 zo = *(const float4*)(Zs + 3072 + tid * 4);
      const float* pzi = (const float*)&zi;
      const float* pzf = (const float*)&zf;
      const float* pzg = (const float*)&zg;
      const float* pzo = (const float*)&zo;
      const float* px = (const float*)&xq[0];
      us4 hv;
      #pragma unroll
      for (int r = 0; r < 4; ++r) {
        float ii = fast_sigmoid(pzi[r] + ((const float*)&xq[0])[r]);
        float ff = fast_sigmoid(pzf[r] + ((const float*)&xq[1])[r]);
        float gg = fast_tanh(pzg[r] + ((const float*)&xq[2])[r]);
        float oo = fast_sigmoid(pzo[r] + ((const float*)&xq[3])[r]);
        c4[r] = ff * c4[r] + ii * gg;
        hv[r] = f2bf(oo * fast_tanh(c4[r]));
      }
      (void)px;
      *(us4*)(hs + (long)(t + 1) * 32768 + prow * 512 + u0 + pu4) = hv;
    }

    if (t < 31) {
      // prefetch next-step xw BEFORE the grid barrier (independent of h)
      float4 xqn[4];
      #pragma unroll
      for (int g = 0; g < 4; ++g)
        xqn[g] = *(const float4*)(xw + (long)((t + 1) * 64 + prow) * 2048 + g * 512 + u0 + pu4);
      __syncthreads();
      if (tid == 0) {
        __threadfence();
        __hip_atomic_fetch_add(&mybar[t], 1, __ATOMIC_RELEASE, __HIP_MEMORY_SCOPE_AGENT);
        while (__hip_atomic_load(&mybar[t], __ATOMIC_ACQUIRE, __HIP_MEMORY_SCOPE_AGENT) < 32) {}
      }
      __syncthreads();
      #pragma unroll
      for (int g = 0; g < 4; ++g) xq[g] = xqn[g];
    }
  }
}

// ---------------- FC + log_softmax (bf16 h inputs) ----------------
__global__ __launch_bounds__(128) void fc_logsoftmax(
    const unsigned short* __restrict__ hsF, const unsigned short* __restrict__ hsB,
    const float* __restrict__ W, const float* __restrict__ bias,
    float* __restrict__ out) {
  int bt = blockIdx.x;
  int b = bt >> 5, t = bt & 31;
  __shared__ float vbuf[1024];
  __shared__ float sl[80];
  __shared__ float red[2];
  int tid = threadIdx.x;
  const unsigned short* fv = hsF + (long)(t + 1) * 32768 + (long)b * 512;
  const unsigned short* bv = hsB + (long)(t + 1) * 32768 + (long)b * 512;
  for (int i = tid; i < 512; i += 128) vbuf[i] = bf2f(fv[i]);
  for (int i = tid; i < 512; i += 128) vbuf[512 + i] = bf2f(bv[i]);
  __syncthreads();
  if (tid < 80) {
    float a0 = 0.f, a1 = 0.f, a2 = 0.f, a3 = 0.f;
    for (int k = 0; k < 1024; k += 4) {
      a0 = fmaf(vbuf[k + 0], W[(long)(k + 0) * 80 + tid], a0);
      a1 = fmaf(vbuf[k + 1], W[(long)(k + 1) * 80 + tid], a1);
      a2 = fmaf(vbuf[k + 2], W[(long)(k + 2) * 80 + tid], a2);
      a3 = fmaf(vbuf[k + 3], W[(long)(k + 3) * 80 + tid], a3);
    }
    sl[tid] = bias[tid] + ((a0 + a1) + (a2 + a3));
  }
  __syncthreads();
  if (tid == 0) {
    float mx = -1e30f;
    for (int j = 0; j < 80; ++j) mx = fmaxf(mx, sl[j]);
    float s = 0.f;
    for (int j = 0; j < 80; ++j) s += expf(sl[j] - mx);
    red[0] = mx;
    red[1] = logf(s);
  }
  __syncthreads();
  if (tid < 80)
    out[(long)bt * 80 + tid] = sl[tid] - red[0] - red[1];
}

__global__ __launch_bounds__(256) void zero_kernel(float* p, int n) {
  int i = blockIdx.x * 256 + threadIdx.x;
  if (i < n) p[i] = 0.f;
}

extern "C" void kernel_launch(void* const* d_in, const int* in_sizes, int n_in,
                              void* d_out, int out_size, void* d_ws, size_t ws_size,
                              hipStream_t stream) {
  const float* x  = (const float*)d_in[0];
  const float* k1 = (const float*)d_in[1];  const float* b1 = (const float*)d_in[2];
  const float* s1 = (const float*)d_in[3];  const float* o1 = (const float*)d_in[4];
  const float* m1 = (const float*)d_in[5];  const float* v1 = (const float*)d_in[6];
  const float* k2 = (const float*)d_in[7];  const float* b2 = (const float*)d_in[8];
  const float* s2 = (const float*)d_in[9];  const float* o2 = (const float*)d_in[10];
  const float* m2 = (const float*)d_in[11]; const float* v2 = (const float*)d_in[12];
  const float* k3 = (const float*)d_in[13]; const float* b3 = (const float*)d_in[14];
  const float* s3 = (const float*)d_in[15]; const float* o3 = (const float*)d_in[16];
  const float* m3 = (const float*)d_in[17]; const float* v3 = (const float*)d_in[18];
  const float* k4 = (const float*)d_in[19]; const float* b4 = (const float*)d_in[20];
  const float* s4 = (const float*)d_in[21]; const float* o4 = (const float*)d_in[22];
  const float* m4 = (const float*)d_in[23]; const float* v4 = (const float*)d_in[24];
  const float* k5 = (const float*)d_in[25]; const float* b5 = (const float*)d_in[26];
  const float* s5 = (const float*)d_in[27]; const float* o5 = (const float*)d_in[28];
  const float* m5 = (const float*)d_in[29]; const float* v5 = (const float*)d_in[30];
  const float* fwWi = (const float*)d_in[31];
  const float* fwWh = (const float*)d_in[32];
  const float* fwb  = (const float*)d_in[33];
  const float* bwWi = (const float*)d_in[34];
  const float* bwWh = (const float*)d_in[35];
  const float* bwb  = (const float*)d_in[36];
  const float* fcW  = (const float*)d_in[37];
  const float* fcb  = (const float*)d_in[38];

  char* wsb = (char*)d_ws;
  // REG_A hosts C1 -> C2 -> C3 -> C5 (sequential lifetimes)
  unsigned short* REG_A = (unsigned short*)(wsb);                  // 67,108,864 B
  unsigned short* REG_P = (unsigned short*)(wsb + 67108864);       // 19,169,280 B (P1/P2/P3)
  unsigned short* C4    = (unsigned short*)(wsb + 86278144);       // 6,684,672 B padded
  unsigned short* wT    = (unsigned short*)(wsb + 92962816);       // 2,359,296 B
  unsigned short* WiTF  = (unsigned short*)(wsb + 95322112);       // 8,388,608 B
  unsigned short* WiTB  = (unsigned short*)(wsb + 103710720);      // 8,388,608 B
  unsigned short* WhTF  = (unsigned short*)(wsb + 112099328);      // 2,097,152 B
  unsigned short* WhTB  = (unsigned short*)(wsb + 114196480);      // 2,097,152 B
  float* xwF = (float*)(wsb + 116293632);                          // 16,777,216 B
  float* xwB = (float*)(wsb + 133070848);                          // 16,777,216 B
  int*   bar = (int*)(wsb + 149848064);                            // 256 B
  unsigned short* hsF = (unsigned short*)(wsb + 149848320);        // [33][64][512]
  unsigned short* hsB = (unsigned short*)(wsb + 152011008);

  // zero: bar + hsF slab0 (contiguous), hsB slab0, C4 (for halo)
  zero_kernel<<<65, 256, 0, stream>>>((float*)(wsb + 149848064), 16448);
  zero_kernel<<<64, 256, 0, stream>>>((float*)(wsb + 152011008), 16384);
  zero_kernel<<<6528, 256, 0, stream>>>((float*)(wsb + 86278144), 1671168);

  // conv1: x [64,32,256,1] -> C1 [64,32,256,64] (REG_A)
  conv1_direct<<<2048, 256, 0, stream>>>(x, k1, b1, s1, o1, m1, v1, REG_A);
  // pool1 -> P1 padded [64,18,130,64]
  maxpool_pad<64, 16, 128><<<dim3(33, 1152), 256, 0, stream>>>(REG_A, REG_P);

  // conv2: P1 -> C2 [64,16,128,128] (REG_A)
  transpose_f32_bf16<<<dim3(18, 4), 256, 0, stream>>>(k2, wT, 576, 128);
  conv_mfma128<64, 128, 16, 128, 0><<<dim3(1024, 1), 256, 0, stream>>>(
      REG_P, wT, b2, s2, o2, m2, v2, REG_A);
  // pool2 -> P2 padded [64,10,66,128]
  maxpool_pad<128, 8, 64><<<dim3(33, 640), 256, 0, stream>>>(REG_A, REG_P);

  // conv3: P2 -> C3 [64,8,64,256] (REG_A)
  transpose_f32_bf16<<<dim3(36, 8), 256, 0, stream>>>(k3, wT, 1152, 256);
  conv_mfma128<128, 256, 8, 64, 0><<<dim3(256, 2), 256, 0, stream>>>(
      REG_P, wT, b3, s3, o3, m3, v3, REG_A);
  // pool3 -> P3 padded [64,6,34,256]
  maxpool_pad<256, 4, 32><<<dim3(34, 384), 256, 0, stream>>>(REG_A, REG_P);

  // conv4: P3 -> C4 PADDED [64,6,34,256]
  transpose_f32_bf16<<<dim3(72, 8), 256, 0, stream>>>(k4, wT, 2304, 256);
  conv_mfma128<256, 256, 4, 32, 1><<<dim3(64, 2), 256, 0, stream>>>(
      REG_P, wT, b4, s4, o4, m4, v4, C4);

  // conv5: C4 -> C5 [64,4,32,512] (REG_A)
  transpose_f32_bf16<<<dim3(72, 16), 256, 0, stream>>>(k5, wT, 2304, 512);
  conv_mfma128<256, 512, 4, 32, 0><<<dim3(64, 4), 256, 0, stream>>>(
      C4, wT, b5, s5, o5, m5, v5, REG_A);

  // xw precompute (layer 1 only — reference keeps only last layer)
  transpose_f32_bf16<<<dim3(64, 64), 256, 0, stream>>>(fwWi + 4194304, WiTF, 2048, 2048);
  transpose_f32_bf16<<<dim3(64, 64), 256, 0, stream>>>(bwWi + 4194304, WiTB, 2048, 2048);
  gemm_xw128<<<dim3(16, 16), 256, 0, stream>>>(REG_A, WiTF, fwb + 2048, xwF, 0);
  gemm_xw128<<<dim3(16, 16), 256, 0, stream>>>(REG_A, WiTB, bwb + 2048, xwB, 1);

  // Wh transposed bf16 (layer 1)
  transpose_f32_bf16<<<dim3(16, 64), 256, 0, stream>>>(fwWh + 1048576, WhTF, 512, 2048);
  transpose_f32_bf16<<<dim3(16, 64), 256, 0, stream>>>(bwWh + 1048576, WhTB, 512, 2048);

  // all 32 LSTM steps, both directions, single launch
  lstm_persist<<<64, 256, 0, stream>>>(WhTF, WhTB, xwF, xwB, hsF, hsB, bar);

  fc_logsoftmax<<<2048, 128, 0, stream>>>(hsF, hsB, fcW, fcb, (float*)d_out);
}

// Round 6
// 569.862 us; speedup vs baseline: 13.6542x; 1.0505x over previous
//
#include <hip/hip_runtime.h>
#include <hip/hip_bf16.h>
#include <math.h>

#define EPSBN 1e-5f

using short8 = __attribute__((ext_vector_type(8))) short;
using f32x4  = __attribute__((ext_vector_type(4))) float;
using us4    = __attribute__((ext_vector_type(4))) unsigned short;

#define MFMA16(a, b, c) __builtin_amdgcn_mfma_f32_16x16x32_bf16(a, b, c, 0, 0, 0)

__device__ __forceinline__ float bf2f(unsigned short u) {
  unsigned int v = ((unsigned int)u) << 16;
  float f;
  __builtin_memcpy(&f, &v, 4);
  return f;
}
__device__ __forceinline__ unsigned short f2bf(float f) {
  __hip_bfloat16 h = __float2bfloat16(f);
  unsigned short u;
  __builtin_memcpy(&u, &h, 2);
  return u;
}
__device__ __forceinline__ float fast_sigmoid(float z) {
  return __builtin_amdgcn_rcpf(1.f + __expf(-z));
}
__device__ __forceinline__ float fast_tanh(float z) {
  float x2 = fminf(fmaxf(2.f * z, -30.f), 30.f);
  float e = __expf(x2);
  return (e - 1.f) * __builtin_amdgcn_rcpf(e + 1.f);
}
// async global->LDS, 16B per lane, dest = wave-uniform base + lane*16
__device__ __forceinline__ void stage16(const unsigned short* g, unsigned short* l) {
  __builtin_amdgcn_global_load_lds(
      (const __attribute__((address_space(1))) void*)g,
      (__attribute__((address_space(3))) void*)l, 16, 0, 0);
}

// ---------------- fused conv1 (3x3, CIN=1, COUT=64) + BN + 2x2 pool -> padded P1 ----------------
// grid: b*16 + y0 (1024); out P1 [64][18][130][64], interior only (halo pre-zeroed)
__global__ __launch_bounds__(256) void conv1_pool(
    const float* __restrict__ in, const float* __restrict__ w,
    const float* __restrict__ bias, const float* __restrict__ sc,
    const float* __restrict__ of, const float* __restrict__ mn,
    const float* __restrict__ vr, unsigned short* __restrict__ out) {
  __shared__ float lds[4][258];
  const int blk = blockIdx.x;
  const int b = blk >> 4, y0 = blk & 15;
  const int tid = threadIdx.x;
  for (int i = tid; i < 4 * 258; i += 256) {
    int row = i / 258, c = i - row * 258;
    int iy = 2 * y0 - 1 + row, xx = c - 1;
    float v = 0.f;
    if ((unsigned)iy < 32u && (unsigned)xx < 256u)
      v = in[((b << 5) + iy) * 256 + xx];
    lds[row][c] = v;
  }
  __syncthreads();
  const int co = tid & 63, xg = tid >> 6;
  float w9[9];
  #pragma unroll
  for (int t = 0; t < 9; ++t) w9[t] = w[t * 64 + co];
  const float scale = sc[co] * rsqrtf(vr[co] + EPSBN);
  const float shift = of[co] - mn[co] * scale;
  const float bs = bias[co];
  unsigned short* op = out + (((long)(b * 18 + y0 + 1) * 130 + xg * 32 + 1) << 6) + co;
  for (int px = 0; px < 32; ++px) {
    const int xp = xg * 32 + px;
    float m = -1e30f;
    #pragma unroll
    for (int dy = 0; dy < 2; ++dy) {
      #pragma unroll
      for (int dx = 0; dx < 2; ++dx) {
        const int x = 2 * xp + dx;
        float acc = bs;
        #pragma unroll
        for (int r = 0; r < 3; ++r)
          #pragma unroll
          for (int cc = 0; cc < 3; ++cc)
            acc = fmaf(lds[dy + r][x + cc], w9[r * 3 + cc], acc);
        float v = fmaxf(acc, 0.f) * scale + shift;
        m = fmaxf(m, v);
      }
    }
    op[(long)px << 6] = f2bf(m);
  }
}

// ---------------- 2x2 maxpool -> PADDED output (writes its own halo) ----------------
template<int C, int H2, int W2>
__global__ __launch_bounds__(256) void maxpool_pad(
    const unsigned short* __restrict__ in, unsigned short* __restrict__ out) {
  constexpr int W2P = W2 + 2, H2P = H2 + 2;
  const int y = blockIdx.y;
  const int b = y / H2P, yp = y - b * H2P;
  const int j = blockIdx.x * 256 + threadIdx.x;
  if (j >= W2P * C) return;
  const int xp = j / C, c = j - xp * C;
  unsigned short res = 0;
  if (yp >= 1 && yp <= H2 && xp >= 1 && xp <= W2) {
    const long rs = (long)(2 * W2) * C;
    const unsigned short* p0 =
        in + (((long)b * (2 * H2) + (yp - 1) * 2) * (2 * W2) + (xp - 1) * 2) * C + c;
    unsigned short u0 = p0[0], u1 = p0[C], u2 = p0[rs], u3 = p0[rs + C];
    unsigned short a = (bf2f(u0) >= bf2f(u1)) ? u0 : u1;
    unsigned short bmx = (bf2f(u2) >= bf2f(u3)) ? u2 : u3;
    res = (bf2f(a) >= bf2f(bmx)) ? a : bmx;
  }
  out[((long)y * W2P + xp) * C + c] = res;
}

// ---------------- generic transpose: fp32 [K][N] -> bf16 [N][K] ----------------
__global__ __launch_bounds__(256) void transpose_f32_bf16(
    const float* __restrict__ in, unsigned short* __restrict__ out, int K, int N) {
  __shared__ float T[32][33];
  int k0 = blockIdx.x * 32, n0 = blockIdx.y * 32;
  int tid = threadIdx.x;
  int r = tid >> 3, c4 = (tid & 7) * 4;
  float4 v = *(const float4*)(in + (long)(k0 + r) * N + n0 + c4);
  T[r][c4 + 0] = v.x; T[r][c4 + 1] = v.y; T[r][c4 + 2] = v.z; T[r][c4 + 3] = v.w;
  __syncthreads();
  us4 o;
  #pragma unroll
  for (int i = 0; i < 4; ++i) o[i] = f2bf(T[c4 + i][r]);
  *(us4*)(out + (long)(n0 + r) * K + k0 + c4) = o;
}

// ---------------- small transpose for FC weight: fp32 [1024][80] -> bf16 [80][1024] ----------------
__global__ __launch_bounds__(256) void transpose_fc(
    const float* __restrict__ W, unsigned short* __restrict__ WT) {
  int i = blockIdx.x * 256 + threadIdx.x;
  if (i < 80 * 1024) {
    int n = i >> 10, k = i & 1023;
    WT[i] = f2bf(W[k * 80 + n]);
  }
}

// ---------------- m97-style implicit-GEMM conv: 128x128 tile, BK=32 ----------------
template<int CIN, int COUT, int H, int W, int OUTPAD>
__global__ __launch_bounds__(256) void conv_mfma128(
    const unsigned short* __restrict__ act, const unsigned short* __restrict__ wT,
    const float* __restrict__ bias, const float* __restrict__ sc,
    const float* __restrict__ of, const float* __restrict__ mn,
    const float* __restrict__ vr, unsigned short* __restrict__ out) {
  constexpr int K9 = 9 * CIN;
  constexpr int HW = H * W;
  constexpr int WP = W + 2;
  __shared__ unsigned short As[128 * 32];
  __shared__ unsigned short Bs[128 * 32];
  const int tid = threadIdx.x;
  const int lane = tid & 63, wave = tid >> 6;
  const int m0 = blockIdx.x * 128, n0 = blockIdx.y * 128;
  const int r0 = tid >> 2, seg = tid & 3;
  const int segp = (seg ^ (r0 & 3)) << 3;
  long pa0, pa1;
  {
    const int m = m0 + r0;
    const int b = m / HW, rem = m % HW;
    const int y = rem / W, x = rem % W;
    pa0 = (((long)b * (H + 2) + y) * WP + x) * CIN + segp;
  }
  {
    const int m = m0 + r0 + 64;
    const int b = m / HW, rem = m % HW;
    const int y = rem / W, x = rem % W;
    pa1 = (((long)b * (H + 2) + y) * WP + x) * CIN + segp;
  }
  const long pb0 = (long)(n0 + r0) * K9 + segp;
  const long pb1 = (long)(n0 + r0 + 64) * K9 + segp;
  unsigned short* AsW = As + wave * 512;
  unsigned short* BsW = Bs + wave * 512;
  const int swz = ((lane >> 4) ^ (lane & 3)) << 3;
  const int arow0 = (wave >> 1) * 64 + (lane & 15);
  const int brow0 = (wave & 1) * 64 + (lane & 15);
  f32x4 acc[4][4] = {};

  #pragma unroll 1
  for (int tap = 0; tap < 9; ++tap) {
    const long aoff = (long)((tap / 3) * WP + (tap % 3)) * CIN;
    #pragma unroll 1
    for (int cib = 0; cib < CIN; cib += 32) {
      const long ka = aoff + cib;
      const long kb = (long)tap * CIN + cib;
      stage16(act + pa0 + ka, AsW);
      stage16(act + pa1 + ka, AsW + 2048);
      stage16(wT + pb0 + kb, BsW);
      stage16(wT + pb1 + kb, BsW + 2048);
      __syncthreads();
      short8 a[4], b[4];
      #pragma unroll
      for (int i = 0; i < 4; ++i)
        a[i] = *(const short8*)(As + (arow0 + i * 16) * 32 + swz);
      #pragma unroll
      for (int j = 0; j < 4; ++j)
        b[j] = *(const short8*)(Bs + (brow0 + j * 16) * 32 + swz);
      #pragma unroll
      for (int i = 0; i < 4; ++i)
        #pragma unroll
        for (int j = 0; j < 4; ++j)
          acc[i][j] = MFMA16(a[i], b[j], acc[i][j]);
      __syncthreads();
    }
  }

  float scl[4], shf[4], bsv[4];
  #pragma unroll
  for (int j = 0; j < 4; ++j) {
    const int col = n0 + (wave & 1) * 64 + j * 16 + (lane & 15);
    scl[j] = sc[col] * rsqrtf(vr[col] + EPSBN);
    shf[j] = of[col] - mn[col] * scl[j];
    bsv[j] = bias[col];
  }
  #pragma unroll
  for (int i = 0; i < 4; ++i) {
    #pragma unroll
    for (int rr = 0; rr < 4; ++rr) {
      const int m = m0 + (wave >> 1) * 64 + i * 16 + (lane >> 4) * 4 + rr;
      const int b = m / HW, rem = m % HW;
      const int y = rem / W, x = rem % W;
      long obase;
      if (OUTPAD) obase = (((long)b * (H + 2) + y + 1) * WP + x + 1) * COUT;
      else        obase = (((long)b * H + y) * W + x) * COUT;
      const int colb = n0 + (wave & 1) * 64 + (lane & 15);
      #pragma unroll
      for (int j = 0; j < 4; ++j) {
        const float v = fmaxf(acc[i][j][rr] + bsv[j], 0.f) * scl[j] + shf[j];
        out[obase + colb + j * 16] = f2bf(v);
      }
    }
  }
}

// ---------------- m97-style GEMM: xw = gather(x_seq) @ WiT^T + b ----------------
__global__ __launch_bounds__(256) void gemm_xw128(
    const unsigned short* __restrict__ src, const unsigned short* __restrict__ WiT,
    const float* __restrict__ bvec, float* __restrict__ xw, int rev) {
  __shared__ unsigned short As[128 * 32];
  __shared__ unsigned short Bs[128 * 32];
  const int tid = threadIdx.x;
  const int lane = tid & 63, wave = tid >> 6;
  const int m0 = blockIdx.x * 128, n0 = blockIdx.y * 128;
  const int r0 = tid >> 2, seg = tid & 3;
  const int segp = (seg ^ (r0 & 3)) << 3;
  long pa0, pa1;
  {
    const int r = m0 + r0;
    const int t = r >> 6, bb = r & 63;
    const int tt = rev ? 31 - t : t;
    pa0 = (long)bb * 65536 + (long)tt * 2048 + segp;
  }
  {
    const int r = m0 + r0 + 64;
    const int t = r >> 6, bb = r & 63;
    const int tt = rev ? 31 - t : t;
    pa1 = (long)bb * 65536 + (long)tt * 2048 + segp;
  }
  const long pb0 = (long)(n0 + r0) * 2048 + segp;
  const long pb1 = (long)(n0 + r0 + 64) * 2048 + segp;
  unsigned short* AsW = As + wave * 512;
  unsigned short* BsW = Bs + wave * 512;
  const int swz = ((lane >> 4) ^ (lane & 3)) << 3;
  const int arow0 = (wave >> 1) * 64 + (lane & 15);
  const int brow0 = (wave & 1) * 64 + (lane & 15);
  f32x4 acc[4][4] = {};

  #pragma unroll 1
  for (int ks = 0; ks < 64; ++ks) {
    const long k0 = (long)ks * 32;
    stage16(src + pa0 + k0, AsW);
    stage16(src + pa1 + k0, AsW + 2048);
    stage16(WiT + pb0 + k0, BsW);
    stage16(WiT + pb1 + k0, BsW + 2048);
    __syncthreads();
    short8 a[4], b[4];
    #pragma unroll
    for (int i = 0; i < 4; ++i)
      a[i] = *(const short8*)(As + (arow0 + i * 16) * 32 + swz);
    #pragma unroll
    for (int j = 0; j < 4; ++j)
      b[j] = *(const short8*)(Bs + (brow0 + j * 16) * 32 + swz);
    #pragma unroll
    for (int i = 0; i < 4; ++i)
      #pragma unroll
      for (int j = 0; j < 4; ++j)
        acc[i][j] = MFMA16(a[i], b[j], acc[i][j]);
    __syncthreads();
  }

  float bsv[4];
  #pragma unroll
  for (int j = 0; j < 4; ++j)
    bsv[j] = bvec[n0 + (wave & 1) * 64 + j * 16 + (lane & 15)];
  #pragma unroll
  for (int i = 0; i < 4; ++i) {
    #pragma unroll
    for (int rr = 0; rr < 4; ++rr) {
      const int row = m0 + (wave >> 1) * 64 + i * 16 + (lane >> 4) * 4 + rr;
      const int colb = n0 + (wave & 1) * 64 + (lane & 15);
      #pragma unroll
      for (int j = 0; j < 4; ++j)
        xw[(long)row * 2048 + colb + j * 16] = acc[i][j][rr] + bsv[j];
    }
  }
}

// ---------------- persistent bidirectional LSTM; flag-array grid barrier ----------------
// bar layout: int[2][32][16] — one 64B line per block, monotone values.
__global__ __launch_bounds__(256) void lstm_persist(
    const unsigned short* __restrict__ WhTF, const unsigned short* __restrict__ WhTB,
    const float* __restrict__ xwF, const float* __restrict__ xwB,
    unsigned short* __restrict__ hsF, unsigned short* __restrict__ hsB,
    int* __restrict__ bar) {
  __shared__ unsigned short Whs[64 * 512];
  __shared__ unsigned short Hs[64 * 512];
  __shared__ float Zs[4 * 64 * 16];
  const int bid = blockIdx.x;
  const int dir = bid >> 5;
  const int nb = bid & 31;
  const int u0 = nb * 16;
  const unsigned short* WhT = dir ? WhTB : WhTF;
  const float* xw = dir ? xwB : xwF;
  unsigned short* hs = dir ? hsB : hsF;
  int* flagbase = bar + dir * 32 * 16;
  int* myflag = flagbase + nb * 16;
  const int tid = threadIdx.x;
  const int lane = tid & 63, wave = tid >> 6;
  const int lr = lane & 15, lk = lane >> 4;
  const int mp = wave >> 1, gp = wave & 1;

  #pragma unroll
  for (int i = 0; i < 16; ++i) {
    const int G = i * 256 + tid;
    const int row = G >> 6, g8 = G & 63;
    const int g = row >> 4, u = row & 15;
    short8 v = *(const short8*)(WhT + ((long)(g * 512 + u0 + u) << 9) + g8 * 8);
    *(short8*)(Whs + row * 512 + ((g8 ^ (row & 7)) << 3)) = v;
  }

  const int prow = tid >> 2;
  const int pu4 = (tid & 3) * 4;
  float c4[4] = {0.f, 0.f, 0.f, 0.f};
  float4 xq[4];
  #pragma unroll
  for (int g = 0; g < 4; ++g)
    xq[g] = *(const float4*)(xw + (long)prow * 2048 + g * 512 + u0 + pu4);

  for (int t = 0; t < 32; ++t) {
    const unsigned short* hsrc = hs + (long)t * 32768;
    #pragma unroll
    for (int i = 0; i < 16; ++i) {
      const int G = i * 256 + tid;
      const int row = G >> 6, g8 = G & 63;
      short8 v = *(const short8*)(hsrc + G * 8);
      *(short8*)(Hs + row * 512 + ((g8 ^ (row & 7)) << 3)) = v;
    }
    __syncthreads();

    f32x4 acc[2][2] = {};
    #pragma unroll
    for (int kk = 0; kk < 16; ++kk) {
      const int sw = ((lk + kk * 4) ^ (lr & 7)) << 3;
      short8 a0 = *(const short8*)(Hs + (mp * 32 + lr) * 512 + sw);
      short8 a1 = *(const short8*)(Hs + (mp * 32 + 16 + lr) * 512 + sw);
      short8 b0 = *(const short8*)(Whs + (gp * 32 + lr) * 512 + sw);
      short8 b1 = *(const short8*)(Whs + (gp * 32 + 16 + lr) * 512 + sw);
      acc[0][0] = MFMA16(a0, b0, acc[0][0]);
      acc[0][1] = MFMA16(a0, b1, acc[0][1]);
      acc[1][0] = MFMA16(a1, b0, acc[1][0]);
      acc[1][1] = MFMA16(a1, b1, acc[1][1]);
    }

    #pragma unroll
    for (int im = 0; im < 2; ++im) {
      const int rowb = (mp * 2 + im) * 16 + lk * 4;
      #pragma unroll
      for (int ig = 0; ig < 2; ++ig) {
        const int g = gp * 2 + ig;
        #pragma unroll
        for (int r = 0; r < 4; ++r)
          Zs[g * 1024 + (rowb + r) * 16 + lr] = acc[im][ig][r];
      }
    }
    __syncthreads();

    {
      float4 zi = *(const float4*)(Zs + tid * 4);
      float4 zf = *(const float4*)(Zs + 1024 + tid * 4);
      float4 zg = *(const float4*)(Zs + 2048 + tid * 4);
      float4 zo = *(const float4*)(Zs + 3072 + tid * 4);
      const float* pzi = (const float*)&zi;
      const float* pzf = (const float*)&zf;
      const float* pzg = (const float*)&zg;
      const float* pzo = (const float*)&zo;
      us4 hv;
      #pragma unroll
      for (int r = 0; r < 4; ++r) {
        float ii = fast_sigmoid(pzi[r] + ((const float*)&xq[0])[r]);
        float ff = fast_sigmoid(pzf[r] + ((const float*)&xq[1])[r]);
        float gg = fast_tanh(pzg[r] + ((const float*)&xq[2])[r]);
        float oo = fast_sigmoid(pzo[r] + ((const float*)&xq[3])[r]);
        c4[r] = ff * c4[r] + ii * gg;
        hv[r] = f2bf(oo * fast_tanh(c4[r]));
      }
      *(us4*)(hs + (long)(t + 1) * 32768 + prow * 512 + u0 + pu4) = hv;
    }

    if (t < 31) {
      // prefetch next-step xw BEFORE the barrier (independent of h)
      float4 xqn[4];
      #pragma unroll
      for (int g = 0; g < 4; ++g)
        xqn[g] = *(const float4*)(xw + (long)((t + 1) * 64 + prow) * 2048 + g * 512 + u0 + pu4);
      __syncthreads();
      if (tid < 64) {
        if (tid == 0) {
          __threadfence();
          __hip_atomic_store(myflag, t + 1, __ATOMIC_RELEASE, __HIP_MEMORY_SCOPE_AGENT);
        }
        int v;
        do {
          v = __hip_atomic_load(flagbase + (tid & 31) * 16,
                                __ATOMIC_ACQUIRE, __HIP_MEMORY_SCOPE_AGENT);
        } while (__any(v < t + 1));
      }
      __syncthreads();
      #pragma unroll
      for (int g = 0; g < 4; ++g) xq[g] = xqn[g];
    }
  }
}

// ---------------- MFMA FC (M=128,N=80,K=1024) + fused log_softmax ----------------
__global__ __launch_bounds__(256) void fc_mfma_ls(
    const unsigned short* __restrict__ hsF, const unsigned short* __restrict__ hsB,
    const unsigned short* __restrict__ WT, const float* __restrict__ bias,
    float* __restrict__ out) {
  __shared__ unsigned short As_[128 * 32];
  __shared__ unsigned short Bs_[80 * 32];
  __shared__ float zbuf[128][81];
  __shared__ float rmax[128];
  __shared__ float rlse[128];
  const int tid = threadIdx.x;
  const int lane = tid & 63, wave = tid >> 6;
  const int m0 = blockIdx.x * 128;
  const int r0 = tid >> 2, seg = tid & 3;
  const int segp = (seg ^ (r0 & 3)) << 3;
  const int swz = ((lane >> 4) ^ (lane & 3)) << 3;
  f32x4 acc[2][5] = {};

  int bA0, tA0, bA1, tA1;
  { int r = m0 + r0;      bA0 = r >> 5; tA0 = r & 31; }
  { int r = m0 + r0 + 64; bA1 = r >> 5; tA1 = r & 31; }

  #pragma unroll 1
  for (int k0 = 0; k0 < 1024; k0 += 32) {
    const unsigned short* src = (k0 < 512) ? hsF : hsB;
    const int koff = k0 & 511;
    stage16(src + (long)(tA0 + 1) * 32768 + bA0 * 512 + koff + segp, As_ + wave * 512);
    stage16(src + (long)(tA1 + 1) * 32768 + bA1 * 512 + koff + segp, As_ + wave * 512 + 2048);
    {
      int G = tid;
      #pragma unroll
      for (int it = 0; it < 2; ++it, G += 256) {
        int rn = G >> 2, sg = G & 3;
        if (rn < 80) {
          short8 v = *(const short8*)(WT + (long)rn * 1024 + k0 + sg * 8);
          *(short8*)(Bs_ + rn * 32 + ((sg ^ (rn & 3)) << 3)) = v;
        }
      }
    }
    __syncthreads();
    short8 a[2], bfrag[5];
    #pragma unroll
    for (int i = 0; i < 2; ++i)
      a[i] = *(const short8*)(As_ + (wave * 32 + i * 16 + (lane & 15)) * 32 + swz);
    #pragma unroll
    for (int j = 0; j < 5; ++j)
      bfrag[j] = *(const short8*)(Bs_ + (j * 16 + (lane & 15)) * 32 + swz);
    #pragma unroll
    for (int i = 0; i < 2; ++i)
      #pragma unroll
      for (int j = 0; j < 5; ++j)
        acc[i][j] = MFMA16(a[i], bfrag[j], acc[i][j]);
    __syncthreads();
  }

  float bsv[5];
  #pragma unroll
  for (int j = 0; j < 5; ++j) bsv[j] = bias[j * 16 + (lane & 15)];
  #pragma unroll
  for (int i = 0; i < 2; ++i)
    #pragma unroll
    for (int j = 0; j < 5; ++j)
      #pragma unroll
      for (int rr = 0; rr < 4; ++rr)
        zbuf[wave * 32 + i * 16 + (lane >> 4) * 4 + rr][j * 16 + (lane & 15)] =
            acc[i][j][rr] + bsv[j];
  __syncthreads();

  if (tid < 128) {
    float mx = -1e30f;
    for (int j = 0; j < 80; ++j) mx = fmaxf(mx, zbuf[tid][j]);
    float s = 0.f;
    for (int j = 0; j < 80; ++j) s += __expf(zbuf[tid][j] - mx);
    rmax[tid] = mx;
    rlse[tid] = logf(s);
  }
  __syncthreads();

  for (int idx = tid; idx < 128 * 80; idx += 256) {
    const int row = idx / 80, j = idx - row * 80;
    out[(long)m0 * 80 + idx] = zbuf[row][j] - rmax[row] - rlse[row];
  }
}

__global__ __launch_bounds__(256) void zero_kernel(float* p, int n) {
  int i = blockIdx.x * 256 + threadIdx.x;
  if (i < n) p[i] = 0.f;
}

extern "C" void kernel_launch(void* const* d_in, const int* in_sizes, int n_in,
                              void* d_out, int out_size, void* d_ws, size_t ws_size,
                              hipStream_t stream) {
  const float* x  = (const float*)d_in[0];
  const float* k1 = (const float*)d_in[1];  const float* b1 = (const float*)d_in[2];
  const float* s1 = (const float*)d_in[3];  const float* o1 = (const float*)d_in[4];
  const float* m1 = (const float*)d_in[5];  const float* v1 = (const float*)d_in[6];
  const float* k2 = (const float*)d_in[7];  const float* b2 = (const float*)d_in[8];
  const float* s2 = (const float*)d_in[9];  const float* o2 = (const float*)d_in[10];
  const float* m2 = (const float*)d_in[11]; const float* v2 = (const float*)d_in[12];
  const float* k3 = (const float*)d_in[13]; const float* b3 = (const float*)d_in[14];
  const float* s3 = (const float*)d_in[15]; const float* o3 = (const float*)d_in[16];
  const float* m3 = (const float*)d_in[17]; const float* v3 = (const float*)d_in[18];
  const float* k4 = (const float*)d_in[19]; const float* b4 = (const float*)d_in[20];
  const float* s4 = (const float*)d_in[21]; const float* o4 = (const float*)d_in[22];
  const float* m4 = (const float*)d_in[23]; const float* v4 = (const float*)d_in[24];
  const float* k5 = (const float*)d_in[25]; const float* b5 = (const float*)d_in[26];
  const float* s5 = (const float*)d_in[27]; const float* o5 = (const float*)d_in[28];
  const float* m5 = (const float*)d_in[29]; const float* v5 = (const float*)d_in[30];
  const float* fwWi = (const float*)d_in[31];
  const float* fwWh = (const float*)d_in[32];
  const float* fwb  = (const float*)d_in[33];
  const float* bwWi = (const float*)d_in[34];
  const float* bwWh = (const float*)d_in[35];
  const float* bwb  = (const float*)d_in[36];
  const float* fcW  = (const float*)d_in[37];
  const float* fcb  = (const float*)d_in[38];

  char* wsb = (char*)d_ws;
  unsigned short* REG_A = (unsigned short*)(wsb);                  // 33,554,432 B (C2/C3/C5)
  unsigned short* REG_P = (unsigned short*)(wsb + 33554432);       // 19,169,280 B (P1/P2/P3)
  unsigned short* C4    = (unsigned short*)(wsb + 52723712);       //  6,684,672 B padded
  unsigned short* wT    = (unsigned short*)(wsb + 59408384);       //  2,359,296 B
  unsigned short* WiTF  = (unsigned short*)(wsb + 61767680);       //  8,388,608 B
  unsigned short* WiTB  = (unsigned short*)(wsb + 70156288);       //  8,388,608 B
  unsigned short* WhTF  = (unsigned short*)(wsb + 78544896);       //  2,097,152 B
  unsigned short* WhTB  = (unsigned short*)(wsb + 80642048);       //  2,097,152 B
  unsigned short* WTfc  = (unsigned short*)(wsb + 82739200);       //    163,840 B
  float* xwF = (float*)(wsb + 82903040);                           // 16,777,216 B
  float* xwB = (float*)(wsb + 99680256);                           // 16,777,216 B
  int*   bar = (int*)(wsb + 116457472);                            //      4,096 B
  unsigned short* hsF = (unsigned short*)(wsb + 116461568);        // [33][64][512]
  unsigned short* hsB = (unsigned short*)(wsb + 118624256);

  // zeros: bar+hsF slab0 (contiguous: 1024 + 16384 floats), hsB slab0, C4, P1
  zero_kernel<<<68, 256, 0, stream>>>((float*)(wsb + 116457472), 17408);
  zero_kernel<<<64, 256, 0, stream>>>((float*)(wsb + 118624256), 16384);
  zero_kernel<<<6528, 256, 0, stream>>>((float*)(wsb + 52723712), 1671168);
  zero_kernel<<<18720, 256, 0, stream>>>((float*)(wsb + 33554432), 4792320);

  // fused conv1+pool1 -> P1 padded [64,18,130,64]
  conv1_pool<<<1024, 256, 0, stream>>>(x, k1, b1, s1, o1, m1, v1, REG_P);

  // conv2: P1 -> C2 [64,16,128,128]
  transpose_f32_bf16<<<dim3(18, 4), 256, 0, stream>>>(k2, wT, 576, 128);
  conv_mfma128<64, 128, 16, 128, 0><<<dim3(1024, 1), 256, 0, stream>>>(
      REG_P, wT, b2, s2, o2, m2, v2, REG_A);
  // pool2 -> P2 padded [64,10,66,128]
  maxpool_pad<128, 8, 64><<<dim3(33, 640), 256, 0, stream>>>(REG_A, REG_P);

  // conv3: P2 -> C3 [64,8,64,256]
  transpose_f32_bf16<<<dim3(36, 8), 256, 0, stream>>>(k3, wT, 1152, 256);
  conv_mfma128<128, 256, 8, 64, 0><<<dim3(256, 2), 256, 0, stream>>>(
      REG_P, wT, b3, s3, o3, m3, v3, REG_A);
  // pool3 -> P3 padded [64,6,34,256]
  maxpool_pad<256, 4, 32><<<dim3(34, 384), 256, 0, stream>>>(REG_A, REG_P);

  // conv4: P3 -> C4 PADDED [64,6,34,256]
  transpose_f32_bf16<<<dim3(72, 8), 256, 0, stream>>>(k4, wT, 2304, 256);
  conv_mfma128<256, 256, 4, 32, 1><<<dim3(64, 2), 256, 0, stream>>>(
      REG_P, wT, b4, s4, o4, m4, v4, C4);

  // conv5: C4 -> C5 [64,4,32,512]
  transpose_f32_bf16<<<dim3(72, 16), 256, 0, stream>>>(k5, wT, 2304, 512);
  conv_mfma128<256, 512, 4, 32, 0><<<dim3(64, 4), 256, 0, stream>>>(
      C4, wT, b5, s5, o5, m5, v5, REG_A);

  // xw precompute (layer 1 only — reference keeps only last layer)
  transpose_f32_bf16<<<dim3(64, 64), 256, 0, stream>>>(fwWi + 4194304, WiTF, 2048, 2048);
  transpose_f32_bf16<<<dim3(64, 64), 256, 0, stream>>>(bwWi + 4194304, WiTB, 2048, 2048);
  gemm_xw128<<<dim3(16, 16), 256, 0, stream>>>(REG_A, WiTF, fwb + 2048, xwF, 0);
  gemm_xw128<<<dim3(16, 16), 256, 0, stream>>>(REG_A, WiTB, bwb + 2048, xwB, 1);

  // Wh transposed bf16 (layer 1) + FC weight
  transpose_f32_bf16<<<dim3(16, 64), 256, 0, stream>>>(fwWh + 1048576, WhTF, 512, 2048);
  transpose_f32_bf16<<<dim3(16, 64), 256, 0, stream>>>(bwWh + 1048576, WhTB, 512, 2048);
  transpose_fc<<<320, 256, 0, stream>>>(fcW, WTfc);

  // all 32 LSTM steps, both directions, single launch
  lstm_persist<<<64, 256, 0, stream>>>(WhTF, WhTB, xwF, xwB, hsF, hsB, bar);

  // FC + log_softmax
  fc_mfma_ls<<<16, 256, 0, stream>>>(hsF, hsB, WTfc, fcb, (float*)d_out);
}

// Round 7
// 499.022 us; speedup vs baseline: 15.5926x; 1.1420x over previous
//
#include <hip/hip_runtime.h>
#include <hip/hip_bf16.h>
#include <math.h>

#define EPSBN 1e-5f

using short8 = __attribute__((ext_vector_type(8))) short;
using f32x4  = __attribute__((ext_vector_type(4))) float;
using us4    = __attribute__((ext_vector_type(4))) unsigned short;

#define MFMA16(a, b, c) __builtin_amdgcn_mfma_f32_16x16x32_bf16(a, b, c, 0, 0, 0)

__device__ __forceinline__ float bf2f(unsigned short u) {
  unsigned int v = ((unsigned int)u) << 16;
  float f;
  __builtin_memcpy(&f, &v, 4);
  return f;
}
__device__ __forceinline__ unsigned short f2bf(float f) {
  __hip_bfloat16 h = __float2bfloat16(f);
  unsigned short u;
  __builtin_memcpy(&u, &h, 2);
  return u;
}
__device__ __forceinline__ float fast_sigmoid(float z) {
  return __builtin_amdgcn_rcpf(1.f + __expf(-z));
}
__device__ __forceinline__ float fast_tanh(float z) {
  float x2 = fminf(fmaxf(2.f * z, -30.f), 30.f);
  float e = __expf(x2);
  return (e - 1.f) * __builtin_amdgcn_rcpf(e + 1.f);
}
// async global->LDS, 16B per lane, dest = wave-uniform base + lane*16
__device__ __forceinline__ void stage16(const unsigned short* g, unsigned short* l) {
  __builtin_amdgcn_global_load_lds(
      (const __attribute__((address_space(1))) void*)g,
      (__attribute__((address_space(3))) void*)l, 16, 0, 0);
}

// ---------------- fused conv1 (3x3, CIN=1, COUT=64) + BN + 2x2 pool -> padded P1 ----------------
__global__ __launch_bounds__(256) void conv1_pool(
    const float* __restrict__ in, const float* __restrict__ w,
    const float* __restrict__ bias, const float* __restrict__ sc,
    const float* __restrict__ of, const float* __restrict__ mn,
    const float* __restrict__ vr, unsigned short* __restrict__ out) {
  __shared__ float lds[4][258];
  const int blk = blockIdx.x;
  const int b = blk >> 4, y0 = blk & 15;
  const int tid = threadIdx.x;
  for (int i = tid; i < 4 * 258; i += 256) {
    int row = i / 258, c = i - row * 258;
    int iy = 2 * y0 - 1 + row, xx = c - 1;
    float v = 0.f;
    if ((unsigned)iy < 32u && (unsigned)xx < 256u)
      v = in[((b << 5) + iy) * 256 + xx];
    lds[row][c] = v;
  }
  __syncthreads();
  const int co = tid & 63, xg = tid >> 6;
  float w9[9];
  #pragma unroll
  for (int t = 0; t < 9; ++t) w9[t] = w[t * 64 + co];
  const float scale = sc[co] * rsqrtf(vr[co] + EPSBN);
  const float shift = of[co] - mn[co] * scale;
  const float bs = bias[co];
  unsigned short* op = out + (((long)(b * 18 + y0 + 1) * 130 + xg * 32 + 1) << 6) + co;
  for (int px = 0; px < 32; ++px) {
    const int xp = xg * 32 + px;
    float m = -1e30f;
    #pragma unroll
    for (int dy = 0; dy < 2; ++dy) {
      #pragma unroll
      for (int dx = 0; dx < 2; ++dx) {
        const int x = 2 * xp + dx;
        float acc = bs;
        #pragma unroll
        for (int r = 0; r < 3; ++r)
          #pragma unroll
          for (int cc = 0; cc < 3; ++cc)
            acc = fmaf(lds[dy + r][x + cc], w9[r * 3 + cc], acc);
        float v = fmaxf(acc, 0.f) * scale + shift;
        m = fmaxf(m, v);
      }
    }
    op[(long)px << 6] = f2bf(m);
  }
}

// ---------------- 2x2 maxpool -> PADDED output (writes its own halo) ----------------
template<int C, int H2, int W2>
__global__ __launch_bounds__(256) void maxpool_pad(
    const unsigned short* __restrict__ in, unsigned short* __restrict__ out) {
  constexpr int W2P = W2 + 2, H2P = H2 + 2;
  const int y = blockIdx.y;
  const int b = y / H2P, yp = y - b * H2P;
  const int j = blockIdx.x * 256 + threadIdx.x;
  if (j >= W2P * C) return;
  const int xp = j / C, c = j - xp * C;
  unsigned short res = 0;
  if (yp >= 1 && yp <= H2 && xp >= 1 && xp <= W2) {
    const long rs = (long)(2 * W2) * C;
    const unsigned short* p0 =
        in + (((long)b * (2 * H2) + (yp - 1) * 2) * (2 * W2) + (xp - 1) * 2) * C + c;
    unsigned short u0 = p0[0], u1 = p0[C], u2 = p0[rs], u3 = p0[rs + C];
    unsigned short a = (bf2f(u0) >= bf2f(u1)) ? u0 : u1;
    unsigned short bmx = (bf2f(u2) >= bf2f(u3)) ? u2 : u3;
    res = (bf2f(a) >= bf2f(bmx)) ? a : bmx;
  }
  out[((long)y * W2P + xp) * C + c] = res;
}

// ---------------- merged weight transposes: fp32 [K][N] -> bf16 [N][K], 8 at once ----------------
struct TAll {
  const float* src[8];
  unsigned short* dst[8];
  int K[8];
  int N[8];
};
__global__ __launch_bounds__(256) void transpose_multi(TAll P) {
  const int z = blockIdx.z;
  const int K = P.K[z], N = P.N[z];
  const int k0 = blockIdx.x * 32, n0 = blockIdx.y * 32;
  if (k0 >= K || n0 >= N) return;
  __shared__ float T[32][33];
  const float* in = P.src[z];
  unsigned short* out = P.dst[z];
  const int tid = threadIdx.x;
  const int r = tid >> 3, c4 = (tid & 7) * 4;
  float4 v = *(const float4*)(in + (long)(k0 + r) * N + n0 + c4);
  T[r][c4 + 0] = v.x; T[r][c4 + 1] = v.y; T[r][c4 + 2] = v.z; T[r][c4 + 3] = v.w;
  __syncthreads();
  us4 o;
  #pragma unroll
  for (int i = 0; i < 4; ++i) o[i] = f2bf(T[c4 + i][r]);
  *(us4*)(out + (long)(n0 + r) * K + k0 + c4) = o;
}

// ---------------- small transpose for FC weight: fp32 [1024][80] -> bf16 [80][1024] ----------------
__global__ __launch_bounds__(256) void transpose_fc(
    const float* __restrict__ W, unsigned short* __restrict__ WT) {
  int i = blockIdx.x * 256 + threadIdx.x;
  if (i < 80 * 1024) {
    int n = i >> 10, k = i & 1023;
    WT[i] = f2bf(W[k * 80 + n]);
  }
}

// ---------------- merged zero init: 4 regions, grid-stride ----------------
__global__ __launch_bounds__(256) void zero_multi(
    float* p0, long n0, float* p1, long n1, float* p2, long n2, float* p3, long n3) {
  const long i0 = (long)blockIdx.x * 256 + threadIdx.x;
  const long st = (long)gridDim.x * 256;
  for (long j = i0; j < n0; j += st) p0[j] = 0.f;
  for (long j = i0; j < n1; j += st) p1[j] = 0.f;
  for (long j = i0; j < n2; j += st) p2[j] = 0.f;
  for (long j = i0; j < n3; j += st) p3[j] = 0.f;
}

// ---------------- 2-phase pipelined implicit-GEMM conv: 128x128 tile, BK=32 ----------------
// act: PADDED [B][H+2][W+2][CIN] bf16. wT: [COUT][9*CIN] bf16.
// double-buffered LDS + counted vmcnt + raw s_barrier (T3 minimum 2-phase).
template<int CIN, int COUT, int H, int W, int OUTPAD>
__global__ __launch_bounds__(256) void conv_mfma128(
    const unsigned short* __restrict__ act, const unsigned short* __restrict__ wT,
    const float* __restrict__ bias, const float* __restrict__ sc,
    const float* __restrict__ of, const float* __restrict__ mn,
    const float* __restrict__ vr, unsigned short* __restrict__ out) {
  constexpr int K9 = 9 * CIN;
  constexpr int HW = H * W;
  constexpr int WP = W + 2;
  constexpr int NK = K9 / 32;
  constexpr int CSH = (CIN == 64) ? 1 : (CIN == 128) ? 2 : 3;
  constexpr int CMSK = (1 << CSH) - 1;
  __shared__ unsigned short As[2][4096];
  __shared__ unsigned short Bs[2][4096];
  const int tid = threadIdx.x;
  const int lane = tid & 63, wave = tid >> 6;
  const int m0 = blockIdx.x * 128, n0 = blockIdx.y * 128;
  const int r0 = tid >> 2, seg = tid & 3;
  const int segp = (seg ^ (r0 & 3)) << 3;
  long pa0, pa1;
  {
    const int m = m0 + r0;
    const int b = m / HW, rem = m % HW;
    const int y = rem / W, x = rem % W;
    pa0 = (((long)b * (H + 2) + y) * WP + x) * CIN + segp;
  }
  {
    const int m = m0 + r0 + 64;
    const int b = m / HW, rem = m % HW;
    const int y = rem / W, x = rem % W;
    pa1 = (((long)b * (H + 2) + y) * WP + x) * CIN + segp;
  }
  const long pb0 = (long)(n0 + r0) * K9 + segp;
  const long pb1 = (long)(n0 + r0 + 64) * K9 + segp;
  const int swz = ((lane >> 4) ^ (lane & 3)) << 3;
  const int arow0 = (wave >> 1) * 64 + (lane & 15);
  const int brow0 = (wave & 1) * 64 + (lane & 15);
  f32x4 acc[4][4] = {};

  auto stage_tile = [&](int ks, int buf) {
    const int tap = ks >> CSH;
    const int cib = (ks & CMSK) << 5;
    const int ty = (tap * 86) >> 8;          // tap/3 for tap<9
    const int tx = tap - ty * 3;
    const long ka = (long)(ty * WP + tx) * CIN + cib;
    const long kb = (long)ks << 5;
    unsigned short* aw = &As[buf][wave * 512];
    unsigned short* bw = &Bs[buf][wave * 512];
    stage16(act + pa0 + ka, aw);
    stage16(act + pa1 + ka, aw + 2048);
    stage16(wT + pb0 + kb, bw);
    stage16(wT + pb1 + kb, bw + 2048);
  };

  stage_tile(0, 0);
  #pragma unroll 1
  for (int ks = 0; ks < NK; ++ks) {
    const int buf = ks & 1;
    if (ks + 1 < NK) {
      stage_tile(ks + 1, buf ^ 1);
      asm volatile("s_waitcnt vmcnt(4)" ::: "memory");
    } else {
      asm volatile("s_waitcnt vmcnt(0)" ::: "memory");
    }
    __builtin_amdgcn_s_barrier();
    __builtin_amdgcn_sched_barrier(0);
    short8 a[4], b[4];
    #pragma unroll
    for (int i = 0; i < 4; ++i)
      a[i] = *(const short8*)(&As[buf][(arow0 + i * 16) * 32 + swz]);
    #pragma unroll
    for (int j = 0; j < 4; ++j)
      b[j] = *(const short8*)(&Bs[buf][(brow0 + j * 16) * 32 + swz]);
    #pragma unroll
    for (int i = 0; i < 4; ++i)
      #pragma unroll
      for (int j = 0; j < 4; ++j)
        acc[i][j] = MFMA16(a[i], b[j], acc[i][j]);
    __builtin_amdgcn_s_barrier();
    __builtin_amdgcn_sched_barrier(0);
  }

  float scl[4], shf[4], bsv[4];
  #pragma unroll
  for (int j = 0; j < 4; ++j) {
    const int col = n0 + (wave & 1) * 64 + j * 16 + (lane & 15);
    scl[j] = sc[col] * rsqrtf(vr[col] + EPSBN);
    shf[j] = of[col] - mn[col] * scl[j];
    bsv[j] = bias[col];
  }
  #pragma unroll
  for (int i = 0; i < 4; ++i) {
    #pragma unroll
    for (int rr = 0; rr < 4; ++rr) {
      const int m = m0 + (wave >> 1) * 64 + i * 16 + (lane >> 4) * 4 + rr;
      const int b = m / HW, rem = m % HW;
      const int y = rem / W, x = rem % W;
      long obase;
      if (OUTPAD) obase = (((long)b * (H + 2) + y + 1) * WP + x + 1) * COUT;
      else        obase = (((long)b * H + y) * W + x) * COUT;
      const int colb = n0 + (wave & 1) * 64 + (lane & 15);
      #pragma unroll
      for (int j = 0; j < 4; ++j) {
        const float v = fmaxf(acc[i][j][rr] + bsv[j], 0.f) * scl[j] + shf[j];
        out[obase + colb + j * 16] = f2bf(v);
      }
    }
  }
}

// ---------------- 2-phase pipelined GEMM: xw = gather(x_seq) @ WiT^T + b ----------------
__global__ __launch_bounds__(256) void gemm_xw128(
    const unsigned short* __restrict__ src, const unsigned short* __restrict__ WiT,
    const float* __restrict__ bvec, float* __restrict__ xw, int rev) {
  __shared__ unsigned short As[2][4096];
  __shared__ unsigned short Bs[2][4096];
  const int tid = threadIdx.x;
  const int lane = tid & 63, wave = tid >> 6;
  const int m0 = blockIdx.x * 128, n0 = blockIdx.y * 128;
  const int r0 = tid >> 2, seg = tid & 3;
  const int segp = (seg ^ (r0 & 3)) << 3;
  long pa0, pa1;
  {
    const int r = m0 + r0;
    const int t = r >> 6, bb = r & 63;
    const int tt = rev ? 31 - t : t;
    pa0 = (long)bb * 65536 + (long)tt * 2048 + segp;
  }
  {
    const int r = m0 + r0 + 64;
    const int t = r >> 6, bb = r & 63;
    const int tt = rev ? 31 - t : t;
    pa1 = (long)bb * 65536 + (long)tt * 2048 + segp;
  }
  const long pb0 = (long)(n0 + r0) * 2048 + segp;
  const long pb1 = (long)(n0 + r0 + 64) * 2048 + segp;
  const int swz = ((lane >> 4) ^ (lane & 3)) << 3;
  const int arow0 = (wave >> 1) * 64 + (lane & 15);
  const int brow0 = (wave & 1) * 64 + (lane & 15);
  f32x4 acc[4][4] = {};

  auto stage_tile = [&](int ks, int buf) {
    const long k0 = (long)ks << 5;
    unsigned short* aw = &As[buf][wave * 512];
    unsigned short* bw = &Bs[buf][wave * 512];
    stage16(src + pa0 + k0, aw);
    stage16(src + pa1 + k0, aw + 2048);
    stage16(WiT + pb0 + k0, bw);
    stage16(WiT + pb1 + k0, bw + 2048);
  };

  stage_tile(0, 0);
  #pragma unroll 1
  for (int ks = 0; ks < 64; ++ks) {
    const int buf = ks & 1;
    if (ks + 1 < 64) {
      stage_tile(ks + 1, buf ^ 1);
      asm volatile("s_waitcnt vmcnt(4)" ::: "memory");
    } else {
      asm volatile("s_waitcnt vmcnt(0)" ::: "memory");
    }
    __builtin_amdgcn_s_barrier();
    __builtin_amdgcn_sched_barrier(0);
    short8 a[4], b[4];
    #pragma unroll
    for (int i = 0; i < 4; ++i)
      a[i] = *(const short8*)(&As[buf][(arow0 + i * 16) * 32 + swz]);
    #pragma unroll
    for (int j = 0; j < 4; ++j)
      b[j] = *(const short8*)(&Bs[buf][(brow0 + j * 16) * 32 + swz]);
    #pragma unroll
    for (int i = 0; i < 4; ++i)
      #pragma unroll
      for (int j = 0; j < 4; ++j)
        acc[i][j] = MFMA16(a[i], b[j], acc[i][j]);
    __builtin_amdgcn_s_barrier();
    __builtin_amdgcn_sched_barrier(0);
  }

  float bsv[4];
  #pragma unroll
  for (int j = 0; j < 4; ++j)
    bsv[j] = bvec[n0 + (wave & 1) * 64 + j * 16 + (lane & 15)];
  #pragma unroll
  for (int i = 0; i < 4; ++i) {
    #pragma unroll
    for (int rr = 0; rr < 4; ++rr) {
      const int row = m0 + (wave >> 1) * 64 + i * 16 + (lane >> 4) * 4 + rr;
      const int colb = n0 + (wave & 1) * 64 + (lane & 15);
      #pragma unroll
      for (int j = 0; j < 4; ++j)
        xw[(long)row * 2048 + colb + j * 16] = acc[i][j][rr] + bsv[j];
    }
  }
}

// ---------------- persistent bidirectional LSTM; flag-array grid barrier ----------------
__global__ __launch_bounds__(256) void lstm_persist(
    const unsigned short* __restrict__ WhTF, const unsigned short* __restrict__ WhTB,
    const float* __restrict__ xwF, const float* __restrict__ xwB,
    unsigned short* __restrict__ hsF, unsigned short* __restrict__ hsB,
    int* __restrict__ bar) {
  __shared__ unsigned short Whs[64 * 512];
  __shared__ unsigned short Hs[64 * 512];
  __shared__ float Zs[4 * 64 * 16];
  const int bid = blockIdx.x;
  const int dir = bid >> 5;
  const int nb = bid & 31;
  const int u0 = nb * 16;
  const unsigned short* WhT = dir ? WhTB : WhTF;
  const float* xw = dir ? xwB : xwF;
  unsigned short* hs = dir ? hsB : hsF;
  int* flagbase = bar + dir * 32 * 16;
  int* myflag = flagbase + nb * 16;
  const int tid = threadIdx.x;
  const int lane = tid & 63, wave = tid >> 6;
  const int lr = lane & 15, lk = lane >> 4;
  const int mp = wave >> 1, gp = wave & 1;

  #pragma unroll
  for (int i = 0; i < 16; ++i) {
    const int G = i * 256 + tid;
    const int row = G >> 6, g8 = G & 63;
    const int g = row >> 4, u = row & 15;
    short8 v = *(const short8*)(WhT + ((long)(g * 512 + u0 + u) << 9) + g8 * 8);
    *(short8*)(Whs + row * 512 + ((g8 ^ (row & 7)) << 3)) = v;
  }

  const int prow = tid >> 2;
  const int pu4 = (tid & 3) * 4;
  float c4[4] = {0.f, 0.f, 0.f, 0.f};
  float4 xq[4];
  #pragma unroll
  for (int g = 0; g < 4; ++g)
    xq[g] = *(const float4*)(xw + (long)prow * 2048 + g * 512 + u0 + pu4);

  for (int t = 0; t < 32; ++t) {
    const unsigned short* hsrc = hs + (long)t * 32768;
    #pragma unroll
    for (int i = 0; i < 16; ++i) {
      const int G = i * 256 + tid;
      const int row = G >> 6, g8 = G & 63;
      short8 v = *(const short8*)(hsrc + G * 8);
      *(short8*)(Hs + row * 512 + ((g8 ^ (row & 7)) << 3)) = v;
    }
    __syncthreads();

    f32x4 acc[2][2] = {};
    #pragma unroll
    for (int kk = 0; kk < 16; ++kk) {
      const int sw = ((lk + kk * 4) ^ (lr & 7)) << 3;
      short8 a0 = *(const short8*)(Hs + (mp * 32 + lr) * 512 + sw);
      short8 a1 = *(const short8*)(Hs + (mp * 32 + 16 + lr) * 512 + sw);
      short8 b0 = *(const short8*)(Whs + (gp * 32 + lr) * 512 + sw);
      short8 b1 = *(const short8*)(Whs + (gp * 32 + 16 + lr) * 512 + sw);
      acc[0][0] = MFMA16(a0, b0, acc[0][0]);
      acc[0][1] = MFMA16(a0, b1, acc[0][1]);
      acc[1][0] = MFMA16(a1, b0, acc[1][0]);
      acc[1][1] = MFMA16(a1, b1, acc[1][1]);
    }

    #pragma unroll
    for (int im = 0; im < 2; ++im) {
      const int rowb = (mp * 2 + im) * 16 + lk * 4;
      #pragma unroll
      for (int ig = 0; ig < 2; ++ig) {
        const int g = gp * 2 + ig;
        #pragma unroll
        for (int r = 0; r < 4; ++r)
          Zs[g * 1024 + (rowb + r) * 16 + lr] = acc[im][ig][r];
      }
    }
    __syncthreads();

    {
      float4 zi = *(const float4*)(Zs + tid * 4);
      float4 zf = *(const float4*)(Zs + 1024 + tid * 4);
      float4 zg = *(const float4*)(Zs + 2048 + tid * 4);
      float4 zo = *(const float4*)(Zs + 3072 + tid * 4);
      const float* pzi = (const float*)&zi;
      const float* pzf = (const float*)&zf;
      const float* pzg = (const float*)&zg;
      const float* pzo = (const float*)&zo;
      us4 hv;
      #pragma unroll
      for (int r = 0; r < 4; ++r) {
        float ii = fast_sigmoid(pzi[r] + ((const float*)&xq[0])[r]);
        float ff = fast_sigmoid(pzf[r] + ((const float*)&xq[1])[r]);
        float gg = fast_tanh(pzg[r] + ((const float*)&xq[2])[r]);
        float oo = fast_sigmoid(pzo[r] + ((const float*)&xq[3])[r]);
        c4[r] = ff * c4[r] + ii * gg;
        hv[r] = f2bf(oo * fast_tanh(c4[r]));
      }
      *(us4*)(hs + (long)(t + 1) * 32768 + prow * 512 + u0 + pu4) = hv;
    }

    if (t < 31) {
      float4 xqn[4];
      #pragma unroll
      for (int g = 0; g < 4; ++g)
        xqn[g] = *(const float4*)(xw + (long)((t + 1) * 64 + prow) * 2048 + g * 512 + u0 + pu4);
      __syncthreads();
      if (tid < 64) {
        if (tid == 0)
          __hip_atomic_store(myflag, t + 1, __ATOMIC_RELEASE, __HIP_MEMORY_SCOPE_AGENT);
        int v;
        do {
          v = __hip_atomic_load(flagbase + (tid & 31) * 16,
                                __ATOMIC_ACQUIRE, __HIP_MEMORY_SCOPE_AGENT);
        } while (__any(v < t + 1));
      }
      __syncthreads();
      #pragma unroll
      for (int g = 0; g < 4; ++g) xq[g] = xqn[g];
    }
  }
}

// ---------------- MFMA FC (M=128,N=80,K=1024) + fused log_softmax ----------------
__global__ __launch_bounds__(256) void fc_mfma_ls(
    const unsigned short* __restrict__ hsF, const unsigned short* __restrict__ hsB,
    const unsigned short* __restrict__ WT, const float* __restrict__ bias,
    float* __restrict__ out) {
  __shared__ unsigned short As_[128 * 32];
  __shared__ unsigned short Bs_[80 * 32];
  __shared__ float zbuf[128][81];
  __shared__ float rmax[128];
  __shared__ float rlse[128];
  const int tid = threadIdx.x;
  const int lane = tid & 63, wave = tid >> 6;
  const int m0 = blockIdx.x * 128;
  const int r0 = tid >> 2, seg = tid & 3;
  const int segp = (seg ^ (r0 & 3)) << 3;
  const int swz = ((lane >> 4) ^ (lane & 3)) << 3;
  f32x4 acc[2][5] = {};

  int bA0, tA0, bA1, tA1;
  { int r = m0 + r0;      bA0 = r >> 5; tA0 = r & 31; }
  { int r = m0 + r0 + 64; bA1 = r >> 5; tA1 = r & 31; }

  #pragma unroll 1
  for (int k0 = 0; k0 < 1024; k0 += 32) {
    const unsigned short* src = (k0 < 512) ? hsF : hsB;
    const int koff = k0 & 511;
    stage16(src + (long)(tA0 + 1) * 32768 + bA0 * 512 + koff + segp, As_ + wave * 512);
    stage16(src + (long)(tA1 + 1) * 32768 + bA1 * 512 + koff + segp, As_ + wave * 512 + 2048);
    {
      int G = tid;
      #pragma unroll
      for (int it = 0; it < 2; ++it, G += 256) {
        int rn = G >> 2, sg = G & 3;
        if (rn < 80) {
          short8 v = *(const short8*)(WT + (long)rn * 1024 + k0 + sg * 8);
          *(short8*)(Bs_ + rn * 32 + ((sg ^ (rn & 3)) << 3)) = v;
        }
      }
    }
    __syncthreads();
    short8 a[2], bfrag[5];
    #pragma unroll
    for (int i = 0; i < 2; ++i)
      a[i] = *(const short8*)(As_ + (wave * 32 + i * 16 + (lane & 15)) * 32 + swz);
    #pragma unroll
    for (int j = 0; j < 5; ++j)
      bfrag[j] = *(const short8*)(Bs_ + (j * 16 + (lane & 15)) * 32 + swz);
    #pragma unroll
    for (int i = 0; i < 2; ++i)
      #pragma unroll
      for (int j = 0; j < 5; ++j)
        acc[i][j] = MFMA16(a[i], bfrag[j], acc[i][j]);
    __syncthreads();
  }

  float bsv[5];
  #pragma unroll
  for (int j = 0; j < 5; ++j) bsv[j] = bias[j * 16 + (lane & 15)];
  #pragma unroll
  for (int i = 0; i < 2; ++i)
    #pragma unroll
    for (int j = 0; j < 5; ++j)
      #pragma unroll
      for (int rr = 0; rr < 4; ++rr)
        zbuf[wave * 32 + i * 16 + (lane >> 4) * 4 + rr][j * 16 + (lane & 15)] =
            acc[i][j][rr] + bsv[j];
  __syncthreads();

  if (tid < 128) {
    float mx = -1e30f;
    for (int j = 0; j < 80; ++j) mx = fmaxf(mx, zbuf[tid][j]);
    float s = 0.f;
    for (int j = 0; j < 80; ++j) s += __expf(zbuf[tid][j] - mx);
    rmax[tid] = mx;
    rlse[tid] = logf(s);
  }
  __syncthreads();

  for (int idx = tid; idx < 128 * 80; idx += 256) {
    const int row = idx / 80, j = idx - row * 80;
    out[(long)m0 * 80 + idx] = zbuf[row][j] - rmax[row] - rlse[row];
  }
}

extern "C" void kernel_launch(void* const* d_in, const int* in_sizes, int n_in,
                              void* d_out, int out_size, void* d_ws, size_t ws_size,
                              hipStream_t stream) {
  const float* x  = (const float*)d_in[0];
  const float* k1 = (const float*)d_in[1];  const float* b1 = (const float*)d_in[2];
  const float* s1 = (const float*)d_in[3];  const float* o1 = (const float*)d_in[4];
  const float* m1 = (const float*)d_in[5];  const float* v1 = (const float*)d_in[6];
  const float* k2 = (const float*)d_in[7];  const float* b2 = (const float*)d_in[8];
  const float* s2 = (const float*)d_in[9];  const float* o2 = (const float*)d_in[10];
  const float* m2 = (const float*)d_in[11]; const float* v2 = (const float*)d_in[12];
  const float* k3 = (const float*)d_in[13]; const float* b3 = (const float*)d_in[14];
  const float* s3 = (const float*)d_in[15]; const float* o3 = (const float*)d_in[16];
  const float* m3 = (const float*)d_in[17]; const float* v3 = (const float*)d_in[18];
  const float* k4 = (const float*)d_in[19]; const float* b4 = (const float*)d_in[20];
  const float* s4 = (const float*)d_in[21]; const float* o4 = (const float*)d_in[22];
  const float* m4 = (const float*)d_in[23]; const float* v4 = (const float*)d_in[24];
  const float* k5 = (const float*)d_in[25]; const float* b5 = (const float*)d_in[26];
  const float* s5 = (const float*)d_in[27]; const float* o5 = (const float*)d_in[28];
  const float* m5 = (const float*)d_in[29]; const float* v5 = (const float*)d_in[30];
  const float* fwWi = (const float*)d_in[31];
  const float* fwWh = (const float*)d_in[32];
  const float* fwb  = (const float*)d_in[33];
  const float* bwWi = (const float*)d_in[34];
  const float* bwWh = (const float*)d_in[35];
  const float* bwb  = (const float*)d_in[36];
  const float* fcW  = (const float*)d_in[37];
  const float* fcb  = (const float*)d_in[38];

  char* wsb = (char*)d_ws;
  unsigned short* REG_A = (unsigned short*)(wsb);                  // 33,554,432 B
  unsigned short* REG_P = (unsigned short*)(wsb + 33554432);       // 19,169,280 B
  unsigned short* C4    = (unsigned short*)(wsb + 52723712);       //  6,684,672 B
  unsigned short* wT2   = (unsigned short*)(wsb + 59408384);       //    147,456 B
  unsigned short* wT3   = (unsigned short*)(wsb + 59555840);       //    589,824 B
  unsigned short* wT4   = (unsigned short*)(wsb + 60145664);       //  1,179,648 B
  unsigned short* wT5   = (unsigned short*)(wsb + 61325312);       //  2,359,296 B
  unsigned short* WiTF  = (unsigned short*)(wsb + 63684608);       //  8,388,608 B
  unsigned short* WiTB  = (unsigned short*)(wsb + 72073216);       //  8,388,608 B
  unsigned short* WhTF  = (unsigned short*)(wsb + 80461824);       //  2,097,152 B
  unsigned short* WhTB  = (unsigned short*)(wsb + 82558976);       //  2,097,152 B
  unsigned short* WTfc  = (unsigned short*)(wsb + 84656128);       //    163,840 B
  float* xwF = (float*)(wsb + 84819968);                           // 16,777,216 B
  float* xwB = (float*)(wsb + 101597184);                          // 16,777,216 B
  int*   bar = (int*)(wsb + 118374400);                            //      4,096 B
  unsigned short* hsF = (unsigned short*)(wsb + 118378496);        //  2,162,688 B
  unsigned short* hsB = (unsigned short*)(wsb + 120541184);        //  2,162,688 B

  // zeros: {bar+hsF slab0}, {hsB slab0}, {C4 full}, {P1 full}
  zero_multi<<<2048, 256, 0, stream>>>(
      (float*)(wsb + 118374400), 17408,
      (float*)(wsb + 120541184), 16384,
      (float*)(wsb + 52723712), 1671168,
      (float*)(wsb + 33554432), 4792320);

  // all weight transposes in one dispatch
  TAll tp;
  tp.src[0] = k2; tp.dst[0] = wT2; tp.K[0] = 576;  tp.N[0] = 128;
  tp.src[1] = k3; tp.dst[1] = wT3; tp.K[1] = 1152; tp.N[1] = 256;
  tp.src[2] = k4; tp.dst[2] = wT4; tp.K[2] = 2304; tp.N[2] = 256;
  tp.src[3] = k5; tp.dst[3] = wT5; tp.K[3] = 2304; tp.N[3] = 512;
  tp.src[4] = fwWi + 4194304; tp.dst[4] = WiTF; tp.K[4] = 2048; tp.N[4] = 2048;
  tp.src[5] = bwWi + 4194304; tp.dst[5] = WiTB; tp.K[5] = 2048; tp.N[5] = 2048;
  tp.src[6] = fwWh + 1048576; tp.dst[6] = WhTF; tp.K[6] = 512;  tp.N[6] = 2048;
  tp.src[7] = bwWh + 1048576; tp.dst[7] = WhTB; tp.K[7] = 512;  tp.N[7] = 2048;
  transpose_multi<<<dim3(72, 64, 8), 256, 0, stream>>>(tp);
  transpose_fc<<<320, 256, 0, stream>>>(fcW, WTfc);

  // fused conv1+pool1 -> P1 padded [64,18,130,64]
  conv1_pool<<<1024, 256, 0, stream>>>(x, k1, b1, s1, o1, m1, v1, REG_P);

  // conv2: P1 -> C2 [64,16,128,128]
  conv_mfma128<64, 128, 16, 128, 0><<<dim3(1024, 1), 256, 0, stream>>>(
      REG_P, wT2, b2, s2, o2, m2, v2, REG_A);
  maxpool_pad<128, 8, 64><<<dim3(33, 640), 256, 0, stream>>>(REG_A, REG_P);

  // conv3: P2 -> C3 [64,8,64,256]
  conv_mfma128<128, 256, 8, 64, 0><<<dim3(256, 2), 256, 0, stream>>>(
      REG_P, wT3, b3, s3, o3, m3, v3, REG_A);
  maxpool_pad<256, 4, 32><<<dim3(34, 384), 256, 0, stream>>>(REG_A, REG_P);

  // conv4: P3 -> C4 PADDED [64,6,34,256]
  conv_mfma128<256, 256, 4, 32, 1><<<dim3(64, 2), 256, 0, stream>>>(
      REG_P, wT4, b4, s4, o4, m4, v4, C4);

  // conv5: C4 -> C5 [64,4,32,512]
  conv_mfma128<256, 512, 4, 32, 0><<<dim3(64, 4), 256, 0, stream>>>(
      C4, wT5, b5, s5, o5, m5, v5, REG_A);

  // xw precompute (layer 1 only — reference keeps only last layer)
  gemm_xw128<<<dim3(16, 16), 256, 0, stream>>>(REG_A, WiTF, fwb + 2048, xwF, 0);
  gemm_xw128<<<dim3(16, 16), 256, 0, stream>>>(REG_A, WiTB, bwb + 2048, xwB, 1);

  // all 32 LSTM steps, both directions, single launch
  lstm_persist<<<64, 256, 0, stream>>>(WhTF, WhTB, xwF, xwB, hsF, hsB, bar);

  // FC + log_softmax
  fc_mfma_ls<<<16, 256, 0, stream>>>(hsF, hsB, WTfc, fcb, (float*)d_out);
}

// Round 8
// 490.966 us; speedup vs baseline: 15.8484x; 1.0164x over previous
//
#include <hip/hip_runtime.h>
#include <hip/hip_bf16.h>
#include <math.h>

#define EPSBN 1e-5f

using short8 = __attribute__((ext_vector_type(8))) short;
using f32x4  = __attribute__((ext_vector_type(4))) float;
using us4    = __attribute__((ext_vector_type(4))) unsigned short;

#define MFMA16(a, b, c) __builtin_amdgcn_mfma_f32_16x16x32_bf16(a, b, c, 0, 0, 0)

__device__ __forceinline__ float bf2f(unsigned short u) {
  unsigned int v = ((unsigned int)u) << 16;
  float f;
  __builtin_memcpy(&f, &v, 4);
  return f;
}
__device__ __forceinline__ unsigned short f2bf(float f) {
  __hip_bfloat16 h = __float2bfloat16(f);
  unsigned short u;
  __builtin_memcpy(&u, &h, 2);
  return u;
}
__device__ __forceinline__ float fast_sigmoid(float z) {
  return __builtin_amdgcn_rcpf(1.f + __expf(-z));
}
__device__ __forceinline__ float fast_tanh(float z) {
  float x2 = fminf(fmaxf(2.f * z, -30.f), 30.f);
  float e = __expf(x2);
  return (e - 1.f) * __builtin_amdgcn_rcpf(e + 1.f);
}
// async global->LDS, 16B per lane, dest = wave-uniform base + lane*16
__device__ __forceinline__ void stage16(const unsigned short* g, unsigned short* l) {
  __builtin_amdgcn_global_load_lds(
      (const __attribute__((address_space(1))) void*)g,
      (__attribute__((address_space(3))) void*)l, 16, 0, 0);
}

// ---------------- fused conv1 (3x3, CIN=1, COUT=64) + BN + 2x2 pool -> padded P1 ----------------
__global__ __launch_bounds__(256) void conv1_pool(
    const float* __restrict__ in, const float* __restrict__ w,
    const float* __restrict__ bias, const float* __restrict__ sc,
    const float* __restrict__ of, const float* __restrict__ mn,
    const float* __restrict__ vr, unsigned short* __restrict__ out) {
  __shared__ float lds[4][258];
  const int blk = blockIdx.x;
  const int b = blk >> 4, y0 = blk & 15;
  const int tid = threadIdx.x;
  for (int i = tid; i < 4 * 258; i += 256) {
    int row = i / 258, c = i - row * 258;
    int iy = 2 * y0 - 1 + row, xx = c - 1;
    float v = 0.f;
    if ((unsigned)iy < 32u && (unsigned)xx < 256u)
      v = in[((b << 5) + iy) * 256 + xx];
    lds[row][c] = v;
  }
  __syncthreads();
  const int co = tid & 63, xg = tid >> 6;
  float w9[9];
  #pragma unroll
  for (int t = 0; t < 9; ++t) w9[t] = w[t * 64 + co];
  const float scale = sc[co] * rsqrtf(vr[co] + EPSBN);
  const float shift = of[co] - mn[co] * scale;
  const float bs = bias[co];
  unsigned short* op = out + (((long)(b * 18 + y0 + 1) * 130 + xg * 32 + 1) << 6) + co;
  for (int px = 0; px < 32; ++px) {
    const int xp = xg * 32 + px;
    float m = -1e30f;
    #pragma unroll
    for (int dy = 0; dy < 2; ++dy) {
      #pragma unroll
      for (int dx = 0; dx < 2; ++dx) {
        const int x = 2 * xp + dx;
        float acc = bs;
        #pragma unroll
        for (int r = 0; r < 3; ++r)
          #pragma unroll
          for (int cc = 0; cc < 3; ++cc)
            acc = fmaf(lds[dy + r][x + cc], w9[r * 3 + cc], acc);
        float v = fmaxf(acc, 0.f) * scale + shift;
        m = fmaxf(m, v);
      }
    }
    op[(long)px << 6] = f2bf(m);
  }
}

// ---------------- 2x2 maxpool -> PADDED output (writes its own halo) ----------------
template<int C, int H2, int W2>
__global__ __launch_bounds__(256) void maxpool_pad(
    const unsigned short* __restrict__ in, unsigned short* __restrict__ out) {
  constexpr int W2P = W2 + 2, H2P = H2 + 2;
  const int y = blockIdx.y;
  const int b = y / H2P, yp = y - b * H2P;
  const int j = blockIdx.x * 256 + threadIdx.x;
  if (j >= W2P * C) return;
  const int xp = j / C, c = j - xp * C;
  unsigned short res = 0;
  if (yp >= 1 && yp <= H2 && xp >= 1 && xp <= W2) {
    const long rs = (long)(2 * W2) * C;
    const unsigned short* p0 =
        in + (((long)b * (2 * H2) + (yp - 1) * 2) * (2 * W2) + (xp - 1) * 2) * C + c;
    unsigned short u0 = p0[0], u1 = p0[C], u2 = p0[rs], u3 = p0[rs + C];
    unsigned short a = (bf2f(u0) >= bf2f(u1)) ? u0 : u1;
    unsigned short bmx = (bf2f(u2) >= bf2f(u3)) ? u2 : u3;
    res = (bf2f(a) >= bf2f(bmx)) ? a : bmx;
  }
  out[((long)y * W2P + xp) * C + c] = res;
}

// ---------------- merged weight transposes: fp32 [K][N] -> bf16 [N][K], 8 at once ----------------
struct TAll {
  const float* src[8];
  unsigned short* dst[8];
  int K[8];
  int N[8];
};
__global__ __launch_bounds__(256) void transpose_multi(TAll P) {
  const int z = blockIdx.z;
  const int K = P.K[z], N = P.N[z];
  const int k0 = blockIdx.x * 32, n0 = blockIdx.y * 32;
  if (k0 >= K || n0 >= N) return;
  __shared__ float T[32][33];
  const float* in = P.src[z];
  unsigned short* out = P.dst[z];
  const int tid = threadIdx.x;
  const int r = tid >> 3, c4 = (tid & 7) * 4;
  float4 v = *(const float4*)(in + (long)(k0 + r) * N + n0 + c4);
  T[r][c4 + 0] = v.x; T[r][c4 + 1] = v.y; T[r][c4 + 2] = v.z; T[r][c4 + 3] = v.w;
  __syncthreads();
  us4 o;
  #pragma unroll
  for (int i = 0; i < 4; ++i) o[i] = f2bf(T[c4 + i][r]);
  *(us4*)(out + (long)(n0 + r) * K + k0 + c4) = o;
}

// ---------------- small transpose for FC weight: fp32 [1024][80] -> bf16 [80][1024] ----------------
__global__ __launch_bounds__(256) void transpose_fc(
    const float* __restrict__ W, unsigned short* __restrict__ WT) {
  int i = blockIdx.x * 256 + threadIdx.x;
  if (i < 80 * 1024) {
    int n = i >> 10, k = i & 1023;
    WT[i] = f2bf(W[k * 80 + n]);
  }
}

// ---------------- merged zero init: 4 regions, grid-stride ----------------
__global__ __launch_bounds__(256) void zero_multi(
    float* p0, long n0, float* p1, long n1, float* p2, long n2, float* p3, long n3) {
  const long i0 = (long)blockIdx.x * 256 + threadIdx.x;
  const long st = (long)gridDim.x * 256;
  for (long j = i0; j < n0; j += st) p0[j] = 0.f;
  for (long j = i0; j < n1; j += st) p1[j] = 0.f;
  for (long j = i0; j < n2; j += st) p2[j] = 0.f;
  for (long j = i0; j < n3; j += st) p3[j] = 0.f;
}

// ---------------- 2-phase pipelined implicit-GEMM conv: 128x128 tile, BK=32 ----------------
template<int CIN, int COUT, int H, int W, int OUTPAD>
__global__ __launch_bounds__(256) void conv_mfma128(
    const unsigned short* __restrict__ act, const unsigned short* __restrict__ wT,
    const float* __restrict__ bias, const float* __restrict__ sc,
    const float* __restrict__ of, const float* __restrict__ mn,
    const float* __restrict__ vr, unsigned short* __restrict__ out) {
  constexpr int K9 = 9 * CIN;
  constexpr int HW = H * W;
  constexpr int WP = W + 2;
  constexpr int NK = K9 / 32;
  constexpr int CSH = (CIN == 64) ? 1 : (CIN == 128) ? 2 : 3;
  constexpr int CMSK = (1 << CSH) - 1;
  __shared__ unsigned short As[2][4096];
  __shared__ unsigned short Bs[2][4096];
  const int tid = threadIdx.x;
  const int lane = tid & 63, wave = tid >> 6;
  const int m0 = blockIdx.x * 128, n0 = blockIdx.y * 128;
  const int r0 = tid >> 2, seg = tid & 3;
  const int segp = (seg ^ (r0 & 3)) << 3;
  long pa0, pa1;
  {
    const int m = m0 + r0;
    const int b = m / HW, rem = m % HW;
    const int y = rem / W, x = rem % W;
    pa0 = (((long)b * (H + 2) + y) * WP + x) * CIN + segp;
  }
  {
    const int m = m0 + r0 + 64;
    const int b = m / HW, rem = m % HW;
    const int y = rem / W, x = rem % W;
    pa1 = (((long)b * (H + 2) + y) * WP + x) * CIN + segp;
  }
  const long pb0 = (long)(n0 + r0) * K9 + segp;
  const long pb1 = (long)(n0 + r0 + 64) * K9 + segp;
  const int swz = ((lane >> 4) ^ (lane & 3)) << 3;
  const int arow0 = (wave >> 1) * 64 + (lane & 15);
  const int brow0 = (wave & 1) * 64 + (lane & 15);
  f32x4 acc[4][4] = {};

  auto stage_tile = [&](int ks, int buf) {
    const int tap = ks >> CSH;
    const int cib = (ks & CMSK) << 5;
    const int ty = (tap * 86) >> 8;          // tap/3 for tap<9
    const int tx = tap - ty * 3;
    const long ka = (long)(ty * WP + tx) * CIN + cib;
    const long kb = (long)ks << 5;
    unsigned short* aw = &As[buf][wave * 512];
    unsigned short* bw = &Bs[buf][wave * 512];
    stage16(act + pa0 + ka, aw);
    stage16(act + pa1 + ka, aw + 2048);
    stage16(wT + pb0 + kb, bw);
    stage16(wT + pb1 + kb, bw + 2048);
  };

  stage_tile(0, 0);
  #pragma unroll 1
  for (int ks = 0; ks < NK; ++ks) {
    const int buf = ks & 1;
    if (ks + 1 < NK) {
      stage_tile(ks + 1, buf ^ 1);
      asm volatile("s_waitcnt vmcnt(4)" ::: "memory");
    } else {
      asm volatile("s_waitcnt vmcnt(0)" ::: "memory");
    }
    __builtin_amdgcn_s_barrier();
    __builtin_amdgcn_sched_barrier(0);
    short8 a[4], b[4];
    #pragma unroll
    for (int i = 0; i < 4; ++i)
      a[i] = *(const short8*)(&As[buf][(arow0 + i * 16) * 32 + swz]);
    #pragma unroll
    for (int j = 0; j < 4; ++j)
      b[j] = *(const short8*)(&Bs[buf][(brow0 + j * 16) * 32 + swz]);
    #pragma unroll
    for (int i = 0; i < 4; ++i)
      #pragma unroll
      for (int j = 0; j < 4; ++j)
        acc[i][j] = MFMA16(a[i], b[j], acc[i][j]);
    __builtin_amdgcn_s_barrier();
    __builtin_amdgcn_sched_barrier(0);
  }

  float scl[4], shf[4], bsv[4];
  #pragma unroll
  for (int j = 0; j < 4; ++j) {
    const int col = n0 + (wave & 1) * 64 + j * 16 + (lane & 15);
    scl[j] = sc[col] * rsqrtf(vr[col] + EPSBN);
    shf[j] = of[col] - mn[col] * scl[j];
    bsv[j] = bias[col];
  }
  #pragma unroll
  for (int i = 0; i < 4; ++i) {
    #pragma unroll
    for (int rr = 0; rr < 4; ++rr) {
      const int m = m0 + (wave >> 1) * 64 + i * 16 + (lane >> 4) * 4 + rr;
      const int b = m / HW, rem = m % HW;
      const int y = rem / W, x = rem % W;
      long obase;
      if (OUTPAD) obase = (((long)b * (H + 2) + y + 1) * WP + x + 1) * COUT;
      else        obase = (((long)b * H + y) * W + x) * COUT;
      const int colb = n0 + (wave & 1) * 64 + (lane & 15);
      #pragma unroll
      for (int j = 0; j < 4; ++j) {
        const float v = fmaxf(acc[i][j][rr] + bsv[j], 0.f) * scl[j] + shf[j];
        out[obase + colb + j * 16] = f2bf(v);
      }
    }
  }
}

// ---------------- fused 2-dir 2-phase GEMM: xw = gather(x_seq) @ WiT^T + b ----------------
__global__ __launch_bounds__(256) void gemm_xw2(
    const unsigned short* __restrict__ src,
    const unsigned short* __restrict__ WiTF, const unsigned short* __restrict__ WiTB,
    const float* __restrict__ bF, const float* __restrict__ bB,
    float* __restrict__ xwFp, float* __restrict__ xwBp) {
  __shared__ unsigned short As[2][4096];
  __shared__ unsigned short Bs[2][4096];
  const int rev = blockIdx.z;
  const unsigned short* WiT = rev ? WiTB : WiTF;
  const float* bvec = rev ? bB : bF;
  float* xw = rev ? xwBp : xwFp;
  const int tid = threadIdx.x;
  const int lane = tid & 63, wave = tid >> 6;
  const int m0 = blockIdx.x * 128, n0 = blockIdx.y * 128;
  const int r0 = tid >> 2, seg = tid & 3;
  const int segp = (seg ^ (r0 & 3)) << 3;
  long pa0, pa1;
  {
    const int r = m0 + r0;
    const int t = r >> 6, bb = r & 63;
    const int tt = rev ? 31 - t : t;
    pa0 = (long)bb * 65536 + (long)tt * 2048 + segp;
  }
  {
    const int r = m0 + r0 + 64;
    const int t = r >> 6, bb = r & 63;
    const int tt = rev ? 31 - t : t;
    pa1 = (long)bb * 65536 + (long)tt * 2048 + segp;
  }
  const long pb0 = (long)(n0 + r0) * 2048 + segp;
  const long pb1 = (long)(n0 + r0 + 64) * 2048 + segp;
  const int swz = ((lane >> 4) ^ (lane & 3)) << 3;
  const int arow0 = (wave >> 1) * 64 + (lane & 15);
  const int brow0 = (wave & 1) * 64 + (lane & 15);
  f32x4 acc[4][4] = {};

  auto stage_tile = [&](int ks, int buf) {
    const long k0 = (long)ks << 5;
    unsigned short* aw = &As[buf][wave * 512];
    unsigned short* bw = &Bs[buf][wave * 512];
    stage16(src + pa0 + k0, aw);
    stage16(src + pa1 + k0, aw + 2048);
    stage16(WiT + pb0 + k0, bw);
    stage16(WiT + pb1 + k0, bw + 2048);
  };

  stage_tile(0, 0);
  #pragma unroll 1
  for (int ks = 0; ks < 64; ++ks) {
    const int buf = ks & 1;
    if (ks + 1 < 64) {
      stage_tile(ks + 1, buf ^ 1);
      asm volatile("s_waitcnt vmcnt(4)" ::: "memory");
    } else {
      asm volatile("s_waitcnt vmcnt(0)" ::: "memory");
    }
    __builtin_amdgcn_s_barrier();
    __builtin_amdgcn_sched_barrier(0);
    short8 a[4], b[4];
    #pragma unroll
    for (int i = 0; i < 4; ++i)
      a[i] = *(const short8*)(&As[buf][(arow0 + i * 16) * 32 + swz]);
    #pragma unroll
    for (int j = 0; j < 4; ++j)
      b[j] = *(const short8*)(&Bs[buf][(brow0 + j * 16) * 32 + swz]);
    #pragma unroll
    for (int i = 0; i < 4; ++i)
      #pragma unroll
      for (int j = 0; j < 4; ++j)
        acc[i][j] = MFMA16(a[i], b[j], acc[i][j]);
    __builtin_amdgcn_s_barrier();
    __builtin_amdgcn_sched_barrier(0);
  }

  float bsv[4];
  #pragma unroll
  for (int j = 0; j < 4; ++j)
    bsv[j] = bvec[n0 + (wave & 1) * 64 + j * 16 + (lane & 15)];
  #pragma unroll
  for (int i = 0; i < 4; ++i) {
    #pragma unroll
    for (int rr = 0; rr < 4; ++rr) {
      const int row = m0 + (wave >> 1) * 64 + i * 16 + (lane >> 4) * 4 + rr;
      const int colb = n0 + (wave & 1) * 64 + (lane & 15);
      #pragma unroll
      for (int j = 0; j < 4; ++j)
        xw[(long)row * 2048 + colb + j * 16] = acc[i][j][rr] + bsv[j];
    }
  }
}

// ---------------- persistent bidirectional LSTM: in-register gates, nt h-exchange ----------------
// 64 blocks = 2 dirs x 32 u-tiles(16). Wave mp owns rows mp*16..+15, all 4 gates.
// Thread (mp,lk,lr): rows mp*16+lk*4+r, unit u0+lr — all gates in-register.
__global__ __launch_bounds__(256) void lstm_persist(
    const unsigned short* __restrict__ WhTF, const unsigned short* __restrict__ WhTB,
    const float* __restrict__ xwF, const float* __restrict__ xwB,
    unsigned short* __restrict__ hsF, unsigned short* __restrict__ hsB,
    int* __restrict__ bar) {
  __shared__ unsigned short Whs[64 * 512];
  __shared__ unsigned short Hs[64 * 512];
  const int bid = blockIdx.x;
  const int dir = bid >> 5;
  const int nb = bid & 31;
  const int u0 = nb * 16;
  const unsigned short* WhT = dir ? WhTB : WhTF;
  const float* xw = dir ? xwB : xwF;
  unsigned short* hs = dir ? hsB : hsF;
  int* flagbase = bar + dir * 32 * 16;
  int* myflag = flagbase + nb * 16;
  const int tid = threadIdx.x;
  const int lane = tid & 63, wave = tid >> 6;
  const int lr = lane & 15, lk = lane >> 4;

  // stage Whs once: LDS row = g*16+u  <-  WhT[g*512+u0+u][.]  (16B-swizzled)
  #pragma unroll
  for (int i = 0; i < 16; ++i) {
    const int G = i * 256 + tid;
    const int row = G >> 6, g8 = G & 63;
    const int g = row >> 4, u = row & 15;
    short8 v = *(const short8*)(WhT + ((long)(g * 512 + u0 + u) << 9) + g8 * 8);
    *(short8*)(Whs + row * 512 + ((g8 ^ (row & 7)) << 3)) = v;
  }

  const int myrow0 = wave * 16 + lk * 4;     // this thread's 4 batch rows
  float c4[4] = {0.f, 0.f, 0.f, 0.f};
  float xq[4][4];
  #pragma unroll
  for (int g = 0; g < 4; ++g)
    #pragma unroll
    for (int r = 0; r < 4; ++r)
      xq[g][r] = xw[(long)(myrow0 + r) * 2048 + g * 512 + u0 + lr];

  for (int t = 0; t < 32; ++t) {
    // stage h_t into LDS (swizzled); slab t is fresh — never cached locally
    const unsigned short* hsrc = hs + (long)t * 32768;
    #pragma unroll
    for (int i = 0; i < 16; ++i) {
      const int G = i * 256 + tid;
      const int row = G >> 6, g8 = G & 63;
      short8 v = *(const short8*)(hsrc + G * 8);
      *(short8*)(Hs + row * 512 + ((g8 ^ (row & 7)) << 3)) = v;
    }
    __syncthreads();

    f32x4 acc[4] = {};
    #pragma unroll
    for (int kk = 0; kk < 16; ++kk) {
      const int sw = ((lk + kk * 4) ^ (lr & 7)) << 3;
      short8 a = *(const short8*)(Hs + (wave * 16 + lr) * 512 + sw);
      #pragma unroll
      for (int g = 0; g < 4; ++g) {
        short8 b = *(const short8*)(Whs + (g * 16 + lr) * 512 + sw);
        acc[g] = MFMA16(a, b, acc[g]);
      }
    }

    // pointwise fully in-register; h stored nontemporal (no dirty L2 lines)
    unsigned short* hdst = hs + (long)(t + 1) * 32768;
    #pragma unroll
    for (int r = 0; r < 4; ++r) {
      float ii = fast_sigmoid(acc[0][r] + xq[0][r]);
      float ff = fast_sigmoid(acc[1][r] + xq[1][r]);
      float gg = fast_tanh(acc[2][r] + xq[2][r]);
      float oo = fast_sigmoid(acc[3][r] + xq[3][r]);
      c4[r] = ff * c4[r] + ii * gg;
      __builtin_nontemporal_store(
          f2bf(oo * fast_tanh(c4[r])),
          hdst + (long)(myrow0 + r) * 512 + u0 + lr);
    }

    if (t < 31) {
      // prefetch next-step xw before the exchange (independent of h)
      #pragma unroll
      for (int g = 0; g < 4; ++g)
        #pragma unroll
        for (int r = 0; r < 4; ++r)
          xq[g][r] = xw[(long)((t + 1) * 64 + myrow0 + r) * 2048 + g * 512 + u0 + lr];
      __syncthreads();
      if (tid == 0)
        __hip_atomic_store(myflag, t + 1, __ATOMIC_RELEASE, __HIP_MEMORY_SCOPE_AGENT);
      if (tid < 64) {
        int v;
        do {
          v = __hip_atomic_load(flagbase + (tid & 31) * 16,
                                __ATOMIC_RELAXED, __HIP_MEMORY_SCOPE_AGENT);
        } while (__any(v < t + 1));
        __threadfence();
      }
      __syncthreads();
    }
  }
}

// ---------------- MFMA FC (M=128,N=80,K=1024) + fused log_softmax ----------------
__global__ __launch_bounds__(256) void fc_mfma_ls(
    const unsigned short* __restrict__ hsF, const unsigned short* __restrict__ hsB,
    const unsigned short* __restrict__ WT, const float* __restrict__ bias,
    float* __restrict__ out) {
  __shared__ unsigned short As_[128 * 32];
  __shared__ unsigned short Bs_[80 * 32];
  __shared__ float zbuf[128][81];
  __shared__ float rmax[128];
  __shared__ float rlse[128];
  const int tid = threadIdx.x;
  const int lane = tid & 63, wave = tid >> 6;
  const int m0 = blockIdx.x * 128;
  const int r0 = tid >> 2, seg = tid & 3;
  const int segp = (seg ^ (r0 & 3)) << 3;
  const int swz = ((lane >> 4) ^ (lane & 3)) << 3;
  f32x4 acc[2][5] = {};

  int bA0, tA0, bA1, tA1;
  { int r = m0 + r0;      bA0 = r >> 5; tA0 = r & 31; }
  { int r = m0 + r0 + 64; bA1 = r >> 5; tA1 = r & 31; }

  #pragma unroll 1
  for (int k0 = 0; k0 < 1024; k0 += 32) {
    const unsigned short* src = (k0 < 512) ? hsF : hsB;
    const int koff = k0 & 511;
    stage16(src + (long)(tA0 + 1) * 32768 + bA0 * 512 + koff + segp, As_ + wave * 512);
    stage16(src + (long)(tA1 + 1) * 32768 + bA1 * 512 + koff + segp, As_ + wave * 512 + 2048);
    {
      int G = tid;
      #pragma unroll
      for (int it = 0; it < 2; ++it, G += 256) {
        int rn = G >> 2, sg = G & 3;
        if (rn < 80) {
          short8 v = *(const short8*)(WT + (long)rn * 1024 + k0 + sg * 8);
          *(short8*)(Bs_ + rn * 32 + ((sg ^ (rn & 3)) << 3)) = v;
        }
      }
    }
    __syncthreads();
    short8 a[2], bfrag[5];
    #pragma unroll
    for (int i = 0; i < 2; ++i)
      a[i] = *(const short8*)(As_ + (wave * 32 + i * 16 + (lane & 15)) * 32 + swz);
    #pragma unroll
    for (int j = 0; j < 5; ++j)
      bfrag[j] = *(const short8*)(Bs_ + (j * 16 + (lane & 15)) * 32 + swz);
    #pragma unroll
    for (int i = 0; i < 2; ++i)
      #pragma unroll
      for (int j = 0; j < 5; ++j)
        acc[i][j] = MFMA16(a[i], bfrag[j], acc[i][j]);
    __syncthreads();
  }

  float bsv[5];
  #pragma unroll
  for (int j = 0; j < 5; ++j) bsv[j] = bias[j * 16 + (lane & 15)];
  #pragma unroll
  for (int i = 0; i < 2; ++i)
    #pragma unroll
    for (int j = 0; j < 5; ++j)
      #pragma unroll
      for (int rr = 0; rr < 4; ++rr)
        zbuf[wave * 32 + i * 16 + (lane >> 4) * 4 + rr][j * 16 + (lane & 15)] =
            acc[i][j][rr] + bsv[j];
  __syncthreads();

  if (tid < 128) {
    float mx = -1e30f;
    for (int j = 0; j < 80; ++j) mx = fmaxf(mx, zbuf[tid][j]);
    float s = 0.f;
    for (int j = 0; j < 80; ++j) s += __expf(zbuf[tid][j] - mx);
    rmax[tid] = mx;
    rlse[tid] = logf(s);
  }
  __syncthreads();

  for (int idx = tid; idx < 128 * 80; idx += 256) {
    const int row = idx / 80, j = idx - row * 80;
    out[(long)m0 * 80 + idx] = zbuf[row][j] - rmax[row] - rlse[row];
  }
}

extern "C" void kernel_launch(void* const* d_in, const int* in_sizes, int n_in,
                              void* d_out, int out_size, void* d_ws, size_t ws_size,
                              hipStream_t stream) {
  const float* x  = (const float*)d_in[0];
  const float* k1 = (const float*)d_in[1];  const float* b1 = (const float*)d_in[2];
  const float* s1 = (const float*)d_in[3];  const float* o1 = (const float*)d_in[4];
  const float* m1 = (const float*)d_in[5];  const float* v1 = (const float*)d_in[6];
  const float* k2 = (const float*)d_in[7];  const float* b2 = (const float*)d_in[8];
  const float* s2 = (const float*)d_in[9];  const float* o2 = (const float*)d_in[10];
  const float* m2 = (const float*)d_in[11]; const float* v2 = (const float*)d_in[12];
  const float* k3 = (const float*)d_in[13]; const float* b3 = (const float*)d_in[14];
  const float* s3 = (const float*)d_in[15]; const float* o3 = (const float*)d_in[16];
  const float* m3 = (const float*)d_in[17]; const float* v3 = (const float*)d_in[18];
  const float* k4 = (const float*)d_in[19]; const float* b4 = (const float*)d_in[20];
  const float* s4 = (const float*)d_in[21]; const float* o4 = (const float*)d_in[22];
  const float* m4 = (const float*)d_in[23]; const float* v4 = (const float*)d_in[24];
  const float* k5 = (const float*)d_in[25]; const float* b5 = (const float*)d_in[26];
  const float* s5 = (const float*)d_in[27]; const float* o5 = (const float*)d_in[28];
  const float* m5 = (const float*)d_in[29]; const float* v5 = (const float*)d_in[30];
  const float* fwWi = (const float*)d_in[31];
  const float* fwWh = (const float*)d_in[32];
  const float* fwb  = (const float*)d_in[33];
  const float* bwWi = (const float*)d_in[34];
  const float* bwWh = (const float*)d_in[35];
  const float* bwb  = (const float*)d_in[36];
  const float* fcW  = (const float*)d_in[37];
  const float* fcb  = (const float*)d_in[38];

  char* wsb = (char*)d_ws;
  unsigned short* REG_A = (unsigned short*)(wsb);                  // 33,554,432 B
  unsigned short* REG_P = (unsigned short*)(wsb + 33554432);       // 19,169,280 B
  unsigned short* C4    = (unsigned short*)(wsb + 52723712);       //  6,684,672 B
  unsigned short* wT2   = (unsigned short*)(wsb + 59408384);       //    147,456 B
  unsigned short* wT3   = (unsigned short*)(wsb + 59555840);       //    589,824 B
  unsigned short* wT4   = (unsigned short*)(wsb + 60145664);       //  1,179,648 B
  unsigned short* wT5   = (unsigned short*)(wsb + 61325312);       //  2,359,296 B
  unsigned short* WiTF  = (unsigned short*)(wsb + 63684608);       //  8,388,608 B
  unsigned short* WiTB  = (unsigned short*)(wsb + 72073216);       //  8,388,608 B
  unsigned short* WhTF  = (unsigned short*)(wsb + 80461824);       //  2,097,152 B
  unsigned short* WhTB  = (unsigned short*)(wsb + 82558976);       //  2,097,152 B
  unsigned short* WTfc  = (unsigned short*)(wsb + 84656128);       //    163,840 B
  float* xwF = (float*)(wsb + 84819968);                           // 16,777,216 B
  float* xwB = (float*)(wsb + 101597184);                          // 16,777,216 B
  int*   bar = (int*)(wsb + 118374400);                            //      4,096 B
  unsigned short* hsF = (unsigned short*)(wsb + 118378496);        //  2,162,688 B
  unsigned short* hsB = (unsigned short*)(wsb + 120541184);        //  2,162,688 B

  // zeros: {bar+hsF slab0}, {hsB slab0}, {C4 full}, {P1 full}
  zero_multi<<<2048, 256, 0, stream>>>(
      (float*)(wsb + 118374400), 17408,
      (float*)(wsb + 120541184), 16384,
      (float*)(wsb + 52723712), 1671168,
      (float*)(wsb + 33554432), 4792320);

  // all weight transposes in one dispatch
  TAll tp;
  tp.src[0] = k2; tp.dst[0] = wT2; tp.K[0] = 576;  tp.N[0] = 128;
  tp.src[1] = k3; tp.dst[1] = wT3; tp.K[1] = 1152; tp.N[1] = 256;
  tp.src[2] = k4; tp.dst[2] = wT4; tp.K[2] = 2304; tp.N[2] = 256;
  tp.src[3] = k5; tp.dst[3] = wT5; tp.K[3] = 2304; tp.N[3] = 512;
  tp.src[4] = fwWi + 4194304; tp.dst[4] = WiTF; tp.K[4] = 2048; tp.N[4] = 2048;
  tp.src[5] = bwWi + 4194304; tp.dst[5] = WiTB; tp.K[5] = 2048; tp.N[5] = 2048;
  tp.src[6] = fwWh + 1048576; tp.dst[6] = WhTF; tp.K[6] = 512;  tp.N[6] = 2048;
  tp.src[7] = bwWh + 1048576; tp.dst[7] = WhTB; tp.K[7] = 512;  tp.N[7] = 2048;
  transpose_multi<<<dim3(72, 64, 8), 256, 0, stream>>>(tp);
  transpose_fc<<<320, 256, 0, stream>>>(fcW, WTfc);

  // fused conv1+pool1 -> P1 padded [64,18,130,64]
  conv1_pool<<<1024, 256, 0, stream>>>(x, k1, b1, s1, o1, m1, v1, REG_P);

  // conv2: P1 -> C2 [64,16,128,128]
  conv_mfma128<64, 128, 16, 128, 0><<<dim3(1024, 1), 256, 0, stream>>>(
      REG_P, wT2, b2, s2, o2, m2, v2, REG_A);
  maxpool_pad<128, 8, 64><<<dim3(33, 640), 256, 0, stream>>>(REG_A, REG_P);

  // conv3: P2 -> C3 [64,8,64,256]
  conv_mfma128<128, 256, 8, 64, 0><<<dim3(256, 2), 256, 0, stream>>>(
      REG_P, wT3, b3, s3, o3, m3, v3, REG_A);
  maxpool_pad<256, 4, 32><<<dim3(34, 384), 256, 0, stream>>>(REG_A, REG_P);

  // conv4: P3 -> C4 PADDED [64,6,34,256]
  conv_mfma128<256, 256, 4, 32, 1><<<dim3(64, 2), 256, 0, stream>>>(
      REG_P, wT4, b4, s4, o4, m4, v4, C4);

  // conv5: C4 -> C5 [64,4,32,512]
  conv_mfma128<256, 512, 4, 32, 0><<<dim3(64, 4), 256, 0, stream>>>(
      C4, wT5, b5, s5, o5, m5, v5, REG_A);

  // xw precompute, both directions fused (layer 1 only)
  gemm_xw2<<<dim3(16, 16, 2), 256, 0, stream>>>(
      REG_A, WiTF, WiTB, fwb + 2048, bwb + 2048, xwF, xwB);

  // all 32 LSTM steps, both directions, single launch
  lstm_persist<<<64, 256, 0, stream>>>(WhTF, WhTB, xwF, xwB, hsF, hsB, bar);

  // FC + log_softmax
  fc_mfma_ls<<<16, 256, 0, stream>>>(hsF, hsB, WTfc, fcb, (float*)d_out);
}

// Round 9
// 469.950 us; speedup vs baseline: 16.5571x; 1.0447x over previous
//
#include <hip/hip_runtime.h>
#include <hip/hip_bf16.h>
#include <math.h>

#define EPSBN 1e-5f

using short8 = __attribute__((ext_vector_type(8))) short;
using f32x4  = __attribute__((ext_vector_type(4))) float;
using us4    = __attribute__((ext_vector_type(4))) unsigned short;

#define MFMA16(a, b, c) __builtin_amdgcn_mfma_f32_16x16x32_bf16(a, b, c, 0, 0, 0)

__device__ __forceinline__ float bf2f(unsigned short u) {
  unsigned int v = ((unsigned int)u) << 16;
  float f;
  __builtin_memcpy(&f, &v, 4);
  return f;
}
__device__ __forceinline__ unsigned short f2bf(float f) {
  __hip_bfloat16 h = __float2bfloat16(f);
  unsigned short u;
  __builtin_memcpy(&u, &h, 2);
  return u;
}
__device__ __forceinline__ float fast_sigmoid(float z) {
  return __builtin_amdgcn_rcpf(1.f + __expf(-z));
}
__device__ __forceinline__ float fast_tanh(float z) {
  float x2 = fminf(fmaxf(2.f * z, -30.f), 30.f);
  float e = __expf(x2);
  return (e - 1.f) * __builtin_amdgcn_rcpf(e + 1.f);
}
// async global->LDS, 16B per lane, dest = wave-uniform base + lane*16
__device__ __forceinline__ void stage16(const unsigned short* g, unsigned short* l) {
  __builtin_amdgcn_global_load_lds(
      (const __attribute__((address_space(1))) void*)g,
      (__attribute__((address_space(3))) void*)l, 16, 0, 0);
}

// ---------------- fused conv1 (3x3, CIN=1, COUT=64) + BN + 2x2 pool -> padded P1 ----------------
__global__ __launch_bounds__(256) void conv1_pool(
    const float* __restrict__ in, const float* __restrict__ w,
    const float* __restrict__ bias, const float* __restrict__ sc,
    const float* __restrict__ of, const float* __restrict__ mn,
    const float* __restrict__ vr, unsigned short* __restrict__ out) {
  __shared__ float lds[4][258];
  const int blk = blockIdx.x;
  const int b = blk >> 4, y0 = blk & 15;
  const int tid = threadIdx.x;
  for (int i = tid; i < 4 * 258; i += 256) {
    int row = i / 258, c = i - row * 258;
    int iy = 2 * y0 - 1 + row, xx = c - 1;
    float v = 0.f;
    if ((unsigned)iy < 32u && (unsigned)xx < 256u)
      v = in[((b << 5) + iy) * 256 + xx];
    lds[row][c] = v;
  }
  __syncthreads();
  const int co = tid & 63, xg = tid >> 6;
  float w9[9];
  #pragma unroll
  for (int t = 0; t < 9; ++t) w9[t] = w[t * 64 + co];
  const float scale = sc[co] * rsqrtf(vr[co] + EPSBN);
  const float shift = of[co] - mn[co] * scale;
  const float bs = bias[co];
  unsigned short* op = out + (((long)(b * 18 + y0 + 1) * 130 + xg * 32 + 1) << 6) + co;
  for (int px = 0; px < 32; ++px) {
    const int xp = xg * 32 + px;
    float m = -1e30f;
    #pragma unroll
    for (int dy = 0; dy < 2; ++dy) {
      #pragma unroll
      for (int dx = 0; dx < 2; ++dx) {
        const int x = 2 * xp + dx;
        float acc = bs;
        #pragma unroll
        for (int r = 0; r < 3; ++r)
          #pragma unroll
          for (int cc = 0; cc < 3; ++cc)
            acc = fmaf(lds[dy + r][x + cc], w9[r * 3 + cc], acc);
        float v = fmaxf(acc, 0.f) * scale + shift;
        m = fmaxf(m, v);
      }
    }
    op[(long)px << 6] = f2bf(m);
  }
}

// ---------------- 2x2 maxpool -> PADDED output (writes its own halo) ----------------
template<int C, int H2, int W2>
__global__ __launch_bounds__(256) void maxpool_pad(
    const unsigned short* __restrict__ in, unsigned short* __restrict__ out) {
  constexpr int W2P = W2 + 2, H2P = H2 + 2;
  const int y = blockIdx.y;
  const int b = y / H2P, yp = y - b * H2P;
  const int j = blockIdx.x * 256 + threadIdx.x;
  if (j >= W2P * C) return;
  const int xp = j / C, c = j - xp * C;
  unsigned short res = 0;
  if (yp >= 1 && yp <= H2 && xp >= 1 && xp <= W2) {
    const long rs = (long)(2 * W2) * C;
    const unsigned short* p0 =
        in + (((long)b * (2 * H2) + (yp - 1) * 2) * (2 * W2) + (xp - 1) * 2) * C + c;
    unsigned short u0 = p0[0], u1 = p0[C], u2 = p0[rs], u3 = p0[rs + C];
    unsigned short a = (bf2f(u0) >= bf2f(u1)) ? u0 : u1;
    unsigned short bmx = (bf2f(u2) >= bf2f(u3)) ? u2 : u3;
    res = (bf2f(a) >= bf2f(bmx)) ? a : bmx;
  }
  out[((long)y * W2P + xp) * C + c] = res;
}

// ---------------- merged weight transposes: fp32 [K][N] -> bf16 [N][K], 8 at once ----------------
struct TAll {
  const float* src[8];
  unsigned short* dst[8];
  int K[8];
  int N[8];
};
__global__ __launch_bounds__(256) void transpose_multi(TAll P) {
  const int z = blockIdx.z;
  const int K = P.K[z], N = P.N[z];
  const int k0 = blockIdx.x * 32, n0 = blockIdx.y * 32;
  if (k0 >= K || n0 >= N) return;
  __shared__ float T[32][33];
  const float* in = P.src[z];
  unsigned short* out = P.dst[z];
  const int tid = threadIdx.x;
  const int r = tid >> 3, c4 = (tid & 7) * 4;
  float4 v = *(const float4*)(in + (long)(k0 + r) * N + n0 + c4);
  T[r][c4 + 0] = v.x; T[r][c4 + 1] = v.y; T[r][c4 + 2] = v.z; T[r][c4 + 3] = v.w;
  __syncthreads();
  us4 o;
  #pragma unroll
  for (int i = 0; i < 4; ++i) o[i] = f2bf(T[c4 + i][r]);
  *(us4*)(out + (long)(n0 + r) * K + k0 + c4) = o;
}

// ---------------- small transpose for FC weight: fp32 [1024][80] -> bf16 [80][1024] ----------------
__global__ __launch_bounds__(256) void transpose_fc(
    const float* __restrict__ W, unsigned short* __restrict__ WT) {
  int i = blockIdx.x * 256 + threadIdx.x;
  if (i < 80 * 1024) {
    int n = i >> 10, k = i & 1023;
    WT[i] = f2bf(W[k * 80 + n]);
  }
}

// ---------------- merged zero init: 4 regions, grid-stride ----------------
__global__ __launch_bounds__(256) void zero_multi(
    float* p0, long n0, float* p1, long n1, float* p2, long n2, float* p3, long n3) {
  const long i0 = (long)blockIdx.x * 256 + threadIdx.x;
  const long st = (long)gridDim.x * 256;
  for (long j = i0; j < n0; j += st) p0[j] = 0.f;
  for (long j = i0; j < n1; j += st) p1[j] = 0.f;
  for (long j = i0; j < n2; j += st) p2[j] = 0.f;
  for (long j = i0; j < n3; j += st) p3[j] = 0.f;
}

// ---------------- 2-phase pipelined implicit-GEMM conv, XCD-swizzled 1-D grid ----------------
// grid = NBM*NBN blocks (multiple of 8); logical = (w&7)*(nwg/8)+(w>>3).
template<int CIN, int COUT, int H, int W, int OUTPAD, int NBM, int NBN>
__global__ __launch_bounds__(256) void conv_mfma128(
    const unsigned short* __restrict__ act, const unsigned short* __restrict__ wT,
    const float* __restrict__ bias, const float* __restrict__ sc,
    const float* __restrict__ of, const float* __restrict__ mn,
    const float* __restrict__ vr, unsigned short* __restrict__ out) {
  constexpr int K9 = 9 * CIN;
  constexpr int HW = H * W;
  constexpr int WP = W + 2;
  constexpr int NK = K9 / 32;
  constexpr int NWG = NBM * NBN;
  constexpr int CSH = (CIN == 64) ? 1 : (CIN == 128) ? 2 : 3;
  constexpr int CMSK = (1 << CSH) - 1;
  __shared__ unsigned short As[2][4096];
  __shared__ unsigned short Bs[2][4096];
  const int tid = threadIdx.x;
  const int lane = tid & 63, wave = tid >> 6;
  const int wzw = blockIdx.x;
  const int logical = (wzw & 7) * (NWG >> 3) + (wzw >> 3);
  const int m0 = (logical % NBM) * 128, n0 = (logical / NBM) * 128;
  const int r0 = tid >> 2, seg = tid & 3;
  const int segp = (seg ^ (r0 & 3)) << 3;
  long pa0, pa1;
  {
    const int m = m0 + r0;
    const int b = m / HW, rem = m % HW;
    const int y = rem / W, x = rem % W;
    pa0 = (((long)b * (H + 2) + y) * WP + x) * CIN + segp;
  }
  {
    const int m = m0 + r0 + 64;
    const int b = m / HW, rem = m % HW;
    const int y = rem / W, x = rem % W;
    pa1 = (((long)b * (H + 2) + y) * WP + x) * CIN + segp;
  }
  const long pb0 = (long)(n0 + r0) * K9 + segp;
  const long pb1 = (long)(n0 + r0 + 64) * K9 + segp;
  const int swz = ((lane >> 4) ^ (lane & 3)) << 3;
  const int arow0 = (wave >> 1) * 64 + (lane & 15);
  const int brow0 = (wave & 1) * 64 + (lane & 15);
  f32x4 acc[4][4] = {};

  auto stage_tile = [&](int ks, int buf) {
    const int tap = ks >> CSH;
    const int cib = (ks & CMSK) << 5;
    const int ty = (tap * 86) >> 8;          // tap/3 for tap<9
    const int tx = tap - ty * 3;
    const long ka = (long)(ty * WP + tx) * CIN + cib;
    const long kb = (long)ks << 5;
    unsigned short* aw = &As[buf][wave * 512];
    unsigned short* bw = &Bs[buf][wave * 512];
    stage16(act + pa0 + ka, aw);
    stage16(act + pa1 + ka, aw + 2048);
    stage16(wT + pb0 + kb, bw);
    stage16(wT + pb1 + kb, bw + 2048);
  };

  stage_tile(0, 0);
  #pragma unroll 1
  for (int ks = 0; ks < NK; ++ks) {
    const int buf = ks & 1;
    if (ks + 1 < NK) {
      stage_tile(ks + 1, buf ^ 1);
      asm volatile("s_waitcnt vmcnt(4)" ::: "memory");
    } else {
      asm volatile("s_waitcnt vmcnt(0)" ::: "memory");
    }
    __builtin_amdgcn_s_barrier();
    __builtin_amdgcn_sched_barrier(0);
    short8 a[4], b[4];
    #pragma unroll
    for (int i = 0; i < 4; ++i)
      a[i] = *(const short8*)(&As[buf][(arow0 + i * 16) * 32 + swz]);
    #pragma unroll
    for (int j = 0; j < 4; ++j)
      b[j] = *(const short8*)(&Bs[buf][(brow0 + j * 16) * 32 + swz]);
    #pragma unroll
    for (int i = 0; i < 4; ++i)
      #pragma unroll
      for (int j = 0; j < 4; ++j)
        acc[i][j] = MFMA16(a[i], b[j], acc[i][j]);
    __builtin_amdgcn_s_barrier();
    __builtin_amdgcn_sched_barrier(0);
  }

  float scl[4], shf[4], bsv[4];
  #pragma unroll
  for (int j = 0; j < 4; ++j) {
    const int col = n0 + (wave & 1) * 64 + j * 16 + (lane & 15);
    scl[j] = sc[col] * rsqrtf(vr[col] + EPSBN);
    shf[j] = of[col] - mn[col] * scl[j];
    bsv[j] = bias[col];
  }
  #pragma unroll
  for (int i = 0; i < 4; ++i) {
    #pragma unroll
    for (int rr = 0; rr < 4; ++rr) {
      const int m = m0 + (wave >> 1) * 64 + i * 16 + (lane >> 4) * 4 + rr;
      const int b = m / HW, rem = m % HW;
      const int y = rem / W, x = rem % W;
      long obase;
      if (OUTPAD) obase = (((long)b * (H + 2) + y + 1) * WP + x + 1) * COUT;
      else        obase = (((long)b * H + y) * W + x) * COUT;
      const int colb = n0 + (wave & 1) * 64 + (lane & 15);
      #pragma unroll
      for (int j = 0; j < 4; ++j) {
        const float v = fmaxf(acc[i][j][rr] + bsv[j], 0.f) * scl[j] + shf[j];
        out[obase + colb + j * 16] = f2bf(v);
      }
    }
  }
}

// ---------------- fused 2-dir 2-phase GEMM, XCD-swizzled: xw = gather(x) @ WiT^T + b ----------------
__global__ __launch_bounds__(256) void gemm_xw2(
    const unsigned short* __restrict__ src,
    const unsigned short* __restrict__ WiTF, const unsigned short* __restrict__ WiTB,
    const float* __restrict__ bF, const float* __restrict__ bB,
    float* __restrict__ xwFp, float* __restrict__ xwBp) {
  __shared__ unsigned short As[2][4096];
  __shared__ unsigned short Bs[2][4096];
  const int rev = blockIdx.z;
  const unsigned short* WiT = rev ? WiTB : WiTF;
  const float* bvec = rev ? bB : bF;
  float* xw = rev ? xwBp : xwFp;
  const int tid = threadIdx.x;
  const int lane = tid & 63, wave = tid >> 6;
  const int wzw = blockIdx.x;                       // 0..255
  const int logical = (wzw & 7) * 32 + (wzw >> 3);  // bijective, chunks of 32/XCD
  const int m0 = (logical & 15) * 128, n0 = (logical >> 4) * 128;
  const int r0 = tid >> 2, seg = tid & 3;
  const int segp = (seg ^ (r0 & 3)) << 3;
  long pa0, pa1;
  {
    const int r = m0 + r0;
    const int t = r >> 6, bb = r & 63;
    const int tt = rev ? 31 - t : t;
    pa0 = (long)bb * 65536 + (long)tt * 2048 + segp;
  }
  {
    const int r = m0 + r0 + 64;
    const int t = r >> 6, bb = r & 63;
    const int tt = rev ? 31 - t : t;
    pa1 = (long)bb * 65536 + (long)tt * 2048 + segp;
  }
  const long pb0 = (long)(n0 + r0) * 2048 + segp;
  const long pb1 = (long)(n0 + r0 + 64) * 2048 + segp;
  const int swz = ((lane >> 4) ^ (lane & 3)) << 3;
  const int arow0 = (wave >> 1) * 64 + (lane & 15);
  const int brow0 = (wave & 1) * 64 + (lane & 15);
  f32x4 acc[4][4] = {};

  auto stage_tile = [&](int ks, int buf) {
    const long k0 = (long)ks << 5;
    unsigned short* aw = &As[buf][wave * 512];
    unsigned short* bw = &Bs[buf][wave * 512];
    stage16(src + pa0 + k0, aw);
    stage16(src + pa1 + k0, aw + 2048);
    stage16(WiT + pb0 + k0, bw);
    stage16(WiT + pb1 + k0, bw + 2048);
  };

  stage_tile(0, 0);
  #pragma unroll 1
  for (int ks = 0; ks < 64; ++ks) {
    const int buf = ks & 1;
    if (ks + 1 < 64) {
      stage_tile(ks + 1, buf ^ 1);
      asm volatile("s_waitcnt vmcnt(4)" ::: "memory");
    } else {
      asm volatile("s_waitcnt vmcnt(0)" ::: "memory");
    }
    __builtin_amdgcn_s_barrier();
    __builtin_amdgcn_sched_barrier(0);
    short8 a[4], b[4];
    #pragma unroll
    for (int i = 0; i < 4; ++i)
      a[i] = *(const short8*)(&As[buf][(arow0 + i * 16) * 32 + swz]);
    #pragma unroll
    for (int j = 0; j < 4; ++j)
      b[j] = *(const short8*)(&Bs[buf][(brow0 + j * 16) * 32 + swz]);
    #pragma unroll
    for (int i = 0; i < 4; ++i)
      #pragma unroll
      for (int j = 0; j < 4; ++j)
        acc[i][j] = MFMA16(a[i], b[j], acc[i][j]);
    __builtin_amdgcn_s_barrier();
    __builtin_amdgcn_sched_barrier(0);
  }

  float bsv[4];
  #pragma unroll
  for (int j = 0; j < 4; ++j)
    bsv[j] = bvec[n0 + (wave & 1) * 64 + j * 16 + (lane & 15)];
  #pragma unroll
  for (int i = 0; i < 4; ++i) {
    #pragma unroll
    for (int rr = 0; rr < 4; ++rr) {
      const int row = m0 + (wave >> 1) * 64 + i * 16 + (lane >> 4) * 4 + rr;
      const int colb = n0 + (wave & 1) * 64 + (lane & 15);
      #pragma unroll
      for (int j = 0; j < 4; ++j)
        xw[(long)row * 2048 + colb + j * 16] = acc[i][j][rr] + bsv[j];
    }
  }
}

// ---------------- persistent bidirectional LSTM (round-7 proven version) ----------------
__global__ __launch_bounds__(256) void lstm_persist(
    const unsigned short* __restrict__ WhTF, const unsigned short* __restrict__ WhTB,
    const float* __restrict__ xwF, const float* __restrict__ xwB,
    unsigned short* __restrict__ hsF, unsigned short* __restrict__ hsB,
    int* __restrict__ bar) {
  __shared__ unsigned short Whs[64 * 512];
  __shared__ unsigned short Hs[64 * 512];
  __shared__ float Zs[4 * 64 * 16];
  const int bid = blockIdx.x;
  const int dir = bid >> 5;
  const int nb = bid & 31;
  const int u0 = nb * 16;
  const unsigned short* WhT = dir ? WhTB : WhTF;
  const float* xw = dir ? xwB : xwF;
  unsigned short* hs = dir ? hsB : hsF;
  int* flagbase = bar + dir * 32 * 16;
  int* myflag = flagbase + nb * 16;
  const int tid = threadIdx.x;
  const int lane = tid & 63, wave = tid >> 6;
  const int lr = lane & 15, lk = lane >> 4;
  const int mp = wave >> 1, gp = wave & 1;

  #pragma unroll
  for (int i = 0; i < 16; ++i) {
    const int G = i * 256 + tid;
    const int row = G >> 6, g8 = G & 63;
    const int g = row >> 4, u = row & 15;
    short8 v = *(const short8*)(WhT + ((long)(g * 512 + u0 + u) << 9) + g8 * 8);
    *(short8*)(Whs + row * 512 + ((g8 ^ (row & 7)) << 3)) = v;
  }

  const int prow = tid >> 2;
  const int pu4 = (tid & 3) * 4;
  float c4[4] = {0.f, 0.f, 0.f, 0.f};
  float4 xq[4];
  #pragma unroll
  for (int g = 0; g < 4; ++g)
    xq[g] = *(const float4*)(xw + (long)prow * 2048 + g * 512 + u0 + pu4);

  for (int t = 0; t < 32; ++t) {
    const unsigned short* hsrc = hs + (long)t * 32768;
    #pragma unroll
    for (int i = 0; i < 16; ++i) {
      const int G = i * 256 + tid;
      const int row = G >> 6, g8 = G & 63;
      short8 v = *(const short8*)(hsrc + G * 8);
      *(short8*)(Hs + row * 512 + ((g8 ^ (row & 7)) << 3)) = v;
    }
    __syncthreads();

    f32x4 acc[2][2] = {};
    #pragma unroll
    for (int kk = 0; kk < 16; ++kk) {
      const int sw = ((lk + kk * 4) ^ (lr & 7)) << 3;
      short8 a0 = *(const short8*)(Hs + (mp * 32 + lr) * 512 + sw);
      short8 a1 = *(const short8*)(Hs + (mp * 32 + 16 + lr) * 512 + sw);
      short8 b0 = *(const short8*)(Whs + (gp * 32 + lr) * 512 + sw);
      short8 b1 = *(const short8*)(Whs + (gp * 32 + 16 + lr) * 512 + sw);
      acc[0][0] = MFMA16(a0, b0, acc[0][0]);
      acc[0][1] = MFMA16(a0, b1, acc[0][1]);
      acc[1][0] = MFMA16(a1, b0, acc[1][0]);
      acc[1][1] = MFMA16(a1, b1, acc[1][1]);
    }

    #pragma unroll
    for (int im = 0; im < 2; ++im) {
      const int rowb = (mp * 2 + im) * 16 + lk * 4;
      #pragma unroll
      for (int ig = 0; ig < 2; ++ig) {
        const int g = gp * 2 + ig;
        #pragma unroll
        for (int r = 0; r < 4; ++r)
          Zs[g * 1024 + (rowb + r) * 16 + lr] = acc[im][ig][r];
      }
    }
    __syncthreads();

    {
      float4 zi = *(const float4*)(Zs + tid * 4);
      float4 zf = *(const float4*)(Zs + 1024 + tid * 4);
      float4 zg = *(const float4*)(Zs + 2048 + tid * 4);
      float4 zo = *(const float4*)(Zs + 3072 + tid * 4);
      const float* pzi = (const float*)&zi;
      const float* pzf = (const float*)&zf;
      const float* pzg = (const float*)&zg;
      const float* pzo = (const float*)&zo;
      us4 hv;
      #pragma unroll
      for (int r = 0; r < 4; ++r) {
        float ii = fast_sigmoid(pzi[r] + ((const float*)&xq[0])[r]);
        float ff = fast_sigmoid(pzf[r] + ((const float*)&xq[1])[r]);
        float gg = fast_tanh(pzg[r] + ((const float*)&xq[2])[r]);
        float oo = fast_sigmoid(pzo[r] + ((const float*)&xq[3])[r]);
        c4[r] = ff * c4[r] + ii * gg;
        hv[r] = f2bf(oo * fast_tanh(c4[r]));
      }
      *(us4*)(hs + (long)(t + 1) * 32768 + prow * 512 + u0 + pu4) = hv;
    }

    if (t < 31) {
      float4 xqn[4];
      #pragma unroll
      for (int g = 0; g < 4; ++g)
        xqn[g] = *(const float4*)(xw + (long)((t + 1) * 64 + prow) * 2048 + g * 512 + u0 + pu4);
      __syncthreads();
      if (tid < 64) {
        if (tid == 0)
          __hip_atomic_store(myflag, t + 1, __ATOMIC_RELEASE, __HIP_MEMORY_SCOPE_AGENT);
        int v;
        do {
          v = __hip_atomic_load(flagbase + (tid & 31) * 16,
                                __ATOMIC_ACQUIRE, __HIP_MEMORY_SCOPE_AGENT);
        } while (__any(v < t + 1));
      }
      __syncthreads();
      #pragma unroll
      for (int g = 0; g < 4; ++g) xq[g] = xqn[g];
    }
  }
}

// ---------------- MFMA FC (M=128,N=80,K=1024) + fused log_softmax ----------------
__global__ __launch_bounds__(256) void fc_mfma_ls(
    const unsigned short* __restrict__ hsF, const unsigned short* __restrict__ hsB,
    const unsigned short* __restrict__ WT, const float* __restrict__ bias,
    float* __restrict__ out) {
  __shared__ unsigned short As_[128 * 32];
  __shared__ unsigned short Bs_[80 * 32];
  __shared__ float zbuf[128][81];
  __shared__ float rmax[128];
  __shared__ float rlse[128];
  const int tid = threadIdx.x;
  const int lane = tid & 63, wave = tid >> 6;
  const int m0 = blockIdx.x * 128;
  const int r0 = tid >> 2, seg = tid & 3;
  const int segp = (seg ^ (r0 & 3)) << 3;
  const int swz = ((lane >> 4) ^ (lane & 3)) << 3;
  f32x4 acc[2][5] = {};

  int bA0, tA0, bA1, tA1;
  { int r = m0 + r0;      bA0 = r >> 5; tA0 = r & 31; }
  { int r = m0 + r0 + 64; bA1 = r >> 5; tA1 = r & 31; }

  #pragma unroll 1
  for (int k0 = 0; k0 < 1024; k0 += 32) {
    const unsigned short* src = (k0 < 512) ? hsF : hsB;
    const int koff = k0 & 511;
    stage16(src + (long)(tA0 + 1) * 32768 + bA0 * 512 + koff + segp, As_ + wave * 512);
    stage16(src + (long)(tA1 + 1) * 32768 + bA1 * 512 + koff + segp, As_ + wave * 512 + 2048);
    {
      int G = tid;
      #pragma unroll
      for (int it = 0; it < 2; ++it, G += 256) {
        int rn = G >> 2, sg = G & 3;
        if (rn < 80) {
          short8 v = *(const short8*)(WT + (long)rn * 1024 + k0 + sg * 8);
          *(short8*)(Bs_ + rn * 32 + ((sg ^ (rn & 3)) << 3)) = v;
        }
      }
    }
    __syncthreads();
    short8 a[2], bfrag[5];
    #pragma unroll
    for (int i = 0; i < 2; ++i)
      a[i] = *(const short8*)(As_ + (wave * 32 + i * 16 + (lane & 15)) * 32 + swz);
    #pragma unroll
    for (int j = 0; j < 5; ++j)
      bfrag[j] = *(const short8*)(Bs_ + (j * 16 + (lane & 15)) * 32 + swz);
    #pragma unroll
    for (int i = 0; i < 2; ++i)
      #pragma unroll
      for (int j = 0; j < 5; ++j)
        acc[i][j] = MFMA16(a[i], bfrag[j], acc[i][j]);
    __syncthreads();
  }

  float bsv[5];
  #pragma unroll
  for (int j = 0; j < 5; ++j) bsv[j] = bias[j * 16 + (lane & 15)];
  #pragma unroll
  for (int i = 0; i < 2; ++i)
    #pragma unroll
    for (int j = 0; j < 5; ++j)
      #pragma unroll
      for (int rr = 0; rr < 4; ++rr)
        zbuf[wave * 32 + i * 16 + (lane >> 4) * 4 + rr][j * 16 + (lane & 15)] =
            acc[i][j][rr] + bsv[j];
  __syncthreads();

  if (tid < 128) {
    float mx = -1e30f;
    for (int j = 0; j < 80; ++j) mx = fmaxf(mx, zbuf[tid][j]);
    float s = 0.f;
    for (int j = 0; j < 80; ++j) s += __expf(zbuf[tid][j] - mx);
    rmax[tid] = mx;
    rlse[tid] = logf(s);
  }
  __syncthreads();

  for (int idx = tid; idx < 128 * 80; idx += 256) {
    const int row = idx / 80, j = idx - row * 80;
    out[(long)m0 * 80 + idx] = zbuf[row][j] - rmax[row] - rlse[row];
  }
}

extern "C" void kernel_launch(void* const* d_in, const int* in_sizes, int n_in,
                              void* d_out, int out_size, void* d_ws, size_t ws_size,
                              hipStream_t stream) {
  const float* x  = (const float*)d_in[0];
  const float* k1 = (const float*)d_in[1];  const float* b1 = (const float*)d_in[2];
  const float* s1 = (const float*)d_in[3];  const float* o1 = (const float*)d_in[4];
  const float* m1 = (const float*)d_in[5];  const float* v1 = (const float*)d_in[6];
  const float* k2 = (const float*)d_in[7];  const float* b2 = (const float*)d_in[8];
  const float* s2 = (const float*)d_in[9];  const float* o2 = (const float*)d_in[10];
  const float* m2 = (const float*)d_in[11]; const float* v2 = (const float*)d_in[12];
  const float* k3 = (const float*)d_in[13]; const float* b3 = (const float*)d_in[14];
  const float* s3 = (const float*)d_in[15]; const float* o3 = (const float*)d_in[16];
  const float* m3 = (const float*)d_in[17]; const float* v3 = (const float*)d_in[18];
  const float* k4 = (const float*)d_in[19]; const float* b4 = (const float*)d_in[20];
  const float* s4 = (const float*)d_in[21]; const float* o4 = (const float*)d_in[22];
  const float* m4 = (const float*)d_in[23]; const float* v4 = (const float*)d_in[24];
  const float* k5 = (const float*)d_in[25]; const float* b5 = (const float*)d_in[26];
  const float* s5 = (const float*)d_in[27]; const float* o5 = (const float*)d_in[28];
  const float* m5 = (const float*)d_in[29]; const float* v5 = (const float*)d_in[30];
  const float* fwWi = (const float*)d_in[31];
  const float* fwWh = (const float*)d_in[32];
  const float* fwb  = (const float*)d_in[33];
  const float* bwWi = (const float*)d_in[34];
  const float* bwWh = (const float*)d_in[35];
  const float* bwb  = (const float*)d_in[36];
  const float* fcW  = (const float*)d_in[37];
  const float* fcb  = (const float*)d_in[38];

  char* wsb = (char*)d_ws;
  unsigned short* REG_A = (unsigned short*)(wsb);                  // 33,554,432 B
  unsigned short* REG_P = (unsigned short*)(wsb + 33554432);       // 19,169,280 B
  unsigned short* C4    = (unsigned short*)(wsb + 52723712);       //  6,684,672 B
  unsigned short* wT2   = (unsigned short*)(wsb + 59408384);       //    147,456 B
  unsigned short* wT3   = (unsigned short*)(wsb + 59555840);       //    589,824 B
  unsigned short* wT4   = (unsigned short*)(wsb + 60145664);       //  1,179,648 B
  unsigned short* wT5   = (unsigned short*)(wsb + 61325312);       //  2,359,296 B
  unsigned short* WiTF  = (unsigned short*)(wsb + 63684608);       //  8,388,608 B
  unsigned short* WiTB  = (unsigned short*)(wsb + 72073216);       //  8,388,608 B
  unsigned short* WhTF  = (unsigned short*)(wsb + 80461824);       //  2,097,152 B
  unsigned short* WhTB  = (unsigned short*)(wsb + 82558976);       //  2,097,152 B
  unsigned short* WTfc  = (unsigned short*)(wsb + 84656128);       //    163,840 B
  float* xwF = (float*)(wsb + 84819968);                           // 16,777,216 B
  float* xwB = (float*)(wsb + 101597184);                          // 16,777,216 B
  int*   bar = (int*)(wsb + 118374400);                            //      4,096 B
  unsigned short* hsF = (unsigned short*)(wsb + 118378496);        //  2,162,688 B
  unsigned short* hsB = (unsigned short*)(wsb + 120541184);        //  2,162,688 B

  // zeros: {bar+hsF slab0}, {hsB slab0}, {C4 full}, {P1 full}
  zero_multi<<<2048, 256, 0, stream>>>(
      (float*)(wsb + 118374400), 17408,
      (float*)(wsb + 120541184), 16384,
      (float*)(wsb + 52723712), 1671168,
      (float*)(wsb + 33554432), 4792320);

  // all weight transposes in one dispatch
  TAll tp;
  tp.src[0] = k2; tp.dst[0] = wT2; tp.K[0] = 576;  tp.N[0] = 128;
  tp.src[1] = k3; tp.dst[1] = wT3; tp.K[1] = 1152; tp.N[1] = 256;
  tp.src[2] = k4; tp.dst[2] = wT4; tp.K[2] = 2304; tp.N[2] = 256;
  tp.src[3] = k5; tp.dst[3] = wT5; tp.K[3] = 2304; tp.N[3] = 512;
  tp.src[4] = fwWi + 4194304; tp.dst[4] = WiTF; tp.K[4] = 2048; tp.N[4] = 2048;
  tp.src[5] = bwWi + 4194304; tp.dst[5] = WiTB; tp.K[5] = 2048; tp.N[5] = 2048;
  tp.src[6] = fwWh + 1048576; tp.dst[6] = WhTF; tp.K[6] = 512;  tp.N[6] = 2048;
  tp.src[7] = bwWh + 1048576; tp.dst[7] = WhTB; tp.K[7] = 512;  tp.N[7] = 2048;
  transpose_multi<<<dim3(72, 64, 8), 256, 0, stream>>>(tp);
  transpose_fc<<<320, 256, 0, stream>>>(fcW, WTfc);

  // fused conv1+pool1 -> P1 padded [64,18,130,64]
  conv1_pool<<<1024, 256, 0, stream>>>(x, k1, b1, s1, o1, m1, v1, REG_P);

  // conv2: P1 -> C2 [64,16,128,128]
  conv_mfma128<64, 128, 16, 128, 0, 1024, 1><<<1024, 256, 0, stream>>>(
      REG_P, wT2, b2, s2, o2, m2, v2, REG_A);
  maxpool_pad<128, 8, 64><<<dim3(33, 640), 256, 0, stream>>>(REG_A, REG_P);

  // conv3: P2 -> C3 [64,8,64,256]
  conv_mfma128<128, 256, 8, 64, 0, 256, 2><<<512, 256, 0, stream>>>(
      REG_P, wT3, b3, s3, o3, m3, v3, REG_A);
  maxpool_pad<256, 4, 32><<<dim3(34, 384), 256, 0, stream>>>(REG_A, REG_P);

  // conv4: P3 -> C4 PADDED [64,6,34,256]
  conv_mfma128<256, 256, 4, 32, 1, 64, 2><<<128, 256, 0, stream>>>(
      REG_P, wT4, b4, s4, o4, m4, v4, C4);

  // conv5: C4 -> C5 [64,4,32,512]
  conv_mfma128<256, 512, 4, 32, 0, 64, 4><<<256, 256, 0, stream>>>(
      C4, wT5, b5, s5, o5, m5, v5, REG_A);

  // xw precompute, both directions fused (layer 1 only), XCD-swizzled
  gemm_xw2<<<dim3(256, 1, 2), 256, 0, stream>>>(
      REG_A, WiTF, WiTB, fwb + 2048, bwb + 2048, xwF, xwB);

  // all 32 LSTM steps, both directions, single launch
  lstm_persist<<<64, 256, 0, stream>>>(WhTF, WhTB, xwF, xwB, hsF, hsB, bar);

  // FC + log_softmax
  fc_mfma_ls<<<16, 256, 0, stream>>>(hsF, hsB, WTfc, fcb, (float*)d_out);
}